// Round 3
// baseline (517.553 us; speedup 1.0000x reference)
//
#include <hip/hip_runtime.h>

#define IN_F 128
#define EF 16

typedef short bf16x8 __attribute__((ext_vector_type(8)));
typedef float f32x4  __attribute__((ext_vector_type(4)));

// bf16 helpers: pack is RNE; unpack low/high halves of a uint holding 2 bf16
__device__ __forceinline__ unsigned short f2b(float f) {
    unsigned b = __float_as_uint(f);
    b += 0x7fffu + ((b >> 16) & 1u);
    return (unsigned short)(b >> 16);
}
__device__ __forceinline__ float blo(unsigned u) { return __uint_as_float(u << 16); }
__device__ __forceinline__ float bhi(unsigned u) { return __uint_as_float(u & 0xffff0000u); }

// ============================ CSR-build path ================================

// fused pre-pass: h2b cast + dst histogram (recording per-edge rank) +
// W1/W2 transpose-cast. all mutually independent, all precede the scan.
__global__ __launch_bounds__(256) void pre_kernel(
    const float* __restrict__ H, unsigned short* __restrict__ Hb, int n4,
    const int* __restrict__ ei, int* __restrict__ counts,
    int* __restrict__ rank, int E,
    const float* __restrict__ W1, unsigned short* __restrict__ W1t,
    const float* __restrict__ W2, unsigned short* __restrict__ W2t,
    int h2b_blocks, int hist_blocks)
{
    int b = blockIdx.x;
    if (b < h2b_blocks) {
        int i = b * 256 + threadIdx.x;
        if (i < n4) {
            float4 v = ((const float4*)H)[i];
            ushort4 r;
            r.x = f2b(v.x); r.y = f2b(v.y); r.z = f2b(v.z); r.w = f2b(v.w);
            ((ushort4*)Hb)[i] = r;
        }
    } else if (b < h2b_blocks + hist_blocks) {
        int e = (b - h2b_blocks) * 256 + threadIdx.x;
        if (e < E) rank[e] = atomicAdd(&counts[ei[E + e]], 1);
    } else {
        int idx = (b - h2b_blocks - hist_blocks) * 256 + threadIdx.x; // 0..32767
        int w = idx >> 14;           // 0: W1, 1: W2
        int r = idx & 16383;
        int n = r >> 7, k = r & 127;
        if (w == 0) W1t[n * IN_F + k] = f2b(W1[k * IN_F + n]);
        else        W2t[n * IN_F + k] = f2b(W2[k * IN_F + n]);
    }
}

// standalone hist (fp32 CSR fallback path) — also records rank
__global__ __launch_bounds__(256) void hist_kernel(
    const int* __restrict__ ei, int* __restrict__ counts,
    int* __restrict__ rank, int E)
{
    int e = blockIdx.x * 256 + threadIdx.x;
    if (e >= E) return;
    rank[e] = atomicAdd(&counts[ei[E + e]], 1);
}

__global__ __launch_bounds__(256) void scan_blocks_kernel(
    const int* __restrict__ in, int* __restrict__ out,
    int* __restrict__ partials, int n)
{
    __shared__ int sdata[256];
    const int t = threadIdx.x;
    const int idx0 = blockIdx.x * 1024 + t * 4;
    int v[4];
    #pragma unroll
    for (int i = 0; i < 4; i++) { int idx = idx0 + i; v[i] = (idx < n) ? in[idx] : 0; }
    int s = v[0] + v[1] + v[2] + v[3];
    sdata[t] = s;
    __syncthreads();
    for (int off = 1; off < 256; off <<= 1) {
        int x = (t >= off) ? sdata[t - off] : 0;
        __syncthreads();
        sdata[t] += x;
        __syncthreads();
    }
    if (t == 255) partials[blockIdx.x] = sdata[255];
    int run = (t > 0) ? sdata[t - 1] : 0;
    #pragma unroll
    for (int i = 0; i < 4; i++) {
        int idx = idx0 + i;
        if (idx < n) out[idx] = run;
        run += v[i];
    }
}

// scan_add with the partial-prefix computed in-block: every index in a
// 256-thread block shares one 1024-group g = blockIdx>>2, so the block needs
// exactly sum(partials[0..g-1]) — reduce it here, kill scan_partials dispatch.
__global__ __launch_bounds__(256) void scan_add_fused_kernel(
    int* __restrict__ out, const int* __restrict__ partials, int n)
{
    __shared__ int sw[4];
    const int t = threadIdx.x;
    const int g = blockIdx.x >> 2;
    int v = 0;
    for (int j = t; j < g; j += 256) v += partials[j];
    #pragma unroll
    for (int off = 1; off < 64; off <<= 1) v += __shfl_xor(v, off, 64);
    if ((t & 63) == 0) sw[t >> 6] = v;
    __syncthreads();
    int P = sw[0] + sw[1] + sw[2] + sw[3];
    int idx = blockIdx.x * 256 + t;
    if (idx < n) out[idx] += P;
}

// build v2: pos = offsets[dst] + rank[e]; scatter src index AND the EA row
// into CSR order so the gather consumes EA as a pure sequential stream.
__global__ __launch_bounds__(256) void build_ea_kernel(
    const int* __restrict__ ei,
    const float* __restrict__ EA,
    const int* __restrict__ offsets, const int* __restrict__ rank,
    int* __restrict__ sorted_src, float* __restrict__ EAsorted, int E)
{
    int e = blockIdx.x * 256 + threadIdx.x;
    if (e >= E) return;
    int src = ei[e];
    int dst = ei[E + e];
    int pos = offsets[dst] + rank[e];
    sorted_src[pos] = src;
    const float4* s4 = (const float4*)(EA + (long long)e * EF);
    float4* d4 = (float4*)(EAsorted + (long long)pos * EF);
    float4 v0 = s4[0], v1 = s4[1], v2 = s4[2], v3 = s4[3];
    d4[0] = v0; d4[1] = v1; d4[2] = v2; d4[3] = v3;
}

// build v1 (mid/fallback path): (src, e) pairs, EA stays edge-ordered
__global__ __launch_bounds__(256) void build_kernel(
    const int* __restrict__ ei, int2* __restrict__ sorted,
    const int* __restrict__ offsets, const int* __restrict__ rank, int E)
{
    int e = blockIdx.x * 256 + threadIdx.x;
    if (e >= E) return;
    int src = ei[e];
    int dst = ei[E + e];
    int pos = offsets[dst] + rank[e];
    sorted[pos] = make_int2(src, e);
}

// gather v2 (bf16 H, CSR-ordered EA) with fused prep epilogue:
// one wave per node; half-waves each own one edge slot (stride 2); lane covers
// feats [4*l32 .. 4*l32+3] via one 8B load. EAsorted is read sequentially.
// Epilogue computes a = agg + aggE@We + deg*be in-register and writes Ab (bf16).
__global__ __launch_bounds__(256) void gather_ea_kernel(
    const unsigned short* __restrict__ Hb,
    const float* __restrict__ EAsorted,
    const int* __restrict__ sorted_src,
    const int* __restrict__ offsets,
    const float* __restrict__ We,
    const float* __restrict__ be,
    unsigned short* __restrict__ Ab,    // [N,128] bf16
    int N)
{
    int n = blockIdx.x * 4 + (threadIdx.x >> 6);
    if (n >= N) return;
    int lane = threadIdx.x & 63;
    int half = lane >> 5;
    int l32  = lane & 31;
    int s = offsets[n];
    int e_end = offsets[n + 1];
    float a0 = 0.f, a1 = 0.f, a2 = 0.f, a3 = 0.f, accE = 0.f;
    int i = s + half;
    for (; i + 6 < e_end; i += 8) {
        int s0 = sorted_src[i];
        int s1 = sorted_src[i + 2];
        int s2 = sorted_src[i + 4];
        int s3 = sorted_src[i + 6];
        uint2 u0 = *(const uint2*)(Hb + (long long)s0 * IN_F + l32 * 4);
        uint2 u1 = *(const uint2*)(Hb + (long long)s1 * IN_F + l32 * 4);
        uint2 u2 = *(const uint2*)(Hb + (long long)s2 * IN_F + l32 * 4);
        uint2 u3 = *(const uint2*)(Hb + (long long)s3 * IN_F + l32 * 4);
        float e0 = 0.f, e1 = 0.f, e2 = 0.f, e3 = 0.f;
        if (l32 < EF) {
            e0 = EAsorted[(long long)(i    ) * EF + l32];
            e1 = EAsorted[(long long)(i + 2) * EF + l32];
            e2 = EAsorted[(long long)(i + 4) * EF + l32];
            e3 = EAsorted[(long long)(i + 6) * EF + l32];
        }
        a0 += (blo(u0.x) + blo(u1.x)) + (blo(u2.x) + blo(u3.x));
        a1 += (bhi(u0.x) + bhi(u1.x)) + (bhi(u2.x) + bhi(u3.x));
        a2 += (blo(u0.y) + blo(u1.y)) + (blo(u2.y) + blo(u3.y));
        a3 += (bhi(u0.y) + bhi(u1.y)) + (bhi(u2.y) + bhi(u3.y));
        accE += (e0 + e1) + (e2 + e3);
    }
    for (; i < e_end; i += 2) {
        int se = sorted_src[i];
        uint2 u = *(const uint2*)(Hb + (long long)se * IN_F + l32 * 4);
        a0 += blo(u.x); a1 += bhi(u.x); a2 += blo(u.y); a3 += bhi(u.y);
        if (l32 < EF) accE += EAsorted[(long long)i * EF + l32];
    }
    a0 += __shfl_xor(a0, 32, 64);
    a1 += __shfl_xor(a1, 32, 64);
    a2 += __shfl_xor(a2, 32, 64);
    a3 += __shfl_xor(a3, 32, 64);
    accE += __shfl_xor(accE, 32, 64);

    // fused prep: v = agg + deg*be + aggE @ We  (accE[k] lives in lane k)
    const int c4 = l32 * 4;
    const float deg = (float)(e_end - s);
    float4 bev = *(const float4*)&be[c4];
    float vx = a0 + deg * bev.x;
    float vy = a1 + deg * bev.y;
    float vz = a2 + deg * bev.z;
    float vw = a3 + deg * bev.w;
    #pragma unroll
    for (int k = 0; k < EF; k++) {
        float ak = __shfl(accE, k, 64);
        float4 w = *(const float4*)&We[k * IN_F + c4];
        vx += ak * w.x; vy += ak * w.y; vz += ak * w.z; vw += ak * w.w;
    }
    if (half == 0) {
        ushort4 o;
        o.x = f2b(vx); o.y = f2b(vy); o.z = f2b(vz); o.w = f2b(vw);
        *(ushort4*)&Ab[(long long)n * IN_F + c4] = o;
    }
}

// gather v1 (bf16 H, edge-ordered EA) with fused prep epilogue — mid path
__global__ __launch_bounds__(256) void gather_fused_kernel(
    const unsigned short* __restrict__ Hb,
    const float* __restrict__ EA,
    const int2* __restrict__ sorted,
    const int* __restrict__ offsets,
    const float* __restrict__ We,
    const float* __restrict__ be,
    unsigned short* __restrict__ Ab,    // [N,128] bf16
    int N)
{
    int n = blockIdx.x * 4 + (threadIdx.x >> 6);
    if (n >= N) return;
    int lane = threadIdx.x & 63;
    int half = lane >> 5;
    int l32  = lane & 31;
    int s = offsets[n];
    int e_end = offsets[n + 1];
    float a0 = 0.f, a1 = 0.f, a2 = 0.f, a3 = 0.f, accE = 0.f;
    int i = s + half;
    for (; i + 6 < e_end; i += 8) {
        int2 s0 = sorted[i];
        int2 s1 = sorted[i + 2];
        int2 s2 = sorted[i + 4];
        int2 s3 = sorted[i + 6];
        uint2 u0 = *(const uint2*)(Hb + (long long)s0.x * IN_F + l32 * 4);
        uint2 u1 = *(const uint2*)(Hb + (long long)s1.x * IN_F + l32 * 4);
        uint2 u2 = *(const uint2*)(Hb + (long long)s2.x * IN_F + l32 * 4);
        uint2 u3 = *(const uint2*)(Hb + (long long)s3.x * IN_F + l32 * 4);
        float e0 = 0.f, e1 = 0.f, e2 = 0.f, e3 = 0.f;
        if (l32 < EF) {
            e0 = EA[(long long)s0.y * EF + l32];
            e1 = EA[(long long)s1.y * EF + l32];
            e2 = EA[(long long)s2.y * EF + l32];
            e3 = EA[(long long)s3.y * EF + l32];
        }
        a0 += (blo(u0.x) + blo(u1.x)) + (blo(u2.x) + blo(u3.x));
        a1 += (bhi(u0.x) + bhi(u1.x)) + (bhi(u2.x) + bhi(u3.x));
        a2 += (blo(u0.y) + blo(u1.y)) + (blo(u2.y) + blo(u3.y));
        a3 += (bhi(u0.y) + bhi(u1.y)) + (bhi(u2.y) + bhi(u3.y));
        accE += (e0 + e1) + (e2 + e3);
    }
    for (; i < e_end; i += 2) {
        int2 se = sorted[i];
        uint2 u = *(const uint2*)(Hb + (long long)se.x * IN_F + l32 * 4);
        a0 += blo(u.x); a1 += bhi(u.x); a2 += blo(u.y); a3 += bhi(u.y);
        if (l32 < EF) accE += EA[(long long)se.y * EF + l32];
    }
    a0 += __shfl_xor(a0, 32, 64);
    a1 += __shfl_xor(a1, 32, 64);
    a2 += __shfl_xor(a2, 32, 64);
    a3 += __shfl_xor(a3, 32, 64);
    accE += __shfl_xor(accE, 32, 64);

    const int c4 = l32 * 4;
    const float deg = (float)(e_end - s);
    float4 bev = *(const float4*)&be[c4];
    float vx = a0 + deg * bev.x;
    float vy = a1 + deg * bev.y;
    float vz = a2 + deg * bev.z;
    float vw = a3 + deg * bev.w;
    #pragma unroll
    for (int k = 0; k < EF; k++) {
        float ak = __shfl(accE, k, 64);
        float4 w = *(const float4*)&We[k * IN_F + c4];
        vx += ak * w.x; vy += ak * w.y; vz += ak * w.z; vw += ak * w.w;
    }
    if (half == 0) {
        ushort4 o;
        o.x = f2b(vx); o.y = f2b(vy); o.z = f2b(vz); o.w = f2b(vw);
        *(ushort4*)&Ab[(long long)n * IN_F + c4] = o;
    }
}

// gather (fp32 H) fallback — writes agg/aggE/deg for node_mlp path
__global__ __launch_bounds__(256) void gather_f32_kernel(
    const float* __restrict__ H,
    const float* __restrict__ EA,
    const int2* __restrict__ sorted,
    const int* __restrict__ offsets,
    float* __restrict__ agg,
    float* __restrict__ aggE,
    float* __restrict__ degf,
    int N)
{
    int n = blockIdx.x * 4 + (threadIdx.x >> 6);
    if (n >= N) return;
    int lane = threadIdx.x & 63;
    int half = lane >> 5;
    int l32  = lane & 31;
    int s = offsets[n];
    int e_end = offsets[n + 1];
    float4 acc = make_float4(0.f, 0.f, 0.f, 0.f);
    float accE = 0.f;
    int i = s + half;
    for (; i + 6 < e_end; i += 8) {
        int2 s0 = sorted[i];
        int2 s1 = sorted[i + 2];
        int2 s2 = sorted[i + 4];
        int2 s3 = sorted[i + 6];
        float4 v0 = *(const float4*)(H + (long long)s0.x * IN_F + l32 * 4);
        float4 v1 = *(const float4*)(H + (long long)s1.x * IN_F + l32 * 4);
        float4 v2 = *(const float4*)(H + (long long)s2.x * IN_F + l32 * 4);
        float4 v3 = *(const float4*)(H + (long long)s3.x * IN_F + l32 * 4);
        float e0 = 0.f, e1 = 0.f, e2 = 0.f, e3 = 0.f;
        if (l32 < EF) {
            e0 = EA[(long long)s0.y * EF + l32];
            e1 = EA[(long long)s1.y * EF + l32];
            e2 = EA[(long long)s2.y * EF + l32];
            e3 = EA[(long long)s3.y * EF + l32];
        }
        acc.x += (v0.x + v1.x) + (v2.x + v3.x);
        acc.y += (v0.y + v1.y) + (v2.y + v3.y);
        acc.z += (v0.z + v1.z) + (v2.z + v3.z);
        acc.w += (v0.w + v1.w) + (v2.w + v3.w);
        accE  += (e0 + e1) + (e2 + e3);
    }
    for (; i < e_end; i += 2) {
        int2 se = sorted[i];
        float4 v = *(const float4*)(H + (long long)se.x * IN_F + l32 * 4);
        acc.x += v.x; acc.y += v.y; acc.z += v.z; acc.w += v.w;
        if (l32 < EF) accE += EA[(long long)se.y * EF + l32];
    }
    acc.x += __shfl_xor(acc.x, 32, 64);
    acc.y += __shfl_xor(acc.y, 32, 64);
    acc.z += __shfl_xor(acc.z, 32, 64);
    acc.w += __shfl_xor(acc.w, 32, 64);
    accE  += __shfl_xor(accE, 32, 64);
    if (half == 0) {
        *(float4*)(agg + (long long)n * IN_F + l32 * 4) = acc;
        if (l32 < EF) aggE[n * EF + l32] = accE;
        if (l32 == 0) degf[n] = (float)(e_end - s);
    }
}

// ======================= fallback: atomic scatter ===========================
__global__ __launch_bounds__(256) void edge_scatter_kernel(
    const float* __restrict__ H,
    const int* __restrict__ ei,
    const float* __restrict__ EA,
    float* __restrict__ agg,
    float* __restrict__ aggE,
    float* __restrict__ deg,
    int E)
{
    long long gid = (long long)blockIdx.x * 256 + threadIdx.x;
    int e = (int)(gid >> 7);
    if (e >= E) return;
    int f = (int)(gid & 127);
    int src = ei[e];
    int dst = ei[E + e];
    float m = H[(long long)src * IN_F + f];
    atomicAdd(&agg[(long long)dst * IN_F + f], m);
    if (f < EF) atomicAdd(&aggE[dst * EF + f], EA[e * EF + f]);
    if (f == 0) atomicAdd(&deg[dst], 1.0f);
}

// ========================= MFMA node-MLP path ===============================

// fused 2-layer MLP on MFMA:
//   h = relu(Ab @ W1 + b1);  out = h @ W2 + b2
// 64-row tile, 4 waves; wave w owns rows M0=16w..M0+15. A-tile + Wt in LDS
// (pitch 136 shorts: row stride 68 dwords -> only free 2-way bank aliasing).
// h written back into the wave-private sX region (C/D -> A layout transform),
// W buffer barrier-swapped W1t -> W2t.
#define XPITCH 136
__global__ __launch_bounds__(256) void mlp_mfma_kernel(
    const unsigned short* __restrict__ Ab,
    const unsigned short* __restrict__ W1t,
    const unsigned short* __restrict__ W2t,
    const float* __restrict__ b1, const float* __restrict__ b2,
    float* __restrict__ out, int N)
{
    __shared__ unsigned short sW[128 * XPITCH];   // 34816 B
    __shared__ unsigned short sX[64 * XPITCH];    // 17408 B
    const int t    = threadIdx.x;
    const int tile = blockIdx.x * 64;
    const int lane = t & 63;
    const int wv   = t >> 6;          // 0..3
    const int quad = lane >> 4;       // 0..3
    const int lr   = lane & 15;
    const int M0   = wv * 16;

    // stage A tile (64 rows x 16 uint4) and W1t (128 rows x 16 uint4); 17 uint4/row pitch
    {
        const uint4 z = make_uint4(0, 0, 0, 0);
        #pragma unroll
        for (int j = 0; j < 4; j++) {
            int idx = t + 256 * j;                 // 0..1023
            int row = idx >> 4, c = idx & 15;
            uint4 v = z;
            if (tile + row < N) v = ((const uint4*)Ab)[(long long)(tile + row) * 16 + c];
            ((uint4*)sX)[row * 17 + c] = v;
        }
        #pragma unroll
        for (int j = 0; j < 8; j++) {
            int idx = t + 256 * j;                 // 0..2047
            int row = idx >> 4, c = idx & 15;
            ((uint4*)sW)[row * 17 + c] = ((const uint4*)W1t)[idx];
        }
    }
    __syncthreads();

    f32x4 acc[8];
    bf16x8 af[4];
    const f32x4 zero = {0.f, 0.f, 0.f, 0.f};

    // phase 2: h = relu(A @ W1 + b1) -> sX rows M0..M0+15 (wave-private)
    #pragma unroll
    for (int kt = 0; kt < 4; kt++)
        af[kt] = *(const bf16x8*)&sX[(M0 + lr) * XPITCH + kt * 32 + quad * 8];
    #pragma unroll
    for (int nt = 0; nt < 8; nt++) {
        acc[nt] = zero;
        #pragma unroll
        for (int kt = 0; kt < 4; kt++) {
            bf16x8 bf = *(const bf16x8*)&sW[(nt * 16 + lr) * XPITCH + kt * 32 + quad * 8];
            acc[nt] = __builtin_amdgcn_mfma_f32_16x16x32_bf16(af[kt], bf, acc[nt], 0, 0, 0);
        }
    }
    #pragma unroll
    for (int nt = 0; nt < 8; nt++) {
        int col = nt * 16 + lr;
        float bias = b1[col];
        #pragma unroll
        for (int r = 0; r < 4; r++) {
            float v = fmaxf(acc[nt][r] + bias, 0.f);
            sX[(M0 + quad * 4 + r) * XPITCH + col] = f2b(v);
        }
    }
    __syncthreads();    // all waves done reading W1t
    #pragma unroll
    for (int j = 0; j < 8; j++) {
        int idx = t + 256 * j;
        int row = idx >> 4, c = idx & 15;
        ((uint4*)sW)[row * 17 + c] = ((const uint4*)W2t)[idx];
    }
    __syncthreads();

    // phase 3: out = h @ W2 + b2
    #pragma unroll
    for (int kt = 0; kt < 4; kt++)
        af[kt] = *(const bf16x8*)&sX[(M0 + lr) * XPITCH + kt * 32 + quad * 8];
    #pragma unroll
    for (int nt = 0; nt < 8; nt++) {
        acc[nt] = zero;
        #pragma unroll
        for (int kt = 0; kt < 4; kt++) {
            bf16x8 bf = *(const bf16x8*)&sW[(nt * 16 + lr) * XPITCH + kt * 32 + quad * 8];
            acc[nt] = __builtin_amdgcn_mfma_f32_16x16x32_bf16(af[kt], bf, acc[nt], 0, 0, 0);
        }
    }
    #pragma unroll
    for (int nt = 0; nt < 8; nt++) {
        int col = nt * 16 + lr;
        float bias = b2[col];
        #pragma unroll
        for (int r = 0; r < 4; r++) {
            int row = tile + M0 + quad * 4 + r;
            if (row < N) out[(long long)row * IN_F + col] = acc[nt][r] + bias;
        }
    }
}

// ================== fp32 node MLP (fallback path only) ======================
__global__ __launch_bounds__(256) void node_mlp_kernel(
    float* agg_out,
    const float* __restrict__ aggE,
    const float* __restrict__ degf,
    const float* __restrict__ We, const float* __restrict__ be,
    const float* __restrict__ W1, const float* __restrict__ b1,
    const float* __restrict__ W2, const float* __restrict__ b2,
    int N)
{
    __shared__ float sA[32][IN_F];
    __shared__ float sH[32][IN_F];
    const int t  = threadIdx.x;
    const int c4 = (t & 31) * 4;
    const int r0 = t >> 5;

    const int tile = blockIdx.x * 32;
    if (tile >= N) return;
    int rows = N - tile;
    if (rows > 32) rows = 32;

    {
        const float4 bev = *(const float4*)&be[c4];
        #pragma unroll
        for (int i = 0; i < 4; i++) {
            int rr = r0 + 8 * i;
            float4 v = make_float4(0.f, 0.f, 0.f, 0.f);
            if (rr < rows) {
                long long r = tile + rr;
                v = *(const float4*)&agg_out[r * IN_F + c4];
                float d = degf[r];
                v.x += d * bev.x; v.y += d * bev.y; v.z += d * bev.z; v.w += d * bev.w;
                #pragma unroll
                for (int k = 0; k < EF; k++) {
                    float a = aggE[r * EF + k];
                    float4 w = *(const float4*)&We[k * IN_F + c4];
                    v.x += a * w.x; v.y += a * w.y; v.z += a * w.z; v.w += a * w.w;
                }
            }
            *(float4*)&sA[rr][c4] = v;
        }
    }
    __syncthreads();
    {
        const float4 bv = *(const float4*)&b1[c4];
        float4 a0 = bv, a1 = bv, a2 = bv, a3 = bv;
        for (int k = 0; k < IN_F; k++) {
            float4 w = *(const float4*)&W1[k * IN_F + c4];
            float x0 = sA[r0][k], x1 = sA[r0 + 8][k], x2 = sA[r0 + 16][k], x3 = sA[r0 + 24][k];
            a0.x += x0 * w.x; a0.y += x0 * w.y; a0.z += x0 * w.z; a0.w += x0 * w.w;
            a1.x += x1 * w.x; a1.y += x1 * w.y; a1.z += x1 * w.z; a1.w += x1 * w.w;
            a2.x += x2 * w.x; a2.y += x2 * w.y; a2.z += x2 * w.z; a2.w += x2 * w.w;
            a3.x += x3 * w.x; a3.y += x3 * w.y; a3.z += x3 * w.z; a3.w += x3 * w.w;
        }
        a0.x = fmaxf(a0.x, 0.f); a0.y = fmaxf(a0.y, 0.f); a0.z = fmaxf(a0.z, 0.f); a0.w = fmaxf(a0.w, 0.f);
        a1.x = fmaxf(a1.x, 0.f); a1.y = fmaxf(a1.y, 0.f); a1.z = fmaxf(a1.z, 0.f); a1.w = fmaxf(a1.w, 0.f);
        a2.x = fmaxf(a2.x, 0.f); a2.y = fmaxf(a2.y, 0.f); a2.z = fmaxf(a2.z, 0.f); a2.w = fmaxf(a2.w, 0.f);
        a3.x = fmaxf(a3.x, 0.f); a3.y = fmaxf(a3.y, 0.f); a3.z = fmaxf(a3.z, 0.f); a3.w = fmaxf(a3.w, 0.f);
        *(float4*)&sH[r0][c4]      = a0;
        *(float4*)&sH[r0 + 8][c4]  = a1;
        *(float4*)&sH[r0 + 16][c4] = a2;
        *(float4*)&sH[r0 + 24][c4] = a3;
    }
    __syncthreads();
    {
        const float4 bv = *(const float4*)&b2[c4];
        float4 a0 = bv, a1 = bv, a2 = bv, a3 = bv;
        for (int k = 0; k < IN_F; k++) {
            float4 w = *(const float4*)&W2[k * IN_F + c4];
            float x0 = sH[r0][k], x1 = sH[r0 + 8][k], x2 = sH[r0 + 16][k], x3 = sH[r0 + 24][k];
            a0.x += x0 * w.x; a0.y += x0 * w.y; a0.z += x0 * w.z; a0.w += x0 * w.w;
            a1.x += x1 * w.x; a1.y += x1 * w.y; a1.z += x1 * w.z; a1.w += x1 * w.w;
            a2.x += x2 * w.x; a2.y += x2 * w.y; a2.z += x2 * w.z; a2.w += x2 * w.w;
            a3.x += x3 * w.x; a3.y += x3 * w.y; a3.z += x3 * w.z; a3.w += x3 * w.w;
        }
        #pragma unroll
        for (int i = 0; i < 4; i++) {
            int rr = r0 + 8 * i;
            if (rr < rows) {
                float4 v = (i == 0) ? a0 : (i == 1) ? a1 : (i == 2) ? a2 : a3;
                *(float4*)&agg_out[(long long)(tile + rr) * IN_F + c4] = v;
            }
        }
    }
}

// ================================ host ======================================
extern "C" void kernel_launch(void* const* d_in, const int* in_sizes, int n_in,
                              void* d_out, int out_size, void* d_ws, size_t ws_size,
                              hipStream_t stream) {
    const float* H  = (const float*)d_in[0];
    const int*   ei = (const int*)d_in[1];     // int32 [2,E]
    const float* EA = (const float*)d_in[2];
    const float* We = (const float*)d_in[3];
    const float* be = (const float*)d_in[4];
    const float* W1 = (const float*)d_in[5];
    const float* b1 = (const float*)d_in[6];
    const float* W2 = (const float*)d_in[7];
    const float* b2 = (const float*)d_in[8];
    float* out = (float*)d_out;

    const int N = in_sizes[0] / IN_F;
    const int E = in_sizes[2] / EF;

    char* p = (char*)d_ws;
    auto alloc = [&](size_t bytes) { char* r = p; p += (bytes + 255) & ~(size_t)255; return r; };
    int2*  sorted   = (int2*)alloc((size_t)E * sizeof(int2));
    int*   rank     = (int*)alloc((size_t)E * sizeof(int));
    float* aggE     = (float*)alloc((size_t)N * EF * sizeof(float));
    float* degf     = (float*)alloc((size_t)N * sizeof(float));
    int*   counts   = (int*)alloc((size_t)(N + 1) * sizeof(int));
    int*   offsets  = (int*)alloc((size_t)(N + 1) * sizeof(int));
    int*   partials = (int*)alloc(1024 * sizeof(int));
    size_t need_base = (size_t)(p - (char*)d_ws);
    unsigned short* Hb = (unsigned short*)alloc((size_t)N * IN_F * sizeof(unsigned short));
    unsigned short* Ab  = (unsigned short*)alloc((size_t)N * IN_F * sizeof(unsigned short));
    unsigned short* W1t = (unsigned short*)alloc((size_t)IN_F * IN_F * sizeof(unsigned short));
    unsigned short* W2t = (unsigned short*)alloc((size_t)IN_F * IN_F * sizeof(unsigned short));
    size_t need_mfma = (size_t)(p - (char*)d_ws);
    float* EAsorted    = (float*)alloc((size_t)E * EF * sizeof(float));
    int*   sorted_src  = (int*)alloc((size_t)E * sizeof(int));
    size_t need_ea = (size_t)(p - (char*)d_ws);

    const int n_scan = N + 1;
    const int B = (n_scan + 1023) / 1024;

    if (ws_size >= need_mfma && B <= 1024) {
        // fast path
        hipMemsetAsync(counts, 0, (size_t)(N + 1) * sizeof(int), stream);
        const int n4 = N * IN_F / 4;
        const int h2b_blocks  = (n4 + 255) / 256;
        const int hist_blocks = (E + 255) / 256;
        pre_kernel<<<h2b_blocks + hist_blocks + 128, 256, 0, stream>>>(
            H, Hb, n4, ei, counts, rank, E, W1, W1t, W2, W2t, h2b_blocks, hist_blocks);
        scan_blocks_kernel<<<B, 256, 0, stream>>>(counts, offsets, partials, n_scan);
        scan_add_fused_kernel<<<(n_scan + 255) / 256, 256, 0, stream>>>(offsets, partials, n_scan);
        if (ws_size >= need_ea) {
            // v2: scatter EA into CSR order; gather streams it sequentially
            build_ea_kernel<<<(E + 255) / 256, 256, 0, stream>>>(
                ei, EA, offsets, rank, sorted_src, EAsorted, E);
            gather_ea_kernel<<<(N + 3) / 4, 256, 0, stream>>>(
                Hb, EAsorted, sorted_src, offsets, We, be, Ab, N);
        } else {
            build_kernel<<<(E + 255) / 256, 256, 0, stream>>>(ei, sorted, offsets, rank, E);
            gather_fused_kernel<<<(N + 3) / 4, 256, 0, stream>>>(Hb, EA, sorted, offsets, We, be, Ab, N);
        }
        mlp_mfma_kernel<<<(N + 63) / 64, 256, 0, stream>>>(Ab, W1t, W2t, b1, b2, out, N);
    } else if (ws_size >= need_base && B <= 1024) {
        // fp32 CSR fallback
        hipMemsetAsync(counts, 0, (size_t)(N + 1) * sizeof(int), stream);
        hist_kernel<<<(E + 255) / 256, 256, 0, stream>>>(ei, counts, rank, E);
        scan_blocks_kernel<<<B, 256, 0, stream>>>(counts, offsets, partials, n_scan);
        scan_add_fused_kernel<<<(n_scan + 255) / 256, 256, 0, stream>>>(offsets, partials, n_scan);
        build_kernel<<<(E + 255) / 256, 256, 0, stream>>>(ei, sorted, offsets, rank, E);
        gather_f32_kernel<<<(N + 3) / 4, 256, 0, stream>>>(H, EA, sorted, offsets, out, aggE, degf, N);
        node_mlp_kernel<<<(N + 31) / 32, 256, 0, stream>>>(out, aggE, degf, We, be, W1, b1, W2, b2, N);
    } else {
        // atomic-scatter fallback
        float* f_aggE = (float*)d_ws;
        float* f_deg  = f_aggE + (size_t)N * EF;
        hipMemsetAsync(d_out, 0, (size_t)N * IN_F * sizeof(float), stream);
        hipMemsetAsync(d_ws, 0, (size_t)N * (EF + 1) * sizeof(float), stream);
        long long tot = (long long)E * IN_F;
        edge_scatter_kernel<<<(int)((tot + 255) / 256), 256, 0, stream>>>(H, ei, EA, out, f_aggE, f_deg, E);
        node_mlp_kernel<<<(N + 31) / 32, 256, 0, stream>>>(out, f_aggE, f_deg, We, be, W1, b1, W2, b2, N);
    }
}

// Round 4
// 498.890 us; speedup vs baseline: 1.0374x; 1.0374x over previous
//
#include <hip/hip_runtime.h>

#define IN_F 128
#define EF 16

typedef short bf16x8 __attribute__((ext_vector_type(8)));
typedef float f32x4  __attribute__((ext_vector_type(4)));

// bf16 helpers: pack is RNE; unpack low/high halves of a uint holding 2 bf16
__device__ __forceinline__ unsigned short f2b(float f) {
    unsigned b = __float_as_uint(f);
    b += 0x7fffu + ((b >> 16) & 1u);
    return (unsigned short)(b >> 16);
}
__device__ __forceinline__ float blo(unsigned u) { return __uint_as_float(u << 16); }
__device__ __forceinline__ float bhi(unsigned u) { return __uint_as_float(u & 0xffff0000u); }

// ============================ CSR-build path ================================

// fused pre-pass: h2b cast + dst histogram (recording per-edge rank) +
// W1/W2 transpose-cast + EA segment-sum into aggE (streaming read, f32
// atomics into the 6.4 MB L2-resident aggE). All partitions independent.
__global__ __launch_bounds__(256) void pre_kernel(
    const float* __restrict__ H, unsigned short* __restrict__ Hb, int n4,
    const int* __restrict__ ei, int* __restrict__ counts,
    int* __restrict__ rank, int E,
    const float* __restrict__ W1, unsigned short* __restrict__ W1t,
    const float* __restrict__ W2, unsigned short* __restrict__ W2t,
    const float* __restrict__ EA, float* __restrict__ aggE,
    int h2b_blocks, int hist_blocks)
{
    int b = blockIdx.x;
    if (b < h2b_blocks) {
        int i = b * 256 + threadIdx.x;
        if (i < n4) {
            float4 v = ((const float4*)H)[i];
            ushort4 r;
            r.x = f2b(v.x); r.y = f2b(v.y); r.z = f2b(v.z); r.w = f2b(v.w);
            ((ushort4*)Hb)[i] = r;
        }
    } else if (b < h2b_blocks + hist_blocks) {
        int e = (b - h2b_blocks) * 256 + threadIdx.x;
        if (e < E) rank[e] = atomicAdd(&counts[ei[E + e]], 1);
    } else if (b < h2b_blocks + hist_blocks + 128) {
        int idx = (b - h2b_blocks - hist_blocks) * 256 + threadIdx.x; // 0..32767
        int w = idx >> 14;           // 0: W1, 1: W2
        int r = idx & 16383;
        int n = r >> 7, k = r & 127;
        if (w == 0) W1t[n * IN_F + k] = f2b(W1[k * IN_F + n]);
        else        W2t[n * IN_F + k] = f2b(W2[k * IN_F + n]);
    } else {
        // EA segment-sum: tid over E*EF; 16 lanes per edge (one 64B line of EA)
        long long idx = (long long)(b - h2b_blocks - hist_blocks - 128) * 256 + threadIdx.x;
        if (idx < (long long)E * EF) {
            int e = (int)(idx >> 4);
            int f = (int)(idx & 15);
            int dst = ei[E + e];
            atomicAdd(&aggE[dst * EF + f], EA[idx]);
        }
    }
}

// standalone hist (fp32 CSR fallback path) — also records rank
__global__ __launch_bounds__(256) void hist_kernel(
    const int* __restrict__ ei, int* __restrict__ counts,
    int* __restrict__ rank, int E)
{
    int e = blockIdx.x * 256 + threadIdx.x;
    if (e >= E) return;
    rank[e] = atomicAdd(&counts[ei[E + e]], 1);
}

__global__ __launch_bounds__(256) void scan_blocks_kernel(
    const int* __restrict__ in, int* __restrict__ out,
    int* __restrict__ partials, int n)
{
    __shared__ int sdata[256];
    const int t = threadIdx.x;
    const int idx0 = blockIdx.x * 1024 + t * 4;
    int v[4];
    #pragma unroll
    for (int i = 0; i < 4; i++) { int idx = idx0 + i; v[i] = (idx < n) ? in[idx] : 0; }
    int s = v[0] + v[1] + v[2] + v[3];
    sdata[t] = s;
    __syncthreads();
    for (int off = 1; off < 256; off <<= 1) {
        int x = (t >= off) ? sdata[t - off] : 0;
        __syncthreads();
        sdata[t] += x;
        __syncthreads();
    }
    if (t == 255) partials[blockIdx.x] = sdata[255];
    int run = (t > 0) ? sdata[t - 1] : 0;
    #pragma unroll
    for (int i = 0; i < 4; i++) {
        int idx = idx0 + i;
        if (idx < n) out[idx] = run;
        run += v[i];
    }
}

// scan_add with the partial-prefix computed in-block: every index in a
// 256-thread block shares one 1024-group g = blockIdx>>2, so the block needs
// exactly sum(partials[0..g-1]) — reduce it here, kill scan_partials dispatch.
__global__ __launch_bounds__(256) void scan_add_fused_kernel(
    int* __restrict__ out, const int* __restrict__ partials, int n)
{
    __shared__ int sw[4];
    const int t = threadIdx.x;
    const int g = blockIdx.x >> 2;
    int v = 0;
    for (int j = t; j < g; j += 256) v += partials[j];
    #pragma unroll
    for (int off = 1; off < 64; off <<= 1) v += __shfl_xor(v, off, 64);
    if ((t & 63) == 0) sw[t >> 6] = v;
    __syncthreads();
    int P = sw[0] + sw[1] + sw[2] + sw[3];
    int idx = blockIdx.x * 256 + t;
    if (idx < n) out[idx] += P;
}

// build (fast path): scatter only the src index — 4 B per edge
__global__ __launch_bounds__(256) void build_src_kernel(
    const int* __restrict__ ei,
    const int* __restrict__ offsets, const int* __restrict__ rank,
    int* __restrict__ sorted_src, int E)
{
    int e = blockIdx.x * 256 + threadIdx.x;
    if (e >= E) return;
    int dst = ei[E + e];
    int pos = offsets[dst] + rank[e];
    sorted_src[pos] = ei[e];
}

// build v1 (fallback path): (src, e) pairs
__global__ __launch_bounds__(256) void build_kernel(
    const int* __restrict__ ei, int2* __restrict__ sorted,
    const int* __restrict__ offsets, const int* __restrict__ rank, int E)
{
    int e = blockIdx.x * 256 + threadIdx.x;
    if (e >= E) return;
    int src = ei[e];
    int dst = ei[E + e];
    int pos = offsets[dst] + rank[e];
    sorted[pos] = make_int2(src, e);
}

// gather v3 (bf16 H, aggE precomputed):
// one wave per node; half-waves each own one edge slot (stride 2); lane covers
// feats [4*l32 .. 4*l32+3] via one 8B load (coalesced 256B per row).
// Only sorted_src (stream) + Hb (random, L3-resident) are touched in the loop.
// Epilogue: a = agg + deg*be + aggE @ We in-register -> Ab (bf16).
__global__ __launch_bounds__(256) void gather_agg_kernel(
    const unsigned short* __restrict__ Hb,
    const int* __restrict__ sorted_src,
    const int* __restrict__ offsets,
    const float* __restrict__ aggE,
    const float* __restrict__ We,
    const float* __restrict__ be,
    unsigned short* __restrict__ Ab,    // [N,128] bf16
    int N)
{
    int n = blockIdx.x * 4 + (threadIdx.x >> 6);
    if (n >= N) return;
    int lane = threadIdx.x & 63;
    int half = lane >> 5;
    int l32  = lane & 31;
    int s = offsets[n];
    int e_end = offsets[n + 1];
    float a0 = 0.f, a1 = 0.f, a2 = 0.f, a3 = 0.f;
    int i = s + half;
    for (; i + 6 < e_end; i += 8) {
        int s0 = sorted_src[i];
        int s1 = sorted_src[i + 2];
        int s2 = sorted_src[i + 4];
        int s3 = sorted_src[i + 6];
        uint2 u0 = *(const uint2*)(Hb + (long long)s0 * IN_F + l32 * 4);
        uint2 u1 = *(const uint2*)(Hb + (long long)s1 * IN_F + l32 * 4);
        uint2 u2 = *(const uint2*)(Hb + (long long)s2 * IN_F + l32 * 4);
        uint2 u3 = *(const uint2*)(Hb + (long long)s3 * IN_F + l32 * 4);
        a0 += (blo(u0.x) + blo(u1.x)) + (blo(u2.x) + blo(u3.x));
        a1 += (bhi(u0.x) + bhi(u1.x)) + (bhi(u2.x) + bhi(u3.x));
        a2 += (blo(u0.y) + blo(u1.y)) + (blo(u2.y) + blo(u3.y));
        a3 += (bhi(u0.y) + bhi(u1.y)) + (bhi(u2.y) + bhi(u3.y));
    }
    for (; i < e_end; i += 2) {
        int se = sorted_src[i];
        uint2 u = *(const uint2*)(Hb + (long long)se * IN_F + l32 * 4);
        a0 += blo(u.x); a1 += bhi(u.x); a2 += blo(u.y); a3 += bhi(u.y);
    }
    a0 += __shfl_xor(a0, 32, 64);
    a1 += __shfl_xor(a1, 32, 64);
    a2 += __shfl_xor(a2, 32, 64);
    a3 += __shfl_xor(a3, 32, 64);

    // fused prep: v = agg + deg*be + aggE @ We (aggE reads are wave-uniform)
    const int c4 = l32 * 4;
    const float deg = (float)(e_end - s);
    float4 bev = *(const float4*)&be[c4];
    float vx = a0 + deg * bev.x;
    float vy = a1 + deg * bev.y;
    float vz = a2 + deg * bev.z;
    float vw = a3 + deg * bev.w;
    #pragma unroll
    for (int k = 0; k < EF; k++) {
        float ak = aggE[n * EF + k];
        float4 w = *(const float4*)&We[k * IN_F + c4];
        vx += ak * w.x; vy += ak * w.y; vz += ak * w.z; vw += ak * w.w;
    }
    if (half == 0) {
        ushort4 o;
        o.x = f2b(vx); o.y = f2b(vy); o.z = f2b(vz); o.w = f2b(vw);
        *(ushort4*)&Ab[(long long)n * IN_F + c4] = o;
    }
}

// gather (fp32 H) fallback — writes agg/aggE/deg for node_mlp path
__global__ __launch_bounds__(256) void gather_f32_kernel(
    const float* __restrict__ H,
    const float* __restrict__ EA,
    const int2* __restrict__ sorted,
    const int* __restrict__ offsets,
    float* __restrict__ agg,
    float* __restrict__ aggE,
    float* __restrict__ degf,
    int N)
{
    int n = blockIdx.x * 4 + (threadIdx.x >> 6);
    if (n >= N) return;
    int lane = threadIdx.x & 63;
    int half = lane >> 5;
    int l32  = lane & 31;
    int s = offsets[n];
    int e_end = offsets[n + 1];
    float4 acc = make_float4(0.f, 0.f, 0.f, 0.f);
    float accE = 0.f;
    int i = s + half;
    for (; i + 6 < e_end; i += 8) {
        int2 s0 = sorted[i];
        int2 s1 = sorted[i + 2];
        int2 s2 = sorted[i + 4];
        int2 s3 = sorted[i + 6];
        float4 v0 = *(const float4*)(H + (long long)s0.x * IN_F + l32 * 4);
        float4 v1 = *(const float4*)(H + (long long)s1.x * IN_F + l32 * 4);
        float4 v2 = *(const float4*)(H + (long long)s2.x * IN_F + l32 * 4);
        float4 v3 = *(const float4*)(H + (long long)s3.x * IN_F + l32 * 4);
        float e0 = 0.f, e1 = 0.f, e2 = 0.f, e3 = 0.f;
        if (l32 < EF) {
            e0 = EA[(long long)s0.y * EF + l32];
            e1 = EA[(long long)s1.y * EF + l32];
            e2 = EA[(long long)s2.y * EF + l32];
            e3 = EA[(long long)s3.y * EF + l32];
        }
        acc.x += (v0.x + v1.x) + (v2.x + v3.x);
        acc.y += (v0.y + v1.y) + (v2.y + v3.y);
        acc.z += (v0.z + v1.z) + (v2.z + v3.z);
        acc.w += (v0.w + v1.w) + (v2.w + v3.w);
        accE  += (e0 + e1) + (e2 + e3);
    }
    for (; i < e_end; i += 2) {
        int2 se = sorted[i];
        float4 v = *(const float4*)(H + (long long)se.x * IN_F + l32 * 4);
        acc.x += v.x; acc.y += v.y; acc.z += v.z; acc.w += v.w;
        if (l32 < EF) accE += EA[(long long)se.y * EF + l32];
    }
    acc.x += __shfl_xor(acc.x, 32, 64);
    acc.y += __shfl_xor(acc.y, 32, 64);
    acc.z += __shfl_xor(acc.z, 32, 64);
    acc.w += __shfl_xor(acc.w, 32, 64);
    accE  += __shfl_xor(accE, 32, 64);
    if (half == 0) {
        *(float4*)(agg + (long long)n * IN_F + l32 * 4) = acc;
        if (l32 < EF) aggE[n * EF + l32] = accE;
        if (l32 == 0) degf[n] = (float)(e_end - s);
    }
}

// ======================= fallback: atomic scatter ===========================
__global__ __launch_bounds__(256) void edge_scatter_kernel(
    const float* __restrict__ H,
    const int* __restrict__ ei,
    const float* __restrict__ EA,
    float* __restrict__ agg,
    float* __restrict__ aggE,
    float* __restrict__ deg,
    int E)
{
    long long gid = (long long)blockIdx.x * 256 + threadIdx.x;
    int e = (int)(gid >> 7);
    if (e >= E) return;
    int f = (int)(gid & 127);
    int src = ei[e];
    int dst = ei[E + e];
    float m = H[(long long)src * IN_F + f];
    atomicAdd(&agg[(long long)dst * IN_F + f], m);
    if (f < EF) atomicAdd(&aggE[dst * EF + f], EA[e * EF + f]);
    if (f == 0) atomicAdd(&deg[dst], 1.0f);
}

// ========================= MFMA node-MLP path ===============================

// fused 2-layer MLP on MFMA:
//   h = relu(Ab @ W1 + b1);  out = h @ W2 + b2
// 64-row tile, 4 waves; wave w owns rows M0=16w..M0+15. A-tile + Wt in LDS
// (pitch 136 shorts: row stride 68 dwords -> only free 2-way bank aliasing).
// h written back into the wave-private sX region (C/D -> A layout transform),
// W buffer barrier-swapped W1t -> W2t.
#define XPITCH 136
__global__ __launch_bounds__(256) void mlp_mfma_kernel(
    const unsigned short* __restrict__ Ab,
    const unsigned short* __restrict__ W1t,
    const unsigned short* __restrict__ W2t,
    const float* __restrict__ b1, const float* __restrict__ b2,
    float* __restrict__ out, int N)
{
    __shared__ unsigned short sW[128 * XPITCH];   // 34816 B
    __shared__ unsigned short sX[64 * XPITCH];    // 17408 B
    const int t    = threadIdx.x;
    const int tile = blockIdx.x * 64;
    const int lane = t & 63;
    const int wv   = t >> 6;          // 0..3
    const int quad = lane >> 4;       // 0..3
    const int lr   = lane & 15;
    const int M0   = wv * 16;

    // stage A tile (64 rows x 16 uint4) and W1t (128 rows x 16 uint4); 17 uint4/row pitch
    {
        const uint4 z = make_uint4(0, 0, 0, 0);
        #pragma unroll
        for (int j = 0; j < 4; j++) {
            int idx = t + 256 * j;                 // 0..1023
            int row = idx >> 4, c = idx & 15;
            uint4 v = z;
            if (tile + row < N) v = ((const uint4*)Ab)[(long long)(tile + row) * 16 + c];
            ((uint4*)sX)[row * 17 + c] = v;
        }
        #pragma unroll
        for (int j = 0; j < 8; j++) {
            int idx = t + 256 * j;                 // 0..2047
            int row = idx >> 4, c = idx & 15;
            ((uint4*)sW)[row * 17 + c] = ((const uint4*)W1t)[idx];
        }
    }
    __syncthreads();

    f32x4 acc[8];
    bf16x8 af[4];
    const f32x4 zero = {0.f, 0.f, 0.f, 0.f};

    // phase 2: h = relu(A @ W1 + b1) -> sX rows M0..M0+15 (wave-private)
    #pragma unroll
    for (int kt = 0; kt < 4; kt++)
        af[kt] = *(const bf16x8*)&sX[(M0 + lr) * XPITCH + kt * 32 + quad * 8];
    #pragma unroll
    for (int nt = 0; nt < 8; nt++) {
        acc[nt] = zero;
        #pragma unroll
        for (int kt = 0; kt < 4; kt++) {
            bf16x8 bf = *(const bf16x8*)&sW[(nt * 16 + lr) * XPITCH + kt * 32 + quad * 8];
            acc[nt] = __builtin_amdgcn_mfma_f32_16x16x32_bf16(af[kt], bf, acc[nt], 0, 0, 0);
        }
    }
    #pragma unroll
    for (int nt = 0; nt < 8; nt++) {
        int col = nt * 16 + lr;
        float bias = b1[col];
        #pragma unroll
        for (int r = 0; r < 4; r++) {
            float v = fmaxf(acc[nt][r] + bias, 0.f);
            sX[(M0 + quad * 4 + r) * XPITCH + col] = f2b(v);
        }
    }
    __syncthreads();    // all waves done reading W1t
    #pragma unroll
    for (int j = 0; j < 8; j++) {
        int idx = t + 256 * j;
        int row = idx >> 4, c = idx & 15;
        ((uint4*)sW)[row * 17 + c] = ((const uint4*)W2t)[idx];
    }
    __syncthreads();

    // phase 3: out = h @ W2 + b2
    #pragma unroll
    for (int kt = 0; kt < 4; kt++)
        af[kt] = *(const bf16x8*)&sX[(M0 + lr) * XPITCH + kt * 32 + quad * 8];
    #pragma unroll
    for (int nt = 0; nt < 8; nt++) {
        acc[nt] = zero;
        #pragma unroll
        for (int kt = 0; kt < 4; kt++) {
            bf16x8 bf = *(const bf16x8*)&sW[(nt * 16 + lr) * XPITCH + kt * 32 + quad * 8];
            acc[nt] = __builtin_amdgcn_mfma_f32_16x16x32_bf16(af[kt], bf, acc[nt], 0, 0, 0);
        }
    }
    #pragma unroll
    for (int nt = 0; nt < 8; nt++) {
        int col = nt * 16 + lr;
        float bias = b2[col];
        #pragma unroll
        for (int r = 0; r < 4; r++) {
            int row = tile + M0 + quad * 4 + r;
            if (row < N) out[(long long)row * IN_F + col] = acc[nt][r] + bias;
        }
    }
}

// ================== fp32 node MLP (fallback path only) ======================
__global__ __launch_bounds__(256) void node_mlp_kernel(
    float* agg_out,
    const float* __restrict__ aggE,
    const float* __restrict__ degf,
    const float* __restrict__ We, const float* __restrict__ be,
    const float* __restrict__ W1, const float* __restrict__ b1,
    const float* __restrict__ W2, const float* __restrict__ b2,
    int N)
{
    __shared__ float sA[32][IN_F];
    __shared__ float sH[32][IN_F];
    const int t  = threadIdx.x;
    const int c4 = (t & 31) * 4;
    const int r0 = t >> 5;

    const int tile = blockIdx.x * 32;
    if (tile >= N) return;
    int rows = N - tile;
    if (rows > 32) rows = 32;

    {
        const float4 bev = *(const float4*)&be[c4];
        #pragma unroll
        for (int i = 0; i < 4; i++) {
            int rr = r0 + 8 * i;
            float4 v = make_float4(0.f, 0.f, 0.f, 0.f);
            if (rr < rows) {
                long long r = tile + rr;
                v = *(const float4*)&agg_out[r * IN_F + c4];
                float d = degf[r];
                v.x += d * bev.x; v.y += d * bev.y; v.z += d * bev.z; v.w += d * bev.w;
                #pragma unroll
                for (int k = 0; k < EF; k++) {
                    float a = aggE[r * EF + k];
                    float4 w = *(const float4*)&We[k * IN_F + c4];
                    v.x += a * w.x; v.y += a * w.y; v.z += a * w.z; v.w += a * w.w;
                }
            }
            *(float4*)&sA[rr][c4] = v;
        }
    }
    __syncthreads();
    {
        const float4 bv = *(const float4*)&b1[c4];
        float4 a0 = bv, a1 = bv, a2 = bv, a3 = bv;
        for (int k = 0; k < IN_F; k++) {
            float4 w = *(const float4*)&W1[k * IN_F + c4];
            float x0 = sA[r0][k], x1 = sA[r0 + 8][k], x2 = sA[r0 + 16][k], x3 = sA[r0 + 24][k];
            a0.x += x0 * w.x; a0.y += x0 * w.y; a0.z += x0 * w.z; a0.w += x0 * w.w;
            a1.x += x1 * w.x; a1.y += x1 * w.y; a1.z += x1 * w.z; a1.w += x1 * w.w;
            a2.x += x2 * w.x; a2.y += x2 * w.y; a2.z += x2 * w.z; a2.w += x2 * w.w;
            a3.x += x3 * w.x; a3.y += x3 * w.y; a3.z += x3 * w.z; a3.w += x3 * w.w;
        }
        a0.x = fmaxf(a0.x, 0.f); a0.y = fmaxf(a0.y, 0.f); a0.z = fmaxf(a0.z, 0.f); a0.w = fmaxf(a0.w, 0.f);
        a1.x = fmaxf(a1.x, 0.f); a1.y = fmaxf(a1.y, 0.f); a1.z = fmaxf(a1.z, 0.f); a1.w = fmaxf(a1.w, 0.f);
        a2.x = fmaxf(a2.x, 0.f); a2.y = fmaxf(a2.y, 0.f); a2.z = fmaxf(a2.z, 0.f); a2.w = fmaxf(a2.w, 0.f);
        a3.x = fmaxf(a3.x, 0.f); a3.y = fmaxf(a3.y, 0.f); a3.z = fmaxf(a3.z, 0.f); a3.w = fmaxf(a3.w, 0.f);
        *(float4*)&sH[r0][c4]      = a0;
        *(float4*)&sH[r0 + 8][c4]  = a1;
        *(float4*)&sH[r0 + 16][c4] = a2;
        *(float4*)&sH[r0 + 24][c4] = a3;
    }
    __syncthreads();
    {
        const float4 bv = *(const float4*)&b2[c4];
        float4 a0 = bv, a1 = bv, a2 = bv, a3 = bv;
        for (int k = 0; k < IN_F; k++) {
            float4 w = *(const float4*)&W2[k * IN_F + c4];
            float x0 = sH[r0][k], x1 = sH[r0 + 8][k], x2 = sH[r0 + 16][k], x3 = sH[r0 + 24][k];
            a0.x += x0 * w.x; a0.y += x0 * w.y; a0.z += x0 * w.z; a0.w += x0 * w.w;
            a1.x += x1 * w.x; a1.y += x1 * w.y; a1.z += x1 * w.z; a1.w += x1 * w.w;
            a2.x += x2 * w.x; a2.y += x2 * w.y; a2.z += x2 * w.z; a2.w += x2 * w.w;
            a3.x += x3 * w.x; a3.y += x3 * w.y; a3.z += x3 * w.z; a3.w += x3 * w.w;
        }
        #pragma unroll
        for (int i = 0; i < 4; i++) {
            int rr = r0 + 8 * i;
            if (rr < rows) {
                float4 v = (i == 0) ? a0 : (i == 1) ? a1 : (i == 2) ? a2 : a3;
                *(float4*)&agg_out[(long long)(tile + rr) * IN_F + c4] = v;
            }
        }
    }
}

// ================================ host ======================================
extern "C" void kernel_launch(void* const* d_in, const int* in_sizes, int n_in,
                              void* d_out, int out_size, void* d_ws, size_t ws_size,
                              hipStream_t stream) {
    const float* H  = (const float*)d_in[0];
    const int*   ei = (const int*)d_in[1];     // int32 [2,E]
    const float* EA = (const float*)d_in[2];
    const float* We = (const float*)d_in[3];
    const float* be = (const float*)d_in[4];
    const float* W1 = (const float*)d_in[5];
    const float* b1 = (const float*)d_in[6];
    const float* W2 = (const float*)d_in[7];
    const float* b2 = (const float*)d_in[8];
    float* out = (float*)d_out;

    const int N = in_sizes[0] / IN_F;
    const int E = in_sizes[2] / EF;

    char* p = (char*)d_ws;
    auto alloc = [&](size_t bytes) { char* r = p; p += (bytes + 255) & ~(size_t)255; return r; };
    int2*  sorted   = (int2*)alloc((size_t)E * sizeof(int2));   // fast path aliases sorted_src
    int*   sorted_src = (int*)sorted;
    int*   rank     = (int*)alloc((size_t)E * sizeof(int));
    float* degf     = (float*)alloc((size_t)N * sizeof(float));
    float* aggE     = (float*)alloc((size_t)N * EF * sizeof(float));   // adjacent to counts:
    int*   counts   = (int*)alloc((size_t)(N + 1) * sizeof(int));      // one memset covers both
    int*   offsets  = (int*)alloc((size_t)(N + 1) * sizeof(int));
    int*   partials = (int*)alloc(1024 * sizeof(int));
    size_t need_base = (size_t)(p - (char*)d_ws);
    unsigned short* Hb = (unsigned short*)alloc((size_t)N * IN_F * sizeof(unsigned short));
    unsigned short* Ab  = (unsigned short*)alloc((size_t)N * IN_F * sizeof(unsigned short));
    unsigned short* W1t = (unsigned short*)alloc((size_t)IN_F * IN_F * sizeof(unsigned short));
    unsigned short* W2t = (unsigned short*)alloc((size_t)IN_F * IN_F * sizeof(unsigned short));
    size_t need_mfma = (size_t)(p - (char*)d_ws);

    const int n_scan = N + 1;
    const int B = (n_scan + 1023) / 1024;
    const size_t zero_bytes = (size_t)((char*)offsets - (char*)aggE);  // aggE + counts

    if (ws_size >= need_mfma && B <= 1024) {
        // fast path: 6 dispatches + 1 memset
        hipMemsetAsync(aggE, 0, zero_bytes, stream);
        const int n4 = N * IN_F / 4;
        const int h2b_blocks  = (n4 + 255) / 256;
        const int hist_blocks = (E + 255) / 256;
        const long long ea_items = (long long)E * EF;
        const int ea_blocks = (int)((ea_items + 255) / 256);
        pre_kernel<<<h2b_blocks + hist_blocks + 128 + ea_blocks, 256, 0, stream>>>(
            H, Hb, n4, ei, counts, rank, E, W1, W1t, W2, W2t, EA, aggE,
            h2b_blocks, hist_blocks);
        scan_blocks_kernel<<<B, 256, 0, stream>>>(counts, offsets, partials, n_scan);
        scan_add_fused_kernel<<<(n_scan + 255) / 256, 256, 0, stream>>>(offsets, partials, n_scan);
        build_src_kernel<<<(E + 255) / 256, 256, 0, stream>>>(ei, offsets, rank, sorted_src, E);
        gather_agg_kernel<<<(N + 3) / 4, 256, 0, stream>>>(
            Hb, sorted_src, offsets, aggE, We, be, Ab, N);
        mlp_mfma_kernel<<<(N + 63) / 64, 256, 0, stream>>>(Ab, W1t, W2t, b1, b2, out, N);
    } else if (ws_size >= need_base && B <= 1024) {
        // fp32 CSR fallback
        hipMemsetAsync(counts, 0, (size_t)(N + 1) * sizeof(int), stream);
        hist_kernel<<<(E + 255) / 256, 256, 0, stream>>>(ei, counts, rank, E);
        scan_blocks_kernel<<<B, 256, 0, stream>>>(counts, offsets, partials, n_scan);
        scan_add_fused_kernel<<<(n_scan + 255) / 256, 256, 0, stream>>>(offsets, partials, n_scan);
        build_kernel<<<(E + 255) / 256, 256, 0, stream>>>(ei, sorted, offsets, rank, E);
        gather_f32_kernel<<<(N + 3) / 4, 256, 0, stream>>>(H, EA, sorted, offsets, out, aggE, degf, N);
        node_mlp_kernel<<<(N + 31) / 32, 256, 0, stream>>>(out, aggE, degf, We, be, W1, b1, W2, b2, N);
    } else {
        // atomic-scatter fallback
        float* f_aggE = (float*)d_ws;
        float* f_deg  = f_aggE + (size_t)N * EF;
        hipMemsetAsync(d_out, 0, (size_t)N * IN_F * sizeof(float), stream);
        hipMemsetAsync(d_ws, 0, (size_t)N * (EF + 1) * sizeof(float), stream);
        long long tot = (long long)E * IN_F;
        edge_scatter_kernel<<<(int)((tot + 255) / 256), 256, 0, stream>>>(H, ei, EA, out, f_aggE, f_deg, E);
        node_mlp_kernel<<<(N + 31) / 32, 256, 0, stream>>>(out, f_aggE, f_deg, We, be, W1, b1, W2, b2, N);
    }
}

// Round 5
// 491.773 us; speedup vs baseline: 1.0524x; 1.0145x over previous
//
#include <hip/hip_runtime.h>

#define IN_F 128
#define EF 16

typedef short bf16x8 __attribute__((ext_vector_type(8)));
typedef float f32x4  __attribute__((ext_vector_type(4)));

// bf16 helpers: pack is RNE; unpack low/high halves of a uint holding 2 bf16
__device__ __forceinline__ unsigned short f2b(float f) {
    unsigned b = __float_as_uint(f);
    b += 0x7fffu + ((b >> 16) & 1u);
    return (unsigned short)(b >> 16);
}
__device__ __forceinline__ float blo(unsigned u) { return __uint_as_float(u << 16); }
__device__ __forceinline__ float bhi(unsigned u) { return __uint_as_float(u & 0xffff0000u); }

// ============================ CSR-build path ================================

// fused pre-pass: h2b cast + dst histogram (recording per-edge rank) +
// W1/W2 transpose-cast. all mutually independent, all precede the scan.
// NOTE: no EA work here — EA is reduced atomic-free post-build (ea_reduce).
__global__ __launch_bounds__(256) void pre_kernel(
    const float* __restrict__ H, unsigned short* __restrict__ Hb, int n4,
    const int* __restrict__ ei, int* __restrict__ counts,
    int* __restrict__ rank, int E,
    const float* __restrict__ W1, unsigned short* __restrict__ W1t,
    const float* __restrict__ W2, unsigned short* __restrict__ W2t,
    int h2b_blocks, int hist_blocks)
{
    int b = blockIdx.x;
    if (b < h2b_blocks) {
        int i = b * 256 + threadIdx.x;
        if (i < n4) {
            float4 v = ((const float4*)H)[i];
            ushort4 r;
            r.x = f2b(v.x); r.y = f2b(v.y); r.z = f2b(v.z); r.w = f2b(v.w);
            ((ushort4*)Hb)[i] = r;
        }
    } else if (b < h2b_blocks + hist_blocks) {
        int e = (b - h2b_blocks) * 256 + threadIdx.x;
        if (e < E) rank[e] = atomicAdd(&counts[ei[E + e]], 1);
    } else {
        int idx = (b - h2b_blocks - hist_blocks) * 256 + threadIdx.x; // 0..32767
        int w = idx >> 14;           // 0: W1, 1: W2
        int r = idx & 16383;
        int n = r >> 7, k = r & 127;
        if (w == 0) W1t[n * IN_F + k] = f2b(W1[k * IN_F + n]);
        else        W2t[n * IN_F + k] = f2b(W2[k * IN_F + n]);
    }
}

// standalone hist (fp32 CSR fallback path) — also records rank
__global__ __launch_bounds__(256) void hist_kernel(
    const int* __restrict__ ei, int* __restrict__ counts,
    int* __restrict__ rank, int E)
{
    int e = blockIdx.x * 256 + threadIdx.x;
    if (e >= E) return;
    rank[e] = atomicAdd(&counts[ei[E + e]], 1);
}

__global__ __launch_bounds__(256) void scan_blocks_kernel(
    const int* __restrict__ in, int* __restrict__ out,
    int* __restrict__ partials, int n)
{
    __shared__ int sdata[256];
    const int t = threadIdx.x;
    const int idx0 = blockIdx.x * 1024 + t * 4;
    int v[4];
    #pragma unroll
    for (int i = 0; i < 4; i++) { int idx = idx0 + i; v[i] = (idx < n) ? in[idx] : 0; }
    int s = v[0] + v[1] + v[2] + v[3];
    sdata[t] = s;
    __syncthreads();
    for (int off = 1; off < 256; off <<= 1) {
        int x = (t >= off) ? sdata[t - off] : 0;
        __syncthreads();
        sdata[t] += x;
        __syncthreads();
    }
    if (t == 255) partials[blockIdx.x] = sdata[255];
    int run = (t > 0) ? sdata[t - 1] : 0;
    #pragma unroll
    for (int i = 0; i < 4; i++) {
        int idx = idx0 + i;
        if (idx < n) out[idx] = run;
        run += v[i];
    }
}

// scan_add with the partial-prefix computed in-block: every index in a
// 256-thread block shares one 1024-group g = blockIdx>>2, so the block needs
// exactly sum(partials[0..g-1]) — reduce it here, kill scan_partials dispatch.
__global__ __launch_bounds__(256) void scan_add_fused_kernel(
    int* __restrict__ out, const int* __restrict__ partials, int n)
{
    __shared__ int sw[4];
    const int t = threadIdx.x;
    const int g = blockIdx.x >> 2;
    int v = 0;
    for (int j = t; j < g; j += 256) v += partials[j];
    #pragma unroll
    for (int off = 1; off < 64; off <<= 1) v += __shfl_xor(v, off, 64);
    if ((t & 63) == 0) sw[t >> 6] = v;
    __syncthreads();
    int P = sw[0] + sw[1] + sw[2] + sw[3];
    int idx = blockIdx.x * 256 + t;
    if (idx < n) out[idx] += P;
}

// build: pos = offsets[dst] + rank[e]; scatter (src, e) — no atomics
__global__ __launch_bounds__(256) void build_kernel(
    const int* __restrict__ ei, int2* __restrict__ sorted,
    const int* __restrict__ offsets, const int* __restrict__ rank, int E)
{
    int e = blockIdx.x * 256 + threadIdx.x;
    if (e >= E) return;
    int src = ei[e];
    int dst = ei[E + e];
    int pos = offsets[dst] + rank[e];
    sorted[pos] = make_int2(src, e);
}

// ea_reduce: atomic-free EA segment-sum. One wave per node; 4 edge slots x
// 16 feats per iteration — each edge's 16 lanes read one aligned 64B EA row
// (clean random-row fetch, zero overfetch), reduce across slots via shfl.
__global__ __launch_bounds__(256) void ea_reduce_kernel(
    const float* __restrict__ EA,
    const int2* __restrict__ sorted,
    const int* __restrict__ offsets,
    float* __restrict__ aggE,          // [N,16]
    int N)
{
    int n = blockIdx.x * 4 + (threadIdx.x >> 6);
    if (n >= N) return;
    int lane = threadIdx.x & 63;
    int sub  = lane >> 4;      // 0..3 edge slot
    int f    = lane & 15;
    int s = offsets[n];
    int e_end = offsets[n + 1];
    float acc = 0.f;
    int i = s + sub;
    for (; i + 4 < e_end; i += 8) {      // 2 edges/slot in flight
        int e0 = sorted[i].y;
        int e1 = sorted[i + 4].y;
        float v0 = EA[(long long)e0 * EF + f];
        float v1 = EA[(long long)e1 * EF + f];
        acc += v0 + v1;
    }
    for (; i < e_end; i += 4) {
        int e0 = sorted[i].y;
        acc += EA[(long long)e0 * EF + f];
    }
    acc += __shfl_xor(acc, 16, 64);
    acc += __shfl_xor(acc, 32, 64);
    if (sub == 0) aggE[n * EF + f] = acc;
}

// gather (bf16 H, aggE precomputed):
// one wave per node; half-waves each own one edge slot (stride 2); lane covers
// feats [4*l32 .. 4*l32+3] via one 8B load (coalesced 256B per row).
// Only sorted (stream) + Hb (random, L3-resident) are touched in the loop.
// Epilogue: a = agg + deg*be + aggE @ We in-register -> Ab (bf16).
__global__ __launch_bounds__(256) void gather_agg_kernel(
    const unsigned short* __restrict__ Hb,
    const int2* __restrict__ sorted,
    const int* __restrict__ offsets,
    const float* __restrict__ aggE,
    const float* __restrict__ We,
    const float* __restrict__ be,
    unsigned short* __restrict__ Ab,    // [N,128] bf16
    int N)
{
    int n = blockIdx.x * 4 + (threadIdx.x >> 6);
    if (n >= N) return;
    int lane = threadIdx.x & 63;
    int half = lane >> 5;
    int l32  = lane & 31;
    int s = offsets[n];
    int e_end = offsets[n + 1];
    float a0 = 0.f, a1 = 0.f, a2 = 0.f, a3 = 0.f;
    int i = s + half;
    for (; i + 6 < e_end; i += 8) {
        int s0 = sorted[i].x;
        int s1 = sorted[i + 2].x;
        int s2 = sorted[i + 4].x;
        int s3 = sorted[i + 6].x;
        uint2 u0 = *(const uint2*)(Hb + (long long)s0 * IN_F + l32 * 4);
        uint2 u1 = *(const uint2*)(Hb + (long long)s1 * IN_F + l32 * 4);
        uint2 u2 = *(const uint2*)(Hb + (long long)s2 * IN_F + l32 * 4);
        uint2 u3 = *(const uint2*)(Hb + (long long)s3 * IN_F + l32 * 4);
        a0 += (blo(u0.x) + blo(u1.x)) + (blo(u2.x) + blo(u3.x));
        a1 += (bhi(u0.x) + bhi(u1.x)) + (bhi(u2.x) + bhi(u3.x));
        a2 += (blo(u0.y) + blo(u1.y)) + (blo(u2.y) + blo(u3.y));
        a3 += (bhi(u0.y) + bhi(u1.y)) + (bhi(u2.y) + bhi(u3.y));
    }
    for (; i < e_end; i += 2) {
        int se = sorted[i].x;
        uint2 u = *(const uint2*)(Hb + (long long)se * IN_F + l32 * 4);
        a0 += blo(u.x); a1 += bhi(u.x); a2 += blo(u.y); a3 += bhi(u.y);
    }
    a0 += __shfl_xor(a0, 32, 64);
    a1 += __shfl_xor(a1, 32, 64);
    a2 += __shfl_xor(a2, 32, 64);
    a3 += __shfl_xor(a3, 32, 64);

    // fused prep: v = agg + deg*be + aggE @ We (aggE reads are wave-uniform)
    const int c4 = l32 * 4;
    const float deg = (float)(e_end - s);
    float4 bev = *(const float4*)&be[c4];
    float vx = a0 + deg * bev.x;
    float vy = a1 + deg * bev.y;
    float vz = a2 + deg * bev.z;
    float vw = a3 + deg * bev.w;
    #pragma unroll
    for (int k = 0; k < EF; k++) {
        float ak = aggE[n * EF + k];
        float4 w = *(const float4*)&We[k * IN_F + c4];
        vx += ak * w.x; vy += ak * w.y; vz += ak * w.z; vw += ak * w.w;
    }
    if (half == 0) {
        ushort4 o;
        o.x = f2b(vx); o.y = f2b(vy); o.z = f2b(vz); o.w = f2b(vw);
        *(ushort4*)&Ab[(long long)n * IN_F + c4] = o;
    }
}

// gather (fp32 H) fallback — writes agg/aggE/deg for node_mlp path
__global__ __launch_bounds__(256) void gather_f32_kernel(
    const float* __restrict__ H,
    const float* __restrict__ EA,
    const int2* __restrict__ sorted,
    const int* __restrict__ offsets,
    float* __restrict__ agg,
    float* __restrict__ aggE,
    float* __restrict__ degf,
    int N)
{
    int n = blockIdx.x * 4 + (threadIdx.x >> 6);
    if (n >= N) return;
    int lane = threadIdx.x & 63;
    int half = lane >> 5;
    int l32  = lane & 31;
    int s = offsets[n];
    int e_end = offsets[n + 1];
    float4 acc = make_float4(0.f, 0.f, 0.f, 0.f);
    float accE = 0.f;
    int i = s + half;
    for (; i + 6 < e_end; i += 8) {
        int2 s0 = sorted[i];
        int2 s1 = sorted[i + 2];
        int2 s2 = sorted[i + 4];
        int2 s3 = sorted[i + 6];
        float4 v0 = *(const float4*)(H + (long long)s0.x * IN_F + l32 * 4);
        float4 v1 = *(const float4*)(H + (long long)s1.x * IN_F + l32 * 4);
        float4 v2 = *(const float4*)(H + (long long)s2.x * IN_F + l32 * 4);
        float4 v3 = *(const float4*)(H + (long long)s3.x * IN_F + l32 * 4);
        float e0 = 0.f, e1 = 0.f, e2 = 0.f, e3 = 0.f;
        if (l32 < EF) {
            e0 = EA[(long long)s0.y * EF + l32];
            e1 = EA[(long long)s1.y * EF + l32];
            e2 = EA[(long long)s2.y * EF + l32];
            e3 = EA[(long long)s3.y * EF + l32];
        }
        acc.x += (v0.x + v1.x) + (v2.x + v3.x);
        acc.y += (v0.y + v1.y) + (v2.y + v3.y);
        acc.z += (v0.z + v1.z) + (v2.z + v3.z);
        acc.w += (v0.w + v1.w) + (v2.w + v3.w);
        accE  += (e0 + e1) + (e2 + e3);
    }
    for (; i < e_end; i += 2) {
        int2 se = sorted[i];
        float4 v = *(const float4*)(H + (long long)se.x * IN_F + l32 * 4);
        acc.x += v.x; acc.y += v.y; acc.z += v.z; acc.w += v.w;
        if (l32 < EF) accE += EA[(long long)se.y * EF + l32];
    }
    acc.x += __shfl_xor(acc.x, 32, 64);
    acc.y += __shfl_xor(acc.y, 32, 64);
    acc.z += __shfl_xor(acc.z, 32, 64);
    acc.w += __shfl_xor(acc.w, 32, 64);
    accE  += __shfl_xor(accE, 32, 64);
    if (half == 0) {
        *(float4*)(agg + (long long)n * IN_F + l32 * 4) = acc;
        if (l32 < EF) aggE[n * EF + l32] = accE;
        if (l32 == 0) degf[n] = (float)(e_end - s);
    }
}

// ======================= fallback: atomic scatter ===========================
__global__ __launch_bounds__(256) void edge_scatter_kernel(
    const float* __restrict__ H,
    const int* __restrict__ ei,
    const float* __restrict__ EA,
    float* __restrict__ agg,
    float* __restrict__ aggE,
    float* __restrict__ deg,
    int E)
{
    long long gid = (long long)blockIdx.x * 256 + threadIdx.x;
    int e = (int)(gid >> 7);
    if (e >= E) return;
    int f = (int)(gid & 127);
    int src = ei[e];
    int dst = ei[E + e];
    float m = H[(long long)src * IN_F + f];
    atomicAdd(&agg[(long long)dst * IN_F + f], m);
    if (f < EF) atomicAdd(&aggE[dst * EF + f], EA[e * EF + f]);
    if (f == 0) atomicAdd(&deg[dst], 1.0f);
}

// ========================= MFMA node-MLP path ===============================

// fused 2-layer MLP on MFMA:
//   h = relu(Ab @ W1 + b1);  out = h @ W2 + b2
// 64-row tile, 4 waves; wave w owns rows M0=16w..M0+15. A-tile + Wt in LDS
// (pitch 136 shorts: row stride 68 dwords -> only free 2-way bank aliasing).
// h written back into the wave-private sX region (C/D -> A layout transform),
// W buffer barrier-swapped W1t -> W2t.
#define XPITCH 136
__global__ __launch_bounds__(256) void mlp_mfma_kernel(
    const unsigned short* __restrict__ Ab,
    const unsigned short* __restrict__ W1t,
    const unsigned short* __restrict__ W2t,
    const float* __restrict__ b1, const float* __restrict__ b2,
    float* __restrict__ out, int N)
{
    __shared__ unsigned short sW[128 * XPITCH];   // 34816 B
    __shared__ unsigned short sX[64 * XPITCH];    // 17408 B
    const int t    = threadIdx.x;
    const int tile = blockIdx.x * 64;
    const int lane = t & 63;
    const int wv   = t >> 6;          // 0..3
    const int quad = lane >> 4;       // 0..3
    const int lr   = lane & 15;
    const int M0   = wv * 16;

    // stage A tile (64 rows x 16 uint4) and W1t (128 rows x 16 uint4); 17 uint4/row pitch
    {
        const uint4 z = make_uint4(0, 0, 0, 0);
        #pragma unroll
        for (int j = 0; j < 4; j++) {
            int idx = t + 256 * j;                 // 0..1023
            int row = idx >> 4, c = idx & 15;
            uint4 v = z;
            if (tile + row < N) v = ((const uint4*)Ab)[(long long)(tile + row) * 16 + c];
            ((uint4*)sX)[row * 17 + c] = v;
        }
        #pragma unroll
        for (int j = 0; j < 8; j++) {
            int idx = t + 256 * j;                 // 0..2047
            int row = idx >> 4, c = idx & 15;
            ((uint4*)sW)[row * 17 + c] = ((const uint4*)W1t)[idx];
        }
    }
    __syncthreads();

    f32x4 acc[8];
    bf16x8 af[4];
    const f32x4 zero = {0.f, 0.f, 0.f, 0.f};

    // phase 2: h = relu(A @ W1 + b1) -> sX rows M0..M0+15 (wave-private)
    #pragma unroll
    for (int kt = 0; kt < 4; kt++)
        af[kt] = *(const bf16x8*)&sX[(M0 + lr) * XPITCH + kt * 32 + quad * 8];
    #pragma unroll
    for (int nt = 0; nt < 8; nt++) {
        acc[nt] = zero;
        #pragma unroll
        for (int kt = 0; kt < 4; kt++) {
            bf16x8 bf = *(const bf16x8*)&sW[(nt * 16 + lr) * XPITCH + kt * 32 + quad * 8];
            acc[nt] = __builtin_amdgcn_mfma_f32_16x16x32_bf16(af[kt], bf, acc[nt], 0, 0, 0);
        }
    }
    #pragma unroll
    for (int nt = 0; nt < 8; nt++) {
        int col = nt * 16 + lr;
        float bias = b1[col];
        #pragma unroll
        for (int r = 0; r < 4; r++) {
            float v = fmaxf(acc[nt][r] + bias, 0.f);
            sX[(M0 + quad * 4 + r) * XPITCH + col] = f2b(v);
        }
    }
    __syncthreads();    // all waves done reading W1t
    #pragma unroll
    for (int j = 0; j < 8; j++) {
        int idx = t + 256 * j;
        int row = idx >> 4, c = idx & 15;
        ((uint4*)sW)[row * 17 + c] = ((const uint4*)W2t)[idx];
    }
    __syncthreads();

    // phase 3: out = h @ W2 + b2
    #pragma unroll
    for (int kt = 0; kt < 4; kt++)
        af[kt] = *(const bf16x8*)&sX[(M0 + lr) * XPITCH + kt * 32 + quad * 8];
    #pragma unroll
    for (int nt = 0; nt < 8; nt++) {
        acc[nt] = zero;
        #pragma unroll
        for (int kt = 0; kt < 4; kt++) {
            bf16x8 bf = *(const bf16x8*)&sW[(nt * 16 + lr) * XPITCH + kt * 32 + quad * 8];
            acc[nt] = __builtin_amdgcn_mfma_f32_16x16x32_bf16(af[kt], bf, acc[nt], 0, 0, 0);
        }
    }
    #pragma unroll
    for (int nt = 0; nt < 8; nt++) {
        int col = nt * 16 + lr;
        float bias = b2[col];
        #pragma unroll
        for (int r = 0; r < 4; r++) {
            int row = tile + M0 + quad * 4 + r;
            if (row < N) out[(long long)row * IN_F + col] = acc[nt][r] + bias;
        }
    }
}

// ================== fp32 node MLP (fallback path only) ======================
__global__ __launch_bounds__(256) void node_mlp_kernel(
    float* agg_out,
    const float* __restrict__ aggE,
    const float* __restrict__ degf,
    const float* __restrict__ We, const float* __restrict__ be,
    const float* __restrict__ W1, const float* __restrict__ b1,
    const float* __restrict__ W2, const float* __restrict__ b2,
    int N)
{
    __shared__ float sA[32][IN_F];
    __shared__ float sH[32][IN_F];
    const int t  = threadIdx.x;
    const int c4 = (t & 31) * 4;
    const int r0 = t >> 5;

    const int tile = blockIdx.x * 32;
    if (tile >= N) return;
    int rows = N - tile;
    if (rows > 32) rows = 32;

    {
        const float4 bev = *(const float4*)&be[c4];
        #pragma unroll
        for (int i = 0; i < 4; i++) {
            int rr = r0 + 8 * i;
            float4 v = make_float4(0.f, 0.f, 0.f, 0.f);
            if (rr < rows) {
                long long r = tile + rr;
                v = *(const float4*)&agg_out[r * IN_F + c4];
                float d = degf[r];
                v.x += d * bev.x; v.y += d * bev.y; v.z += d * bev.z; v.w += d * bev.w;
                #pragma unroll
                for (int k = 0; k < EF; k++) {
                    float a = aggE[r * EF + k];
                    float4 w = *(const float4*)&We[k * IN_F + c4];
                    v.x += a * w.x; v.y += a * w.y; v.z += a * w.z; v.w += a * w.w;
                }
            }
            *(float4*)&sA[rr][c4] = v;
        }
    }
    __syncthreads();
    {
        const float4 bv = *(const float4*)&b1[c4];
        float4 a0 = bv, a1 = bv, a2 = bv, a3 = bv;
        for (int k = 0; k < IN_F; k++) {
            float4 w = *(const float4*)&W1[k * IN_F + c4];
            float x0 = sA[r0][k], x1 = sA[r0 + 8][k], x2 = sA[r0 + 16][k], x3 = sA[r0 + 24][k];
            a0.x += x0 * w.x; a0.y += x0 * w.y; a0.z += x0 * w.z; a0.w += x0 * w.w;
            a1.x += x1 * w.x; a1.y += x1 * w.y; a1.z += x1 * w.z; a1.w += x1 * w.w;
            a2.x += x2 * w.x; a2.y += x2 * w.y; a2.z += x2 * w.z; a2.w += x2 * w.w;
            a3.x += x3 * w.x; a3.y += x3 * w.y; a3.z += x3 * w.z; a3.w += x3 * w.w;
        }
        a0.x = fmaxf(a0.x, 0.f); a0.y = fmaxf(a0.y, 0.f); a0.z = fmaxf(a0.z, 0.f); a0.w = fmaxf(a0.w, 0.f);
        a1.x = fmaxf(a1.x, 0.f); a1.y = fmaxf(a1.y, 0.f); a1.z = fmaxf(a1.z, 0.f); a1.w = fmaxf(a1.w, 0.f);
        a2.x = fmaxf(a2.x, 0.f); a2.y = fmaxf(a2.y, 0.f); a2.z = fmaxf(a2.z, 0.f); a2.w = fmaxf(a2.w, 0.f);
        a3.x = fmaxf(a3.x, 0.f); a3.y = fmaxf(a3.y, 0.f); a3.z = fmaxf(a3.z, 0.f); a3.w = fmaxf(a3.w, 0.f);
        *(float4*)&sH[r0][c4]      = a0;
        *(float4*)&sH[r0 + 8][c4]  = a1;
        *(float4*)&sH[r0 + 16][c4] = a2;
        *(float4*)&sH[r0 + 24][c4] = a3;
    }
    __syncthreads();
    {
        const float4 bv = *(const float4*)&b2[c4];
        float4 a0 = bv, a1 = bv, a2 = bv, a3 = bv;
        for (int k = 0; k < IN_F; k++) {
            float4 w = *(const float4*)&W2[k * IN_F + c4];
            float x0 = sH[r0][k], x1 = sH[r0 + 8][k], x2 = sH[r0 + 16][k], x3 = sH[r0 + 24][k];
            a0.x += x0 * w.x; a0.y += x0 * w.y; a0.z += x0 * w.z; a0.w += x0 * w.w;
            a1.x += x1 * w.x; a1.y += x1 * w.y; a1.z += x1 * w.z; a1.w += x1 * w.w;
            a2.x += x2 * w.x; a2.y += x2 * w.y; a2.z += x2 * w.z; a2.w += x2 * w.w;
            a3.x += x3 * w.x; a3.y += x3 * w.y; a3.z += x3 * w.z; a3.w += x3 * w.w;
        }
        #pragma unroll
        for (int i = 0; i < 4; i++) {
            int rr = r0 + 8 * i;
            if (rr < rows) {
                float4 v = (i == 0) ? a0 : (i == 1) ? a1 : (i == 2) ? a2 : a3;
                *(float4*)&agg_out[(long long)(tile + rr) * IN_F + c4] = v;
            }
        }
    }
}

// ================================ host ======================================
extern "C" void kernel_launch(void* const* d_in, const int* in_sizes, int n_in,
                              void* d_out, int out_size, void* d_ws, size_t ws_size,
                              hipStream_t stream) {
    const float* H  = (const float*)d_in[0];
    const int*   ei = (const int*)d_in[1];     // int32 [2,E]
    const float* EA = (const float*)d_in[2];
    const float* We = (const float*)d_in[3];
    const float* be = (const float*)d_in[4];
    const float* W1 = (const float*)d_in[5];
    const float* b1 = (const float*)d_in[6];
    const float* W2 = (const float*)d_in[7];
    const float* b2 = (const float*)d_in[8];
    float* out = (float*)d_out;

    const int N = in_sizes[0] / IN_F;
    const int E = in_sizes[2] / EF;

    char* p = (char*)d_ws;
    auto alloc = [&](size_t bytes) { char* r = p; p += (bytes + 255) & ~(size_t)255; return r; };
    int2*  sorted   = (int2*)alloc((size_t)E * sizeof(int2));
    int*   rank     = (int*)alloc((size_t)E * sizeof(int));
    float* degf     = (float*)alloc((size_t)N * sizeof(float));
    float* aggE     = (float*)alloc((size_t)N * EF * sizeof(float));
    int*   counts   = (int*)alloc((size_t)(N + 1) * sizeof(int));
    int*   offsets  = (int*)alloc((size_t)(N + 1) * sizeof(int));
    int*   partials = (int*)alloc(1024 * sizeof(int));
    size_t need_base = (size_t)(p - (char*)d_ws);
    unsigned short* Hb = (unsigned short*)alloc((size_t)N * IN_F * sizeof(unsigned short));
    unsigned short* Ab  = (unsigned short*)alloc((size_t)N * IN_F * sizeof(unsigned short));
    unsigned short* W1t = (unsigned short*)alloc((size_t)IN_F * IN_F * sizeof(unsigned short));
    unsigned short* W2t = (unsigned short*)alloc((size_t)IN_F * IN_F * sizeof(unsigned short));
    size_t need_mfma = (size_t)(p - (char*)d_ws);

    const int n_scan = N + 1;
    const int B = (n_scan + 1023) / 1024;

    if (ws_size >= need_mfma && B <= 1024) {
        // fast path: 7 dispatches + 1 memset
        hipMemsetAsync(counts, 0, (size_t)(N + 1) * sizeof(int), stream);
        const int n4 = N * IN_F / 4;
        const int h2b_blocks  = (n4 + 255) / 256;
        const int hist_blocks = (E + 255) / 256;
        pre_kernel<<<h2b_blocks + hist_blocks + 128, 256, 0, stream>>>(
            H, Hb, n4, ei, counts, rank, E, W1, W1t, W2, W2t, h2b_blocks, hist_blocks);
        scan_blocks_kernel<<<B, 256, 0, stream>>>(counts, offsets, partials, n_scan);
        scan_add_fused_kernel<<<(n_scan + 255) / 256, 256, 0, stream>>>(offsets, partials, n_scan);
        build_kernel<<<(E + 255) / 256, 256, 0, stream>>>(ei, sorted, offsets, rank, E);
        ea_reduce_kernel<<<(N + 3) / 4, 256, 0, stream>>>(EA, sorted, offsets, aggE, N);
        gather_agg_kernel<<<(N + 3) / 4, 256, 0, stream>>>(
            Hb, sorted, offsets, aggE, We, be, Ab, N);
        mlp_mfma_kernel<<<(N + 63) / 64, 256, 0, stream>>>(Ab, W1t, W2t, b1, b2, out, N);
    } else if (ws_size >= need_base && B <= 1024) {
        // fp32 CSR fallback
        hipMemsetAsync(counts, 0, (size_t)(N + 1) * sizeof(int), stream);
        hist_kernel<<<(E + 255) / 256, 256, 0, stream>>>(ei, counts, rank, E);
        scan_blocks_kernel<<<B, 256, 0, stream>>>(counts, offsets, partials, n_scan);
        scan_add_fused_kernel<<<(n_scan + 255) / 256, 256, 0, stream>>>(offsets, partials, n_scan);
        build_kernel<<<(E + 255) / 256, 256, 0, stream>>>(ei, sorted, offsets, rank, E);
        gather_f32_kernel<<<(N + 3) / 4, 256, 0, stream>>>(H, EA, sorted, offsets, out, aggE, degf, N);
        node_mlp_kernel<<<(N + 31) / 32, 256, 0, stream>>>(out, aggE, degf, We, be, W1, b1, W2, b2, N);
    } else {
        // atomic-scatter fallback
        float* f_aggE = (float*)d_ws;
        float* f_deg  = f_aggE + (size_t)N * EF;
        hipMemsetAsync(d_out, 0, (size_t)N * IN_F * sizeof(float), stream);
        hipMemsetAsync(d_ws, 0, (size_t)N * (EF + 1) * sizeof(float), stream);
        long long tot = (long long)E * IN_F;
        edge_scatter_kernel<<<(int)((tot + 255) / 256), 256, 0, stream>>>(H, ei, EA, out, f_aggE, f_deg, E);
        node_mlp_kernel<<<(N + 31) / 32, 256, 0, stream>>>(out, f_aggE, f_deg, We, be, W1, b1, W2, b2, N);
    }
}

// Round 6
// 487.215 us; speedup vs baseline: 1.0623x; 1.0094x over previous
//
#include <hip/hip_runtime.h>

#define IN_F 128
#define EF 16

typedef short bf16x8 __attribute__((ext_vector_type(8)));
typedef float f32x4  __attribute__((ext_vector_type(4)));

// bf16 helpers: pack is RNE; unpack low/high halves of a uint holding 2 bf16
__device__ __forceinline__ unsigned short f2b(float f) {
    unsigned b = __float_as_uint(f);
    b += 0x7fffu + ((b >> 16) & 1u);
    return (unsigned short)(b >> 16);
}
__device__ __forceinline__ float blo(unsigned u) { return __uint_as_float(u << 16); }
__device__ __forceinline__ float bhi(unsigned u) { return __uint_as_float(u & 0xffff0000u); }

// ============================ CSR-build path ================================

// fused pre-pass: h2b cast + dst histogram (recording per-edge rank) +
// W1/W2 transpose-cast + Wea = We@W1, bea = be@W1 (folds the edge-MLP
// correction into the node-MLP accumulator init — see mlp_mfma_kernel).
__global__ __launch_bounds__(256) void pre_kernel(
    const float* __restrict__ H, unsigned short* __restrict__ Hb, int n4,
    const int* __restrict__ ei, int* __restrict__ counts,
    int* __restrict__ rank, int E,
    const float* __restrict__ W1, unsigned short* __restrict__ W1t,
    const float* __restrict__ W2, unsigned short* __restrict__ W2t,
    const float* __restrict__ We, const float* __restrict__ be,
    float* __restrict__ Wea, float* __restrict__ bea,
    int h2b_blocks, int hist_blocks)
{
    int b = blockIdx.x;
    if (b < h2b_blocks) {
        int i = b * 256 + threadIdx.x;
        if (i < n4) {
            float4 v = ((const float4*)H)[i];
            ushort4 r;
            r.x = f2b(v.x); r.y = f2b(v.y); r.z = f2b(v.z); r.w = f2b(v.w);
            ((ushort4*)Hb)[i] = r;
        }
    } else if (b < h2b_blocks + hist_blocks) {
        int e = (b - h2b_blocks) * 256 + threadIdx.x;
        if (e < E) rank[e] = atomicAdd(&counts[ei[E + e]], 1);
    } else if (b < h2b_blocks + hist_blocks + 128) {
        int idx = (b - h2b_blocks - hist_blocks) * 256 + threadIdx.x; // 0..32767
        int w = idx >> 14;           // 0: W1, 1: W2
        int r = idx & 16383;
        int n = r >> 7, k = r & 127;
        if (w == 0) W1t[n * IN_F + k] = f2b(W1[k * IN_F + n]);
        else        W2t[n * IN_F + k] = f2b(W2[k * IN_F + n]);
    } else {
        // Wea[k][n] = sum_j We[k][j]*W1[j][n];  bea[n] = sum_j be[j]*W1[j][n]
        int idx = (b - h2b_blocks - hist_blocks - 128) * 256 + threadIdx.x; // 0..2303
        if (idx < EF * IN_F) {
            int k = idx >> 7, n = idx & 127;
            float acc = 0.f;
            for (int j = 0; j < IN_F; j++) acc += We[k * IN_F + j] * W1[j * IN_F + n];
            Wea[k * IN_F + n] = acc;
        } else if (idx < EF * IN_F + IN_F) {
            int n = idx - EF * IN_F;
            float acc = 0.f;
            for (int j = 0; j < IN_F; j++) acc += be[j] * W1[j * IN_F + n];
            bea[n] = acc;
        }
    }
}

// standalone hist (fp32 CSR fallback path) — also records rank
__global__ __launch_bounds__(256) void hist_kernel(
    const int* __restrict__ ei, int* __restrict__ counts,
    int* __restrict__ rank, int E)
{
    int e = blockIdx.x * 256 + threadIdx.x;
    if (e >= E) return;
    rank[e] = atomicAdd(&counts[ei[E + e]], 1);
}

__global__ __launch_bounds__(256) void scan_blocks_kernel(
    const int* __restrict__ in, int* __restrict__ out,
    int* __restrict__ partials, int n)
{
    __shared__ int sdata[256];
    const int t = threadIdx.x;
    const int idx0 = blockIdx.x * 1024 + t * 4;
    int v[4];
    #pragma unroll
    for (int i = 0; i < 4; i++) { int idx = idx0 + i; v[i] = (idx < n) ? in[idx] : 0; }
    int s = v[0] + v[1] + v[2] + v[3];
    sdata[t] = s;
    __syncthreads();
    for (int off = 1; off < 256; off <<= 1) {
        int x = (t >= off) ? sdata[t - off] : 0;
        __syncthreads();
        sdata[t] += x;
        __syncthreads();
    }
    if (t == 255) partials[blockIdx.x] = sdata[255];
    int run = (t > 0) ? sdata[t - 1] : 0;
    #pragma unroll
    for (int i = 0; i < 4; i++) {
        int idx = idx0 + i;
        if (idx < n) out[idx] = run;
        run += v[i];
    }
}

// scan_add with the partial-prefix computed in-block
__global__ __launch_bounds__(256) void scan_add_fused_kernel(
    int* __restrict__ out, const int* __restrict__ partials, int n)
{
    __shared__ int sw[4];
    const int t = threadIdx.x;
    const int g = blockIdx.x >> 2;
    int v = 0;
    for (int j = t; j < g; j += 256) v += partials[j];
    #pragma unroll
    for (int off = 1; off < 64; off <<= 1) v += __shfl_xor(v, off, 64);
    if ((t & 63) == 0) sw[t >> 6] = v;
    __syncthreads();
    int P = sw[0] + sw[1] + sw[2] + sw[3];
    int idx = blockIdx.x * 256 + t;
    if (idx < n) out[idx] += P;
}

// build: pos = offsets[dst] + rank[e]; scatter (src, e) — no atomics
__global__ __launch_bounds__(256) void build_kernel(
    const int* __restrict__ ei, int2* __restrict__ sorted,
    const int* __restrict__ offsets, const int* __restrict__ rank, int E)
{
    int e = blockIdx.x * 256 + threadIdx.x;
    if (e >= E) return;
    int src = ei[e];
    int dst = ei[E + e];
    int pos = offsets[dst] + rank[e];
    sorted[pos] = make_int2(src, e);
}

// fused gather + EA segment-sum, co-scheduled in one dispatch:
// even blocks: gather Hb rows -> Ab (bf16) for 4 nodes (latency-bound).
// odd  blocks: EA segment-sum -> aggE for 4 nodes (BW-bound).
// Interleaving puts both kinds on every CU so the memory pipes overlap.
// Both are independent now that the We/be correction is folded into the MLP.
__global__ __launch_bounds__(256) void gather_ea_kernel(
    const unsigned short* __restrict__ Hb,
    const float* __restrict__ EA,
    const int2* __restrict__ sorted,
    const int* __restrict__ offsets,
    unsigned short* __restrict__ Ab,    // [N,128] bf16
    float* __restrict__ aggE,           // [N,16]
    int N)
{
    const int bt = blockIdx.x & 1;
    const int bg = blockIdx.x >> 1;
    int n = bg * 4 + (threadIdx.x >> 6);
    if (n >= N) return;
    int lane = threadIdx.x & 63;
    int s = offsets[n];
    int e_end = offsets[n + 1];

    if (bt == 0) {
        // ---- gather: half-waves own alternate edge slots; 32 lanes x 8B/row
        int half = lane >> 5;
        int l32  = lane & 31;
        float a0 = 0.f, a1 = 0.f, a2 = 0.f, a3 = 0.f;
        int i = s + half;
        for (; i + 6 < e_end; i += 8) {
            int s0 = sorted[i].x;
            int s1 = sorted[i + 2].x;
            int s2 = sorted[i + 4].x;
            int s3 = sorted[i + 6].x;
            uint2 u0 = *(const uint2*)(Hb + (long long)s0 * IN_F + l32 * 4);
            uint2 u1 = *(const uint2*)(Hb + (long long)s1 * IN_F + l32 * 4);
            uint2 u2 = *(const uint2*)(Hb + (long long)s2 * IN_F + l32 * 4);
            uint2 u3 = *(const uint2*)(Hb + (long long)s3 * IN_F + l32 * 4);
            a0 += (blo(u0.x) + blo(u1.x)) + (blo(u2.x) + blo(u3.x));
            a1 += (bhi(u0.x) + bhi(u1.x)) + (bhi(u2.x) + bhi(u3.x));
            a2 += (blo(u0.y) + blo(u1.y)) + (blo(u2.y) + blo(u3.y));
            a3 += (bhi(u0.y) + bhi(u1.y)) + (bhi(u2.y) + bhi(u3.y));
        }
        for (; i < e_end; i += 2) {
            int se = sorted[i].x;
            uint2 u = *(const uint2*)(Hb + (long long)se * IN_F + l32 * 4);
            a0 += blo(u.x); a1 += bhi(u.x); a2 += blo(u.y); a3 += bhi(u.y);
        }
        a0 += __shfl_xor(a0, 32, 64);
        a1 += __shfl_xor(a1, 32, 64);
        a2 += __shfl_xor(a2, 32, 64);
        a3 += __shfl_xor(a3, 32, 64);
        if (half == 0) {
            ushort4 o;
            o.x = f2b(a0); o.y = f2b(a1); o.z = f2b(a2); o.w = f2b(a3);
            *(ushort4*)&Ab[(long long)n * IN_F + l32 * 4] = o;
        }
    } else {
        // ---- EA segment-sum: 4 edge slots x 16 feats; one 64B EA row/edge
        int sub = lane >> 4;
        int f   = lane & 15;
        float acc = 0.f;
        int i = s + sub;
        for (; i + 4 < e_end; i += 8) {
            int e0 = sorted[i].y;
            int e1 = sorted[i + 4].y;
            float v0 = EA[(long long)e0 * EF + f];
            float v1 = EA[(long long)e1 * EF + f];
            acc += v0 + v1;
        }
        for (; i < e_end; i += 4) {
            int e0 = sorted[i].y;
            acc += EA[(long long)e0 * EF + f];
        }
        acc += __shfl_xor(acc, 16, 64);
        acc += __shfl_xor(acc, 32, 64);
        if (sub == 0) aggE[n * EF + f] = acc;
    }
}

// gather (fp32 H) fallback — writes agg/aggE/deg for node_mlp path
__global__ __launch_bounds__(256) void gather_f32_kernel(
    const float* __restrict__ H,
    const float* __restrict__ EA,
    const int2* __restrict__ sorted,
    const int* __restrict__ offsets,
    float* __restrict__ agg,
    float* __restrict__ aggE,
    float* __restrict__ degf,
    int N)
{
    int n = blockIdx.x * 4 + (threadIdx.x >> 6);
    if (n >= N) return;
    int lane = threadIdx.x & 63;
    int half = lane >> 5;
    int l32  = lane & 31;
    int s = offsets[n];
    int e_end = offsets[n + 1];
    float4 acc = make_float4(0.f, 0.f, 0.f, 0.f);
    float accE = 0.f;
    int i = s + half;
    for (; i + 6 < e_end; i += 8) {
        int2 s0 = sorted[i];
        int2 s1 = sorted[i + 2];
        int2 s2 = sorted[i + 4];
        int2 s3 = sorted[i + 6];
        float4 v0 = *(const float4*)(H + (long long)s0.x * IN_F + l32 * 4);
        float4 v1 = *(const float4*)(H + (long long)s1.x * IN_F + l32 * 4);
        float4 v2 = *(const float4*)(H + (long long)s2.x * IN_F + l32 * 4);
        float4 v3 = *(const float4*)(H + (long long)s3.x * IN_F + l32 * 4);
        float e0 = 0.f, e1 = 0.f, e2 = 0.f, e3 = 0.f;
        if (l32 < EF) {
            e0 = EA[(long long)s0.y * EF + l32];
            e1 = EA[(long long)s1.y * EF + l32];
            e2 = EA[(long long)s2.y * EF + l32];
            e3 = EA[(long long)s3.y * EF + l32];
        }
        acc.x += (v0.x + v1.x) + (v2.x + v3.x);
        acc.y += (v0.y + v1.y) + (v2.y + v3.y);
        acc.z += (v0.z + v1.z) + (v2.z + v3.z);
        acc.w += (v0.w + v1.w) + (v2.w + v3.w);
        accE  += (e0 + e1) + (e2 + e3);
    }
    for (; i < e_end; i += 2) {
        int2 se = sorted[i];
        float4 v = *(const float4*)(H + (long long)se.x * IN_F + l32 * 4);
        acc.x += v.x; acc.y += v.y; acc.z += v.z; acc.w += v.w;
        if (l32 < EF) accE += EA[(long long)se.y * EF + l32];
    }
    acc.x += __shfl_xor(acc.x, 32, 64);
    acc.y += __shfl_xor(acc.y, 32, 64);
    acc.z += __shfl_xor(acc.z, 32, 64);
    acc.w += __shfl_xor(acc.w, 32, 64);
    accE  += __shfl_xor(accE, 32, 64);
    if (half == 0) {
        *(float4*)(agg + (long long)n * IN_F + l32 * 4) = acc;
        if (l32 < EF) aggE[n * EF + l32] = accE;
        if (l32 == 0) degf[n] = (float)(e_end - s);
    }
}

// ======================= fallback: atomic scatter ===========================
__global__ __launch_bounds__(256) void edge_scatter_kernel(
    const float* __restrict__ H,
    const int* __restrict__ ei,
    const float* __restrict__ EA,
    float* __restrict__ agg,
    float* __restrict__ aggE,
    float* __restrict__ deg,
    int E)
{
    long long gid = (long long)blockIdx.x * 256 + threadIdx.x;
    int e = (int)(gid >> 7);
    if (e >= E) return;
    int f = (int)(gid & 127);
    int src = ei[e];
    int dst = ei[E + e];
    float m = H[(long long)src * IN_F + f];
    atomicAdd(&agg[(long long)dst * IN_F + f], m);
    if (f < EF) atomicAdd(&aggE[dst * EF + f], EA[e * EF + f]);
    if (f == 0) atomicAdd(&deg[dst], 1.0f);
}

// ========================= MFMA node-MLP path ===============================

// fused 2-layer MLP on MFMA with edge-correction folded into the layer-1
// accumulator init:
//   h = relu(Ab@W1 + [b1 + deg*bea + aggE@Wea]);  out = h@W2 + b2
// 64-row tile, 4 waves; wave w owns rows M0=16w..M0+15. A-tile + Wt in LDS.
#define XPITCH 136
__global__ __launch_bounds__(256) void mlp_mfma_kernel(
    const unsigned short* __restrict__ Ab,
    const unsigned short* __restrict__ W1t,
    const unsigned short* __restrict__ W2t,
    const float* __restrict__ aggE,     // [N,16]
    const int* __restrict__ offsets,    // [N+1] (deg = diff)
    const float* __restrict__ Wea,      // [16,128] f32 = We@W1
    const float* __restrict__ bea,      // [128]    f32 = be@W1
    const float* __restrict__ b1, const float* __restrict__ b2,
    float* __restrict__ out, int N)
{
    __shared__ unsigned short sW[128 * XPITCH];   // 34816 B
    __shared__ unsigned short sX[64 * XPITCH];    // 17408 B
    const int t    = threadIdx.x;
    const int tile = blockIdx.x * 64;
    const int lane = t & 63;
    const int wv   = t >> 6;          // 0..3
    const int quad = lane >> 4;       // 0..3
    const int lr   = lane & 15;
    const int M0   = wv * 16;

    // stage A tile (64 rows x 16 uint4) and W1t (128 rows x 16 uint4)
    {
        const uint4 z = make_uint4(0, 0, 0, 0);
        #pragma unroll
        for (int j = 0; j < 4; j++) {
            int idx = t + 256 * j;                 // 0..1023
            int row = idx >> 4, c = idx & 15;
            uint4 v = z;
            if (tile + row < N) v = ((const uint4*)Ab)[(long long)(tile + row) * 16 + c];
            ((uint4*)sX)[row * 17 + c] = v;
        }
        #pragma unroll
        for (int j = 0; j < 8; j++) {
            int idx = t + 256 * j;                 // 0..2047
            int row = idx >> 4, c = idx & 15;
            ((uint4*)sW)[row * 17 + c] = ((const uint4*)W1t)[idx];
        }
    }

    // per-lane correction inputs (global loads; overlap with LDS staging)
    float degv[4];
    f32x4 aeq[4][4];
    #pragma unroll
    for (int r = 0; r < 4; r++) {
        int row = tile + M0 + quad * 4 + r;
        if (row < N) {
            degv[r] = (float)(offsets[row + 1] - offsets[row]);
            #pragma unroll
            for (int q = 0; q < 4; q++)
                aeq[r][q] = *(const f32x4*)&aggE[(long long)row * EF + q * 4];
        } else {
            degv[r] = 0.f;
            #pragma unroll
            for (int q = 0; q < 4; q++) aeq[r][q] = (f32x4){0.f, 0.f, 0.f, 0.f};
        }
    }
    __syncthreads();

    f32x4 acc[8];
    bf16x8 af[4];

    // phase 2: h = relu(A @ W1 + corr) -> sX rows M0..M0+15 (wave-private)
    #pragma unroll
    for (int kt = 0; kt < 4; kt++)
        af[kt] = *(const bf16x8*)&sX[(M0 + lr) * XPITCH + kt * 32 + quad * 8];
    #pragma unroll
    for (int nt = 0; nt < 8; nt++) {
        int col = nt * 16 + lr;
        float base = b1[col];
        float beac = bea[col];
        float c0 = base + degv[0] * beac;
        float c1 = base + degv[1] * beac;
        float c2 = base + degv[2] * beac;
        float c3 = base + degv[3] * beac;
        #pragma unroll
        for (int k = 0; k < EF; k++) {
            float wk = Wea[k * IN_F + col];
            c0 += ((const float*)&aeq[0][k >> 2])[k & 3] * wk;
            c1 += ((const float*)&aeq[1][k >> 2])[k & 3] * wk;
            c2 += ((const float*)&aeq[2][k >> 2])[k & 3] * wk;
            c3 += ((const float*)&aeq[3][k >> 2])[k & 3] * wk;
        }
        acc[nt] = (f32x4){c0, c1, c2, c3};
        #pragma unroll
        for (int kt = 0; kt < 4; kt++) {
            bf16x8 bf = *(const bf16x8*)&sW[(nt * 16 + lr) * XPITCH + kt * 32 + quad * 8];
            acc[nt] = __builtin_amdgcn_mfma_f32_16x16x32_bf16(af[kt], bf, acc[nt], 0, 0, 0);
        }
    }
    #pragma unroll
    for (int nt = 0; nt < 8; nt++) {
        int col = nt * 16 + lr;
        #pragma unroll
        for (int r = 0; r < 4; r++) {
            float v = fmaxf(acc[nt][r], 0.f);
            sX[(M0 + quad * 4 + r) * XPITCH + col] = f2b(v);
        }
    }
    __syncthreads();    // all waves done reading W1t
    #pragma unroll
    for (int j = 0; j < 8; j++) {
        int idx = t + 256 * j;
        int row = idx >> 4, c = idx & 15;
        ((uint4*)sW)[row * 17 + c] = ((const uint4*)W2t)[idx];
    }
    __syncthreads();

    // phase 3: out = h @ W2 + b2
    const f32x4 zero = {0.f, 0.f, 0.f, 0.f};
    #pragma unroll
    for (int kt = 0; kt < 4; kt++)
        af[kt] = *(const bf16x8*)&sX[(M0 + lr) * XPITCH + kt * 32 + quad * 8];
    #pragma unroll
    for (int nt = 0; nt < 8; nt++) {
        acc[nt] = zero;
        #pragma unroll
        for (int kt = 0; kt < 4; kt++) {
            bf16x8 bf = *(const bf16x8*)&sW[(nt * 16 + lr) * XPITCH + kt * 32 + quad * 8];
            acc[nt] = __builtin_amdgcn_mfma_f32_16x16x32_bf16(af[kt], bf, acc[nt], 0, 0, 0);
        }
    }
    #pragma unroll
    for (int nt = 0; nt < 8; nt++) {
        int col = nt * 16 + lr;
        float bias = b2[col];
        #pragma unroll
        for (int r = 0; r < 4; r++) {
            int row = tile + M0 + quad * 4 + r;
            if (row < N) out[(long long)row * IN_F + col] = acc[nt][r] + bias;
        }
    }
}

// ================== fp32 node MLP (fallback path only) ======================
__global__ __launch_bounds__(256) void node_mlp_kernel(
    float* agg_out,
    const float* __restrict__ aggE,
    const float* __restrict__ degf,
    const float* __restrict__ We, const float* __restrict__ be,
    const float* __restrict__ W1, const float* __restrict__ b1,
    const float* __restrict__ W2, const float* __restrict__ b2,
    int N)
{
    __shared__ float sA[32][IN_F];
    __shared__ float sH[32][IN_F];
    const int t  = threadIdx.x;
    const int c4 = (t & 31) * 4;
    const int r0 = t >> 5;

    const int tile = blockIdx.x * 32;
    if (tile >= N) return;
    int rows = N - tile;
    if (rows > 32) rows = 32;

    {
        const float4 bev = *(const float4*)&be[c4];
        #pragma unroll
        for (int i = 0; i < 4; i++) {
            int rr = r0 + 8 * i;
            float4 v = make_float4(0.f, 0.f, 0.f, 0.f);
            if (rr < rows) {
                long long r = tile + rr;
                v = *(const float4*)&agg_out[r * IN_F + c4];
                float d = degf[r];
                v.x += d * bev.x; v.y += d * bev.y; v.z += d * bev.z; v.w += d * bev.w;
                #pragma unroll
                for (int k = 0; k < EF; k++) {
                    float a = aggE[r * EF + k];
                    float4 w = *(const float4*)&We[k * IN_F + c4];
                    v.x += a * w.x; v.y += a * w.y; v.z += a * w.z; v.w += a * w.w;
                }
            }
            *(float4*)&sA[rr][c4] = v;
        }
    }
    __syncthreads();
    {
        const float4 bv = *(const float4*)&b1[c4];
        float4 a0 = bv, a1 = bv, a2 = bv, a3 = bv;
        for (int k = 0; k < IN_F; k++) {
            float4 w = *(const float4*)&W1[k * IN_F + c4];
            float x0 = sA[r0][k], x1 = sA[r0 + 8][k], x2 = sA[r0 + 16][k], x3 = sA[r0 + 24][k];
            a0.x += x0 * w.x; a0.y += x0 * w.y; a0.z += x0 * w.z; a0.w += x0 * w.w;
            a1.x += x1 * w.x; a1.y += x1 * w.y; a1.z += x1 * w.z; a1.w += x1 * w.w;
            a2.x += x2 * w.x; a2.y += x2 * w.y; a2.z += x2 * w.z; a2.w += x2 * w.w;
            a3.x += x3 * w.x; a3.y += x3 * w.y; a3.z += x3 * w.z; a3.w += x3 * w.w;
        }
        a0.x = fmaxf(a0.x, 0.f); a0.y = fmaxf(a0.y, 0.f); a0.z = fmaxf(a0.z, 0.f); a0.w = fmaxf(a0.w, 0.f);
        a1.x = fmaxf(a1.x, 0.f); a1.y = fmaxf(a1.y, 0.f); a1.z = fmaxf(a1.z, 0.f); a1.w = fmaxf(a1.w, 0.f);
        a2.x = fmaxf(a2.x, 0.f); a2.y = fmaxf(a2.y, 0.f); a2.z = fmaxf(a2.z, 0.f); a2.w = fmaxf(a2.w, 0.f);
        a3.x = fmaxf(a3.x, 0.f); a3.y = fmaxf(a3.y, 0.f); a3.z = fmaxf(a3.z, 0.f); a3.w = fmaxf(a3.w, 0.f);
        *(float4*)&sH[r0][c4]      = a0;
        *(float4*)&sH[r0 + 8][c4]  = a1;
        *(float4*)&sH[r0 + 16][c4] = a2;
        *(float4*)&sH[r0 + 24][c4] = a3;
    }
    __syncthreads();
    {
        const float4 bv = *(const float4*)&b2[c4];
        float4 a0 = bv, a1 = bv, a2 = bv, a3 = bv;
        for (int k = 0; k < IN_F; k++) {
            float4 w = *(const float4*)&W2[k * IN_F + c4];
            float x0 = sH[r0][k], x1 = sH[r0 + 8][k], x2 = sH[r0 + 16][k], x3 = sH[r0 + 24][k];
            a0.x += x0 * w.x; a0.y += x0 * w.y; a0.z += x0 * w.z; a0.w += x0 * w.w;
            a1.x += x1 * w.x; a1.y += x1 * w.y; a1.z += x1 * w.z; a1.w += x1 * w.w;
            a2.x += x2 * w.x; a2.y += x2 * w.y; a2.z += x2 * w.z; a2.w += x2 * w.w;
            a3.x += x3 * w.x; a3.y += x3 * w.y; a3.z += x3 * w.z; a3.w += x3 * w.w;
        }
        #pragma unroll
        for (int i = 0; i < 4; i++) {
            int rr = r0 + 8 * i;
            if (rr < rows) {
                float4 v = (i == 0) ? a0 : (i == 1) ? a1 : (i == 2) ? a2 : a3;
                *(float4*)&agg_out[(long long)(tile + rr) * IN_F + c4] = v;
            }
        }
    }
}

// ================================ host ======================================
extern "C" void kernel_launch(void* const* d_in, const int* in_sizes, int n_in,
                              void* d_out, int out_size, void* d_ws, size_t ws_size,
                              hipStream_t stream) {
    const float* H  = (const float*)d_in[0];
    const int*   ei = (const int*)d_in[1];     // int32 [2,E]
    const float* EA = (const float*)d_in[2];
    const float* We = (const float*)d_in[3];
    const float* be = (const float*)d_in[4];
    const float* W1 = (const float*)d_in[5];
    const float* b1 = (const float*)d_in[6];
    const float* W2 = (const float*)d_in[7];
    const float* b2 = (const float*)d_in[8];
    float* out = (float*)d_out;

    const int N = in_sizes[0] / IN_F;
    const int E = in_sizes[2] / EF;

    char* p = (char*)d_ws;
    auto alloc = [&](size_t bytes) { char* r = p; p += (bytes + 255) & ~(size_t)255; return r; };
    int2*  sorted   = (int2*)alloc((size_t)E * sizeof(int2));
    int*   rank     = (int*)alloc((size_t)E * sizeof(int));
    float* degf     = (float*)alloc((size_t)N * sizeof(float));
    float* aggE     = (float*)alloc((size_t)N * EF * sizeof(float));
    int*   counts   = (int*)alloc((size_t)(N + 1) * sizeof(int));
    int*   offsets  = (int*)alloc((size_t)(N + 1) * sizeof(int));
    int*   partials = (int*)alloc(1024 * sizeof(int));
    size_t need_base = (size_t)(p - (char*)d_ws);
    unsigned short* Hb = (unsigned short*)alloc((size_t)N * IN_F * sizeof(unsigned short));
    unsigned short* Ab  = (unsigned short*)alloc((size_t)N * IN_F * sizeof(unsigned short));
    unsigned short* W1t = (unsigned short*)alloc((size_t)IN_F * IN_F * sizeof(unsigned short));
    unsigned short* W2t = (unsigned short*)alloc((size_t)IN_F * IN_F * sizeof(unsigned short));
    float* Wea = (float*)alloc((size_t)EF * IN_F * sizeof(float));
    float* bea = (float*)alloc((size_t)IN_F * sizeof(float));
    size_t need_mfma = (size_t)(p - (char*)d_ws);

    const int n_scan = N + 1;
    const int B = (n_scan + 1023) / 1024;

    if (ws_size >= need_mfma && B <= 1024) {
        // fast path: 6 dispatches + 1 memset
        hipMemsetAsync(counts, 0, (size_t)(N + 1) * sizeof(int), stream);
        const int n4 = N * IN_F / 4;
        const int h2b_blocks  = (n4 + 255) / 256;
        const int hist_blocks = (E + 255) / 256;
        const int wea_blocks  = (EF * IN_F + IN_F + 255) / 256;   // 9
        pre_kernel<<<h2b_blocks + hist_blocks + 128 + wea_blocks, 256, 0, stream>>>(
            H, Hb, n4, ei, counts, rank, E, W1, W1t, W2, W2t, We, be, Wea, bea,
            h2b_blocks, hist_blocks);
        scan_blocks_kernel<<<B, 256, 0, stream>>>(counts, offsets, partials, n_scan);
        scan_add_fused_kernel<<<(n_scan + 255) / 256, 256, 0, stream>>>(offsets, partials, n_scan);
        build_kernel<<<(E + 255) / 256, 256, 0, stream>>>(ei, sorted, offsets, rank, E);
        gather_ea_kernel<<<2 * ((N + 3) / 4), 256, 0, stream>>>(
            Hb, EA, sorted, offsets, Ab, aggE, N);
        mlp_mfma_kernel<<<(N + 63) / 64, 256, 0, stream>>>(
            Ab, W1t, W2t, aggE, offsets, Wea, bea, b1, b2, out, N);
    } else if (ws_size >= need_base && B <= 1024) {
        // fp32 CSR fallback
        hipMemsetAsync(counts, 0, (size_t)(N + 1) * sizeof(int), stream);
        hist_kernel<<<(E + 255) / 256, 256, 0, stream>>>(ei, counts, rank, E);
        scan_blocks_kernel<<<B, 256, 0, stream>>>(counts, offsets, partials, n_scan);
        scan_add_fused_kernel<<<(n_scan + 255) / 256, 256, 0, stream>>>(offsets, partials, n_scan);
        build_kernel<<<(E + 255) / 256, 256, 0, stream>>>(ei, sorted, offsets, rank, E);
        gather_f32_kernel<<<(N + 3) / 4, 256, 0, stream>>>(H, EA, sorted, offsets, out, aggE, degf, N);
        node_mlp_kernel<<<(N + 31) / 32, 256, 0, stream>>>(out, aggE, degf, We, be, W1, b1, W2, b2, N);
    } else {
        // atomic-scatter fallback
        float* f_aggE = (float*)d_ws;
        float* f_deg  = f_aggE + (size_t)N * EF;
        hipMemsetAsync(d_out, 0, (size_t)N * IN_F * sizeof(float), stream);
        hipMemsetAsync(d_ws, 0, (size_t)N * (EF + 1) * sizeof(float), stream);
        long long tot = (long long)E * IN_F;
        edge_scatter_kernel<<<(int)((tot + 255) / 256), 256, 0, stream>>>(H, ei, EA, out, f_aggE, f_deg, E);
        node_mlp_kernel<<<(N + 31) / 32, 256, 0, stream>>>(out, f_aggE, f_deg, We, be, W1, b1, W2, b2, N);
    }
}

// Round 8
// 481.099 us; speedup vs baseline: 1.0758x; 1.0127x over previous
//
#include <hip/hip_runtime.h>

#define IN_F 128
#define EF 16

typedef short bf16x8 __attribute__((ext_vector_type(8)));
typedef float f32x4  __attribute__((ext_vector_type(4)));

// bf16 helpers: pack is RNE; unpack low/high halves of a uint holding 2 bf16
__device__ __forceinline__ unsigned short f2b(float f) {
    unsigned b = __float_as_uint(f);
    b += 0x7fffu + ((b >> 16) & 1u);
    return (unsigned short)(b >> 16);
}
__device__ __forceinline__ float blo(unsigned u) { return __uint_as_float(u << 16); }
__device__ __forceinline__ float bhi(unsigned u) { return __uint_as_float(u & 0xffff0000u); }

// ============================ CSR-build path ================================

// fused pre-pass: h2b cast + dst histogram (recording per-edge rank) +
// W1/W2 transpose-cast + WeaTb (bf16 [128][32]): augmented edge-correction
// operand — col k<16 = (We@W1)^T, col 16 = be@W1, cols 17..31 = 0.
// The node-MLP folds the edge correction in as ONE extra MFMA per tile.
__global__ __launch_bounds__(256) void pre_kernel(
    const float* __restrict__ H, unsigned short* __restrict__ Hb, int n4,
    const int* __restrict__ ei, int* __restrict__ counts,
    int* __restrict__ rank, int E,
    const float* __restrict__ W1, unsigned short* __restrict__ W1t,
    const float* __restrict__ W2, unsigned short* __restrict__ W2t,
    const float* __restrict__ We, const float* __restrict__ be,
    unsigned short* __restrict__ WeaTb,
    int h2b_blocks, int hist_blocks)
{
    int b = blockIdx.x;
    if (b < h2b_blocks) {
        int i = b * 256 + threadIdx.x;
        if (i < n4) {
            float4 v = ((const float4*)H)[i];
            ushort4 r;
            r.x = f2b(v.x); r.y = f2b(v.y); r.z = f2b(v.z); r.w = f2b(v.w);
            ((ushort4*)Hb)[i] = r;
        }
    } else if (b < h2b_blocks + hist_blocks) {
        int e = (b - h2b_blocks) * 256 + threadIdx.x;
        if (e < E) rank[e] = atomicAdd(&counts[ei[E + e]], 1);
    } else if (b < h2b_blocks + hist_blocks + 128) {
        int idx = (b - h2b_blocks - hist_blocks) * 256 + threadIdx.x; // 0..32767
        int w = idx >> 14;           // 0: W1, 1: W2
        int r = idx & 16383;
        int n = r >> 7, k = r & 127;
        if (w == 0) W1t[n * IN_F + k] = f2b(W1[k * IN_F + n]);
        else        W2t[n * IN_F + k] = f2b(W2[k * IN_F + n]);
    } else {
        // WeaTb[n][k]: k<16 -> sum_j We[k][j]*W1[j][n]; k==16 -> sum_j be[j]*W1[j][n]
        int idx = (b - h2b_blocks - hist_blocks - 128) * 256 + threadIdx.x; // 0..4095
        if (idx < IN_F * 32) {
            int n = idx >> 5, k = idx & 31;
            unsigned short o = 0;
            if (k < EF) {
                float acc = 0.f;
                for (int j = 0; j < IN_F; j++) acc += We[k * IN_F + j] * W1[j * IN_F + n];
                o = f2b(acc);
            } else if (k == EF) {
                float acc = 0.f;
                for (int j = 0; j < IN_F; j++) acc += be[j] * W1[j * IN_F + n];
                o = f2b(acc);
            }
            WeaTb[n * 32 + k] = o;
        }
    }
}

// standalone hist (fp32 CSR fallback path) — also records rank
__global__ __launch_bounds__(256) void hist_kernel(
    const int* __restrict__ ei, int* __restrict__ counts,
    int* __restrict__ rank, int E)
{
    int e = blockIdx.x * 256 + threadIdx.x;
    if (e >= E) return;
    rank[e] = atomicAdd(&counts[ei[E + e]], 1);
}

__global__ __launch_bounds__(256) void scan_blocks_kernel(
    const int* __restrict__ in, int* __restrict__ out,
    int* __restrict__ partials, int n)
{
    __shared__ int sdata[256];
    const int t = threadIdx.x;
    const int idx0 = blockIdx.x * 1024 + t * 4;
    int v[4];
    #pragma unroll
    for (int i = 0; i < 4; i++) { int idx = idx0 + i; v[i] = (idx < n) ? in[idx] : 0; }
    int s = v[0] + v[1] + v[2] + v[3];
    sdata[t] = s;
    __syncthreads();
    for (int off = 1; off < 256; off <<= 1) {
        int x = (t >= off) ? sdata[t - off] : 0;
        __syncthreads();
        sdata[t] += x;
        __syncthreads();
    }
    if (t == 255) partials[blockIdx.x] = sdata[255];
    int run = (t > 0) ? sdata[t - 1] : 0;
    #pragma unroll
    for (int i = 0; i < 4; i++) {
        int idx = idx0 + i;
        if (idx < n) out[idx] = run;
        run += v[i];
    }
}

// scan_add with the partial-prefix computed in-block
__global__ __launch_bounds__(256) void scan_add_fused_kernel(
    int* __restrict__ out, const int* __restrict__ partials, int n)
{
    __shared__ int sw[4];
    const int t = threadIdx.x;
    const int g = blockIdx.x >> 2;
    int v = 0;
    for (int j = t; j < g; j += 256) v += partials[j];
    #pragma unroll
    for (int off = 1; off < 64; off <<= 1) v += __shfl_xor(v, off, 64);
    if ((t & 63) == 0) sw[t >> 6] = v;
    __syncthreads();
    int P = sw[0] + sw[1] + sw[2] + sw[3];
    int idx = blockIdx.x * 256 + t;
    if (idx < n) out[idx] += P;
}

// build: pos = offsets[dst] + rank[e]; scatter (src, e) packed as one 8B
// NONTEMPORAL store (scattered 8B writes — skip L2 write-allocate/RFO).
__global__ __launch_bounds__(256) void build_kernel(
    const int* __restrict__ ei, int2* __restrict__ sorted,
    const int* __restrict__ offsets, const int* __restrict__ rank, int E)
{
    int e = blockIdx.x * 256 + threadIdx.x;
    if (e >= E) return;
    int src = ei[e];
    int dst = ei[E + e];
    int pos = offsets[dst] + rank[e];
    long long v = ((long long)(unsigned)e << 32) | (unsigned)src;  // .x=src,.y=e
    __builtin_nontemporal_store(v, (long long*)&sorted[pos]);
}

// fused gather + EA segment-sum, co-scheduled in one dispatch:
// even blocks: gather Hb rows -> Ab (bf16) for 4 nodes (latency-bound).
// odd  blocks: EA segment-sum -> aggE for 4 nodes (BW-bound; EA read
// nontemporal — read-once stream must not evict the Hb working set).
__global__ __launch_bounds__(256) void gather_ea_kernel(
    const unsigned short* __restrict__ Hb,
    const float* __restrict__ EA,
    const int2* __restrict__ sorted,
    const int* __restrict__ offsets,
    unsigned short* __restrict__ Ab,    // [N,128] bf16
    float* __restrict__ aggE,           // [N,16]
    int N)
{
    const int bt = blockIdx.x & 1;
    const int bg = blockIdx.x >> 1;
    int n = bg * 4 + (threadIdx.x >> 6);
    if (n >= N) return;
    int lane = threadIdx.x & 63;
    int s = offsets[n];
    int e_end = offsets[n + 1];

    if (bt == 0) {
        // ---- gather: half-waves own alternate edge slots; 32 lanes x 8B/row
        int half = lane >> 5;
        int l32  = lane & 31;
        float a0 = 0.f, a1 = 0.f, a2 = 0.f, a3 = 0.f;
        int i = s + half;
        for (; i + 6 < e_end; i += 8) {
            int s0 = sorted[i].x;
            int s1 = sorted[i + 2].x;
            int s2 = sorted[i + 4].x;
            int s3 = sorted[i + 6].x;
            uint2 u0 = *(const uint2*)(Hb + (long long)s0 * IN_F + l32 * 4);
            uint2 u1 = *(const uint2*)(Hb + (long long)s1 * IN_F + l32 * 4);
            uint2 u2 = *(const uint2*)(Hb + (long long)s2 * IN_F + l32 * 4);
            uint2 u3 = *(const uint2*)(Hb + (long long)s3 * IN_F + l32 * 4);
            a0 += (blo(u0.x) + blo(u1.x)) + (blo(u2.x) + blo(u3.x));
            a1 += (bhi(u0.x) + bhi(u1.x)) + (bhi(u2.x) + bhi(u3.x));
            a2 += (blo(u0.y) + blo(u1.y)) + (blo(u2.y) + blo(u3.y));
            a3 += (bhi(u0.y) + bhi(u1.y)) + (bhi(u2.y) + bhi(u3.y));
        }
        for (; i < e_end; i += 2) {
            int se = sorted[i].x;
            uint2 u = *(const uint2*)(Hb + (long long)se * IN_F + l32 * 4);
            a0 += blo(u.x); a1 += bhi(u.x); a2 += blo(u.y); a3 += bhi(u.y);
        }
        a0 += __shfl_xor(a0, 32, 64);
        a1 += __shfl_xor(a1, 32, 64);
        a2 += __shfl_xor(a2, 32, 64);
        a3 += __shfl_xor(a3, 32, 64);
        if (half == 0) {
            ushort4 o;
            o.x = f2b(a0); o.y = f2b(a1); o.z = f2b(a2); o.w = f2b(a3);
            *(ushort4*)&Ab[(long long)n * IN_F + l32 * 4] = o;
        }
    } else {
        // ---- EA segment-sum: 4 edge slots x 16 feats; one 64B EA row/edge
        int sub = lane >> 4;
        int f   = lane & 15;
        float acc = 0.f;
        int i = s + sub;
        for (; i + 4 < e_end; i += 8) {
            int e0 = sorted[i].y;
            int e1 = sorted[i + 4].y;
            float v0 = __builtin_nontemporal_load(&EA[(long long)e0 * EF + f]);
            float v1 = __builtin_nontemporal_load(&EA[(long long)e1 * EF + f]);
            acc += v0 + v1;
        }
        for (; i < e_end; i += 4) {
            int e0 = sorted[i].y;
            acc += __builtin_nontemporal_load(&EA[(long long)e0 * EF + f]);
        }
        acc += __shfl_xor(acc, 16, 64);
        acc += __shfl_xor(acc, 32, 64);
        if (sub == 0) aggE[n * EF + f] = acc;
    }
}

// gather (fp32 H) fallback — writes agg/aggE/deg for node_mlp path
__global__ __launch_bounds__(256) void gather_f32_kernel(
    const float* __restrict__ H,
    const float* __restrict__ EA,
    const int2* __restrict__ sorted,
    const int* __restrict__ offsets,
    float* __restrict__ agg,
    float* __restrict__ aggE,
    float* __restrict__ degf,
    int N)
{
    int n = blockIdx.x * 4 + (threadIdx.x >> 6);
    if (n >= N) return;
    int lane = threadIdx.x & 63;
    int half = lane >> 5;
    int l32  = lane & 31;
    int s = offsets[n];
    int e_end = offsets[n + 1];
    float4 acc = make_float4(0.f, 0.f, 0.f, 0.f);
    float accE = 0.f;
    int i = s + half;
    for (; i + 6 < e_end; i += 8) {
        int2 s0 = sorted[i];
        int2 s1 = sorted[i + 2];
        int2 s2 = sorted[i + 4];
        int2 s3 = sorted[i + 6];
        float4 v0 = *(const float4*)(H + (long long)s0.x * IN_F + l32 * 4);
        float4 v1 = *(const float4*)(H + (long long)s1.x * IN_F + l32 * 4);
        float4 v2 = *(const float4*)(H + (long long)s2.x * IN_F + l32 * 4);
        float4 v3 = *(const float4*)(H + (long long)s3.x * IN_F + l32 * 4);
        float e0 = 0.f, e1 = 0.f, e2 = 0.f, e3 = 0.f;
        if (l32 < EF) {
            e0 = EA[(long long)s0.y * EF + l32];
            e1 = EA[(long long)s1.y * EF + l32];
            e2 = EA[(long long)s2.y * EF + l32];
            e3 = EA[(long long)s3.y * EF + l32];
        }
        acc.x += (v0.x + v1.x) + (v2.x + v3.x);
        acc.y += (v0.y + v1.y) + (v2.y + v3.y);
        acc.z += (v0.z + v1.z) + (v2.z + v3.z);
        acc.w += (v0.w + v1.w) + (v2.w + v3.w);
        accE  += (e0 + e1) + (e2 + e3);
    }
    for (; i < e_end; i += 2) {
        int2 se = sorted[i];
        float4 v = *(const float4*)(H + (long long)se.x * IN_F + l32 * 4);
        acc.x += v.x; acc.y += v.y; acc.z += v.z; acc.w += v.w;
        if (l32 < EF) accE += EA[(long long)se.y * EF + l32];
    }
    acc.x += __shfl_xor(acc.x, 32, 64);
    acc.y += __shfl_xor(acc.y, 32, 64);
    acc.z += __shfl_xor(acc.z, 32, 64);
    acc.w += __shfl_xor(acc.w, 32, 64);
    accE  += __shfl_xor(accE, 32, 64);
    if (half == 0) {
        *(float4*)(agg + (long long)n * IN_F + l32 * 4) = acc;
        if (l32 < EF) aggE[n * EF + l32] = accE;
        if (l32 == 0) degf[n] = (float)(e_end - s);
    }
}

// ======================= fallback: atomic scatter ===========================
__global__ __launch_bounds__(256) void edge_scatter_kernel(
    const float* __restrict__ H,
    const int* __restrict__ ei,
    const float* __restrict__ EA,
    float* __restrict__ agg,
    float* __restrict__ aggE,
    float* __restrict__ deg,
    int E)
{
    long long gid = (long long)blockIdx.x * 256 + threadIdx.x;
    int e = (int)(gid >> 7);
    if (e >= E) return;
    int f = (int)(gid & 127);
    int src = ei[e];
    int dst = ei[E + e];
    float m = H[(long long)src * IN_F + f];
    atomicAdd(&agg[(long long)dst * IN_F + f], m);
    if (f < EF) atomicAdd(&aggE[dst * EF + f], EA[e * EF + f]);
    if (f == 0) atomicAdd(&deg[dst], 1.0f);
}

// ========================= MFMA node-MLP path ===============================

// fused 2-layer MLP on MFMA. Edge correction folded in as ONE extra MFMA
// per output tile via augmented operands:
//   corr = [aggE | deg | 0] (64x32) @ [Wea ; bea ; 0] (32x128)   (bf16 MFMA)
//   h = relu(corr + Ab@W1 + b1);  out = h@W2 + b2
#define XPITCH 136
__global__ __launch_bounds__(256) void mlp_mfma_kernel(
    const unsigned short* __restrict__ Ab,
    const unsigned short* __restrict__ W1t,
    const unsigned short* __restrict__ W2t,
    const float* __restrict__ aggE,     // [N,16]
    const int* __restrict__ offsets,    // [N+1] (deg = diff)
    const unsigned short* __restrict__ WeaTb, // [128][32] bf16 augmented
    const float* __restrict__ b1, const float* __restrict__ b2,
    float* __restrict__ out, int N)
{
    __shared__ unsigned short sW[128 * XPITCH];   // 34816 B
    __shared__ unsigned short sX[64 * XPITCH];    // 17408 B
    const int t    = threadIdx.x;
    const int tile = blockIdx.x * 64;
    const int lane = t & 63;
    const int wv   = t >> 6;          // 0..3
    const int quad = lane >> 4;       // 0..3
    const int lr   = lane & 15;
    const int M0   = wv * 16;

    // stage A tile (64 rows x 16 uint4) and W1t (128 rows x 16 uint4)
    {
        const uint4 z = make_uint4(0, 0, 0, 0);
        #pragma unroll
        for (int j = 0; j < 4; j++) {
            int idx = t + 256 * j;                 // 0..1023
            int row = idx >> 4, c = idx & 15;
            uint4 v = z;
            if (tile + row < N) v = ((const uint4*)Ab)[(long long)(tile + row) * 16 + c];
            ((uint4*)sX)[row * 17 + c] = v;
        }
        #pragma unroll
        for (int j = 0; j < 8; j++) {
            int idx = t + 256 * j;                 // 0..2047
            int row = idx >> 4, c = idx & 15;
            ((uint4*)sW)[row * 17 + c] = ((const uint4*)W1t)[idx];
        }
    }

    // augmented A fragment (in registers; each lane reads ITS row's aggE slice)
    // A-frag layout for 16x16x32: row = lr, k = quad*8 + j.
    bf16x8 afE = (bf16x8){0, 0, 0, 0, 0, 0, 0, 0};
    {
        int grow = tile + M0 + lr;
        if (grow < N) {
            if (quad < 2) {
                const float* ap = &aggE[(long long)grow * EF + quad * 8];
                #pragma unroll
                for (int j = 0; j < 8; j++) afE[j] = (short)f2b(ap[j]);
            } else if (quad == 2) {
                afE[0] = (short)f2b((float)(offsets[grow + 1] - offsets[grow]));
            }
        }
    }
    __syncthreads();

    f32x4 acc[8];
    bf16x8 af[4];
    const f32x4 zero = {0.f, 0.f, 0.f, 0.f};

    // phase 2: h = relu(corr + A@W1 + b1) -> sX rows M0..M0+15 (wave-private)
    #pragma unroll
    for (int kt = 0; kt < 4; kt++)
        af[kt] = *(const bf16x8*)&sX[(M0 + lr) * XPITCH + kt * 32 + quad * 8];
    #pragma unroll
    for (int nt = 0; nt < 8; nt++) {
        bf16x8 bfE = *(const bf16x8*)&WeaTb[(nt * 16 + lr) * 32 + quad * 8];
        acc[nt] = __builtin_amdgcn_mfma_f32_16x16x32_bf16(afE, bfE, zero, 0, 0, 0);
        #pragma unroll
        for (int kt = 0; kt < 4; kt++) {
            bf16x8 bf = *(const bf16x8*)&sW[(nt * 16 + lr) * XPITCH + kt * 32 + quad * 8];
            acc[nt] = __builtin_amdgcn_mfma_f32_16x16x32_bf16(af[kt], bf, acc[nt], 0, 0, 0);
        }
    }
    #pragma unroll
    for (int nt = 0; nt < 8; nt++) {
        int col = nt * 16 + lr;
        float bias = b1[col];
        #pragma unroll
        for (int r = 0; r < 4; r++) {
            float v = fmaxf(acc[nt][r] + bias, 0.f);
            sX[(M0 + quad * 4 + r) * XPITCH + col] = f2b(v);
        }
    }
    __syncthreads();    // all waves done reading W1t
    #pragma unroll
    for (int j = 0; j < 8; j++) {
        int idx = t + 256 * j;
        int row = idx >> 4, c = idx & 15;
        ((uint4*)sW)[row * 17 + c] = ((const uint4*)W2t)[idx];
    }
    __syncthreads();

    // phase 3: out = h @ W2 + b2
    #pragma unroll
    for (int kt = 0; kt < 4; kt++)
        af[kt] = *(const bf16x8*)&sX[(M0 + lr) * XPITCH + kt * 32 + quad * 8];
    #pragma unroll
    for (int nt = 0; nt < 8; nt++) {
        acc[nt] = zero;
        #pragma unroll
        for (int kt = 0; kt < 4; kt++) {
            bf16x8 bf = *(const bf16x8*)&sW[(nt * 16 + lr) * XPITCH + kt * 32 + quad * 8];
            acc[nt] = __builtin_amdgcn_mfma_f32_16x16x32_bf16(af[kt], bf, acc[nt], 0, 0, 0);
        }
    }
    #pragma unroll
    for (int nt = 0; nt < 8; nt++) {
        int col = nt * 16 + lr;
        float bias = b2[col];
        #pragma unroll
        for (int r = 0; r < 4; r++) {
            int row = tile + M0 + quad * 4 + r;
            if (row < N)
                __builtin_nontemporal_store(acc[nt][r] + bias,
                                            &out[(long long)row * IN_F + col]);
        }
    }
}

// ================== fp32 node MLP (fallback path only) ======================
__global__ __launch_bounds__(256) void node_mlp_kernel(
    float* agg_out,
    const float* __restrict__ aggE,
    const float* __restrict__ degf,
    const float* __restrict__ We, const float* __restrict__ be,
    const float* __restrict__ W1, const float* __restrict__ b1,
    const float* __restrict__ W2, const float* __restrict__ b2,
    int N)
{
    __shared__ float sA[32][IN_F];
    __shared__ float sH[32][IN_F];
    const int t  = threadIdx.x;
    const int c4 = (t & 31) * 4;
    const int r0 = t >> 5;

    const int tile = blockIdx.x * 32;
    if (tile >= N) return;
    int rows = N - tile;
    if (rows > 32) rows = 32;

    {
        const float4 bev = *(const float4*)&be[c4];
        #pragma unroll
        for (int i = 0; i < 4; i++) {
            int rr = r0 + 8 * i;
            float4 v = make_float4(0.f, 0.f, 0.f, 0.f);
            if (rr < rows) {
                long long r = tile + rr;
                v = *(const float4*)&agg_out[r * IN_F + c4];
                float d = degf[r];
                v.x += d * bev.x; v.y += d * bev.y; v.z += d * bev.z; v.w += d * bev.w;
                #pragma unroll
                for (int k = 0; k < EF; k++) {
                    float a = aggE[r * EF + k];
                    float4 w = *(const float4*)&We[k * IN_F + c4];
                    v.x += a * w.x; v.y += a * w.y; v.z += a * w.z; v.w += a * w.w;
                }
            }
            *(float4*)&sA[rr][c4] = v;
        }
    }
    __syncthreads();
    {
        const float4 bv = *(const float4*)&b1[c4];
        float4 a0 = bv, a1 = bv, a2 = bv, a3 = bv;
        for (int k = 0; k < IN_F; k++) {
            float4 w = *(const float4*)&W1[k * IN_F + c4];
            float x0 = sA[r0][k], x1 = sA[r0 + 8][k], x2 = sA[r0 + 16][k], x3 = sA[r0 + 24][k];
            a0.x += x0 * w.x; a0.y += x0 * w.y; a0.z += x0 * w.z; a0.w += x0 * w.w;
            a1.x += x1 * w.x; a1.y += x1 * w.y; a1.z += x1 * w.z; a1.w += x1 * w.w;
            a2.x += x2 * w.x; a2.y += x2 * w.y; a2.z += x2 * w.z; a2.w += x2 * w.w;
            a3.x += x3 * w.x; a3.y += x3 * w.y; a3.z += x3 * w.z; a3.w += x3 * w.w;
        }
        a0.x = fmaxf(a0.x, 0.f); a0.y = fmaxf(a0.y, 0.f); a0.z = fmaxf(a0.z, 0.f); a0.w = fmaxf(a0.w, 0.f);
        a1.x = fmaxf(a1.x, 0.f); a1.y = fmaxf(a1.y, 0.f); a1.z = fmaxf(a1.z, 0.f); a1.w = fmaxf(a1.w, 0.f);
        a2.x = fmaxf(a2.x, 0.f); a2.y = fmaxf(a2.y, 0.f); a2.z = fmaxf(a2.z, 0.f); a2.w = fmaxf(a2.w, 0.f);
        a3.x = fmaxf(a3.x, 0.f); a3.y = fmaxf(a3.y, 0.f); a3.z = fmaxf(a3.z, 0.f); a3.w = fmaxf(a3.w, 0.f);
        *(float4*)&sH[r0][c4]      = a0;
        *(float4*)&sH[r0 + 8][c4]  = a1;
        *(float4*)&sH[r0 + 16][c4] = a2;
        *(float4*)&sH[r0 + 24][c4] = a3;
    }
    __syncthreads();
    {
        const float4 bv = *(const float4*)&b2[c4];
        float4 a0 = bv, a1 = bv, a2 = bv, a3 = bv;
        for (int k = 0; k < IN_F; k++) {
            float4 w = *(const float4*)&W2[k * IN_F + c4];
            float x0 = sH[r0][k], x1 = sH[r0 + 8][k], x2 = sH[r0 + 16][k], x3 = sH[r0 + 24][k];
            a0.x += x0 * w.x; a0.y += x0 * w.y; a0.z += x0 * w.z; a0.w += x0 * w.w;
            a1.x += x1 * w.x; a1.y += x1 * w.y; a1.z += x1 * w.z; a1.w += x1 * w.w;
            a2.x += x2 * w.x; a2.y += x2 * w.y; a2.z += x2 * w.z; a2.w += x2 * w.w;
            a3.x += x3 * w.x; a3.y += x3 * w.y; a3.z += x3 * w.z; a3.w += x3 * w.w;
        }
        #pragma unroll
        for (int i = 0; i < 4; i++) {
            int rr = r0 + 8 * i;
            if (rr < rows) {
                float4 v = (i == 0) ? a0 : (i == 1) ? a1 : (i == 2) ? a2 : a3;
                *(float4*)&agg_out[(long long)(tile + rr) * IN_F + c4] = v;
            }
        }
    }
}

// ================================ host ======================================
extern "C" void kernel_launch(void* const* d_in, const int* in_sizes, int n_in,
                              void* d_out, int out_size, void* d_ws, size_t ws_size,
                              hipStream_t stream) {
    const float* H  = (const float*)d_in[0];
    const int*   ei = (const int*)d_in[1];     // int32 [2,E]
    const float* EA = (const float*)d_in[2];
    const float* We = (const float*)d_in[3];
    const float* be = (const float*)d_in[4];
    const float* W1 = (const float*)d_in[5];
    const float* b1 = (const float*)d_in[6];
    const float* W2 = (const float*)d_in[7];
    const float* b2 = (const float*)d_in[8];
    float* out = (float*)d_out;

    const int N = in_sizes[0] / IN_F;
    const int E = in_sizes[2] / EF;

    char* p = (char*)d_ws;
    auto alloc = [&](size_t bytes) { char* r = p; p += (bytes + 255) & ~(size_t)255; return r; };
    int2*  sorted   = (int2*)alloc((size_t)E * sizeof(int2));
    int*   rank     = (int*)alloc((size_t)E * sizeof(int));
    float* degf     = (float*)alloc((size_t)N * sizeof(float));
    float* aggE     = (float*)alloc((size_t)N * EF * sizeof(float));
    int*   counts   = (int*)alloc((size_t)(N + 1) * sizeof(int));
    int*   offsets  = (int*)alloc((size_t)(N + 1) * sizeof(int));
    int*   partials = (int*)alloc(1024 * sizeof(int));
    size_t need_base = (size_t)(p - (char*)d_ws);
    unsigned short* Hb = (unsigned short*)alloc((size_t)N * IN_F * sizeof(unsigned short));
    unsigned short* Ab  = (unsigned short*)alloc((size_t)N * IN_F * sizeof(unsigned short));
    unsigned short* W1t = (unsigned short*)alloc((size_t)IN_F * IN_F * sizeof(unsigned short));
    unsigned short* W2t = (unsigned short*)alloc((size_t)IN_F * IN_F * sizeof(unsigned short));
    unsigned short* WeaTb = (unsigned short*)alloc((size_t)IN_F * 32 * sizeof(unsigned short));
    size_t need_mfma = (size_t)(p - (char*)d_ws);

    const int n_scan = N + 1;
    const int B = (n_scan + 1023) / 1024;

    if (ws_size >= need_mfma && B <= 1024) {
        // fast path: 6 dispatches + 1 memset
        hipMemsetAsync(counts, 0, (size_t)(N + 1) * sizeof(int), stream);
        const int n4 = N * IN_F / 4;
        const int h2b_blocks  = (n4 + 255) / 256;
        const int hist_blocks = (E + 255) / 256;
        const int wea_blocks  = (IN_F * 32 + 255) / 256;   // 16
        pre_kernel<<<h2b_blocks + hist_blocks + 128 + wea_blocks, 256, 0, stream>>>(
            H, Hb, n4, ei, counts, rank, E, W1, W1t, W2, W2t, We, be, WeaTb,
            h2b_blocks, hist_blocks);
        scan_blocks_kernel<<<B, 256, 0, stream>>>(counts, offsets, partials, n_scan);
        scan_add_fused_kernel<<<(n_scan + 255) / 256, 256, 0, stream>>>(offsets, partials, n_scan);
        build_kernel<<<(E + 255) / 256, 256, 0, stream>>>(ei, sorted, offsets, rank, E);
        gather_ea_kernel<<<2 * ((N + 3) / 4), 256, 0, stream>>>(
            Hb, EA, sorted, offsets, Ab, aggE, N);
        mlp_mfma_kernel<<<(N + 63) / 64, 256, 0, stream>>>(
            Ab, W1t, W2t, aggE, offsets, WeaTb, b1, b2, out, N);
    } else if (ws_size >= need_base && B <= 1024) {
        // fp32 CSR fallback
        hipMemsetAsync(counts, 0, (size_t)(N + 1) * sizeof(int), stream);
        hist_kernel<<<(E + 255) / 256, 256, 0, stream>>>(ei, counts, rank, E);
        scan_blocks_kernel<<<B, 256, 0, stream>>>(counts, offsets, partials, n_scan);
        scan_add_fused_kernel<<<(n_scan + 255) / 256, 256, 0, stream>>>(offsets, partials, n_scan);
        build_kernel<<<(E + 255) / 256, 256, 0, stream>>>(ei, sorted, offsets, rank, E);
        gather_f32_kernel<<<(N + 3) / 4, 256, 0, stream>>>(H, EA, sorted, offsets, out, aggE, degf, N);
        node_mlp_kernel<<<(N + 31) / 32, 256, 0, stream>>>(out, aggE, degf, We, be, W1, b1, W2, b2, N);
    } else {
        // atomic-scatter fallback
        float* f_aggE = (float*)d_ws;
        float* f_deg  = f_aggE + (size_t)N * EF;
        hipMemsetAsync(d_out, 0, (size_t)N * IN_F * sizeof(float), stream);
        hipMemsetAsync(d_ws, 0, (size_t)N * (EF + 1) * sizeof(float), stream);
        long long tot = (long long)E * IN_F;
        edge_scatter_kernel<<<(int)((tot + 255) / 256), 256, 0, stream>>>(H, ei, EA, out, f_aggE, f_deg, E);
        node_mlp_kernel<<<(N + 31) / 32, 256, 0, stream>>>(out, f_aggE, f_deg, We, be, W1, b1, W2, b2, N);
    }
}

// Round 9
// 470.270 us; speedup vs baseline: 1.1005x; 1.0230x over previous
//
#include <hip/hip_runtime.h>

#define IN_F 128
#define EF 16

typedef short bf16x8 __attribute__((ext_vector_type(8)));
typedef float f32x4  __attribute__((ext_vector_type(4)));

// bf16 helpers: pack is RNE; unpack low/high halves of a uint holding 2 bf16
__device__ __forceinline__ unsigned short f2b(float f) {
    unsigned b = __float_as_uint(f);
    b += 0x7fffu + ((b >> 16) & 1u);
    return (unsigned short)(b >> 16);
}
__device__ __forceinline__ float blo(unsigned u) { return __uint_as_float(u << 16); }
__device__ __forceinline__ float bhi(unsigned u) { return __uint_as_float(u & 0xffff0000u); }

// ============================ CSR-build path ================================

// hist: standalone so its cost is visible in the top-5 — suspected ~100 us
// (1.6M random atomics). Records per-edge rank for the atomic-free build.
__global__ __launch_bounds__(256) void hist_kernel(
    const int* __restrict__ ei, int* __restrict__ counts,
    int* __restrict__ rank, int E)
{
    int e = blockIdx.x * 256 + threadIdx.x;
    if (e >= E) return;
    rank[e] = atomicAdd(&counts[ei[E + e]], 1);
}

__global__ __launch_bounds__(256) void scan_blocks_kernel(
    const int* __restrict__ in, int* __restrict__ out,
    int* __restrict__ partials, int n)
{
    __shared__ int sdata[256];
    const int t = threadIdx.x;
    const int idx0 = blockIdx.x * 1024 + t * 4;
    int v[4];
    #pragma unroll
    for (int i = 0; i < 4; i++) { int idx = idx0 + i; v[i] = (idx < n) ? in[idx] : 0; }
    int s = v[0] + v[1] + v[2] + v[3];
    sdata[t] = s;
    __syncthreads();
    for (int off = 1; off < 256; off <<= 1) {
        int x = (t >= off) ? sdata[t - off] : 0;
        __syncthreads();
        sdata[t] += x;
        __syncthreads();
    }
    if (t == 255) partials[blockIdx.x] = sdata[255];
    int run = (t > 0) ? sdata[t - 1] : 0;
    #pragma unroll
    for (int i = 0; i < 4; i++) {
        int idx = idx0 + i;
        if (idx < n) out[idx] = run;
        run += v[i];
    }
}

// scan_add (partial-prefix computed in-block) FUSED with the h2b cast:
// scan_add alone fills ~20% of the machine; h2b's streaming blocks ride in
// the same dispatch and use the idle capacity (independent work).
__global__ __launch_bounds__(256) void scan_add_h2b_kernel(
    int* __restrict__ out, const int* __restrict__ partials, int n,
    const float* __restrict__ H, unsigned short* __restrict__ Hb, int n4,
    int sa_blocks)
{
    __shared__ int sw[4];
    const int t = threadIdx.x;
    const int b = blockIdx.x;
    if (b < sa_blocks) {
        const int g = b >> 2;
        int v = 0;
        for (int j = t; j < g; j += 256) v += partials[j];
        #pragma unroll
        for (int off = 1; off < 64; off <<= 1) v += __shfl_xor(v, off, 64);
        if ((t & 63) == 0) sw[t >> 6] = v;
        __syncthreads();
        int P = sw[0] + sw[1] + sw[2] + sw[3];
        int idx = b * 256 + t;
        if (idx < n) out[idx] += P;
    } else {
        int i = (b - sa_blocks) * 256 + t;
        if (i < n4) {
            float4 v = ((const float4*)H)[i];
            ushort4 r;
            r.x = f2b(v.x); r.y = f2b(v.y); r.z = f2b(v.z); r.w = f2b(v.w);
            ((ushort4*)Hb)[i] = r;
        }
    }
}

// standalone scan_add (fp32 fallback path)
__global__ __launch_bounds__(256) void scan_add_fused_kernel(
    int* __restrict__ out, const int* __restrict__ partials, int n)
{
    __shared__ int sw[4];
    const int t = threadIdx.x;
    const int g = blockIdx.x >> 2;
    int v = 0;
    for (int j = t; j < g; j += 256) v += partials[j];
    #pragma unroll
    for (int off = 1; off < 64; off <<= 1) v += __shfl_xor(v, off, 64);
    if ((t & 63) == 0) sw[t >> 6] = v;
    __syncthreads();
    int P = sw[0] + sw[1] + sw[2] + sw[3];
    int idx = blockIdx.x * 256 + t;
    if (idx < n) out[idx] += P;
}

// build (pos = offsets[dst] + rank[e], nt 8B scatter) FUSED with the
// W1/W2 transpose-casts and WeaTb (bf16 [128][32] augmented edge-correction
// operand: col k<16 = (We@W1)^T, col 16 = be@W1, rest 0) — all independent.
__global__ __launch_bounds__(256) void build_wcast_kernel(
    const int* __restrict__ ei, int2* __restrict__ sorted,
    const int* __restrict__ offsets, const int* __restrict__ rank, int E,
    const float* __restrict__ W1, unsigned short* __restrict__ W1t,
    const float* __restrict__ W2, unsigned short* __restrict__ W2t,
    const float* __restrict__ We, const float* __restrict__ be,
    unsigned short* __restrict__ WeaTb,
    int build_blocks)
{
    int b = blockIdx.x;
    if (b < build_blocks) {
        int e = b * 256 + threadIdx.x;
        if (e >= E) return;
        int src = ei[e];
        int dst = ei[E + e];
        int pos = offsets[dst] + rank[e];
        long long v = ((long long)(unsigned)e << 32) | (unsigned)src;  // .x=src,.y=e
        __builtin_nontemporal_store(v, (long long*)&sorted[pos]);
    } else if (b < build_blocks + 128) {
        int idx = (b - build_blocks) * 256 + threadIdx.x; // 0..32767
        int w = idx >> 14;           // 0: W1, 1: W2
        int r = idx & 16383;
        int n = r >> 7, k = r & 127;
        if (w == 0) W1t[n * IN_F + k] = f2b(W1[k * IN_F + n]);
        else        W2t[n * IN_F + k] = f2b(W2[k * IN_F + n]);
    } else {
        // WeaTb[n][k]: k<16 -> sum_j We[k][j]*W1[j][n]; k==16 -> be@W1
        int idx = (b - build_blocks - 128) * 256 + threadIdx.x; // 0..4095
        if (idx < IN_F * 32) {
            int n = idx >> 5, k = idx & 31;
            unsigned short o = 0;
            if (k < EF) {
                float acc = 0.f;
                for (int j = 0; j < IN_F; j++) acc += We[k * IN_F + j] * W1[j * IN_F + n];
                o = f2b(acc);
            } else if (k == EF) {
                float acc = 0.f;
                for (int j = 0; j < IN_F; j++) acc += be[j] * W1[j * IN_F + n];
                o = f2b(acc);
            }
            WeaTb[n * 32 + k] = o;
        }
    }
}

// build v1 (fallback path): (src, e) pairs
__global__ __launch_bounds__(256) void build_kernel(
    const int* __restrict__ ei, int2* __restrict__ sorted,
    const int* __restrict__ offsets, const int* __restrict__ rank, int E)
{
    int e = blockIdx.x * 256 + threadIdx.x;
    if (e >= E) return;
    int src = ei[e];
    int dst = ei[E + e];
    int pos = offsets[dst] + rank[e];
    sorted[pos] = make_int2(src, e);
}

// fused gather + EA segment-sum, co-scheduled in one dispatch:
// even blocks: gather Hb rows -> Ab (bf16) for 4 nodes (latency-bound).
// odd  blocks: EA segment-sum -> aggE for 4 nodes (BW-bound; EA read
// nontemporal — read-once stream must not evict the Hb working set).
__global__ __launch_bounds__(256) void gather_ea_kernel(
    const unsigned short* __restrict__ Hb,
    const float* __restrict__ EA,
    const int2* __restrict__ sorted,
    const int* __restrict__ offsets,
    unsigned short* __restrict__ Ab,    // [N,128] bf16
    float* __restrict__ aggE,           // [N,16]
    int N)
{
    const int bt = blockIdx.x & 1;
    const int bg = blockIdx.x >> 1;
    int n = bg * 4 + (threadIdx.x >> 6);
    if (n >= N) return;
    int lane = threadIdx.x & 63;
    int s = offsets[n];
    int e_end = offsets[n + 1];

    if (bt == 0) {
        // ---- gather: half-waves own alternate edge slots; 32 lanes x 8B/row
        int half = lane >> 5;
        int l32  = lane & 31;
        float a0 = 0.f, a1 = 0.f, a2 = 0.f, a3 = 0.f;
        int i = s + half;
        for (; i + 6 < e_end; i += 8) {
            int s0 = sorted[i].x;
            int s1 = sorted[i + 2].x;
            int s2 = sorted[i + 4].x;
            int s3 = sorted[i + 6].x;
            uint2 u0 = *(const uint2*)(Hb + (long long)s0 * IN_F + l32 * 4);
            uint2 u1 = *(const uint2*)(Hb + (long long)s1 * IN_F + l32 * 4);
            uint2 u2 = *(const uint2*)(Hb + (long long)s2 * IN_F + l32 * 4);
            uint2 u3 = *(const uint2*)(Hb + (long long)s3 * IN_F + l32 * 4);
            a0 += (blo(u0.x) + blo(u1.x)) + (blo(u2.x) + blo(u3.x));
            a1 += (bhi(u0.x) + bhi(u1.x)) + (bhi(u2.x) + bhi(u3.x));
            a2 += (blo(u0.y) + blo(u1.y)) + (blo(u2.y) + blo(u3.y));
            a3 += (bhi(u0.y) + bhi(u1.y)) + (bhi(u2.y) + bhi(u3.y));
        }
        for (; i < e_end; i += 2) {
            int se = sorted[i].x;
            uint2 u = *(const uint2*)(Hb + (long long)se * IN_F + l32 * 4);
            a0 += blo(u.x); a1 += bhi(u.x); a2 += blo(u.y); a3 += bhi(u.y);
        }
        a0 += __shfl_xor(a0, 32, 64);
        a1 += __shfl_xor(a1, 32, 64);
        a2 += __shfl_xor(a2, 32, 64);
        a3 += __shfl_xor(a3, 32, 64);
        if (half == 0) {
            ushort4 o;
            o.x = f2b(a0); o.y = f2b(a1); o.z = f2b(a2); o.w = f2b(a3);
            *(ushort4*)&Ab[(long long)n * IN_F + l32 * 4] = o;
        }
    } else {
        // ---- EA segment-sum: 4 edge slots x 16 feats; one 64B EA row/edge
        int sub = lane >> 4;
        int f   = lane & 15;
        float acc = 0.f;
        int i = s + sub;
        for (; i + 4 < e_end; i += 8) {
            int e0 = sorted[i].y;
            int e1 = sorted[i + 4].y;
            float v0 = __builtin_nontemporal_load(&EA[(long long)e0 * EF + f]);
            float v1 = __builtin_nontemporal_load(&EA[(long long)e1 * EF + f]);
            acc += v0 + v1;
        }
        for (; i < e_end; i += 4) {
            int e0 = sorted[i].y;
            acc += __builtin_nontemporal_load(&EA[(long long)e0 * EF + f]);
        }
        acc += __shfl_xor(acc, 16, 64);
        acc += __shfl_xor(acc, 32, 64);
        if (sub == 0) aggE[n * EF + f] = acc;
    }
}

// gather (fp32 H) fallback — writes agg/aggE/deg for node_mlp path
__global__ __launch_bounds__(256) void gather_f32_kernel(
    const float* __restrict__ H,
    const float* __restrict__ EA,
    const int2* __restrict__ sorted,
    const int* __restrict__ offsets,
    float* __restrict__ agg,
    float* __restrict__ aggE,
    float* __restrict__ degf,
    int N)
{
    int n = blockIdx.x * 4 + (threadIdx.x >> 6);
    if (n >= N) return;
    int lane = threadIdx.x & 63;
    int half = lane >> 5;
    int l32  = lane & 31;
    int s = offsets[n];
    int e_end = offsets[n + 1];
    float4 acc = make_float4(0.f, 0.f, 0.f, 0.f);
    float accE = 0.f;
    int i = s + half;
    for (; i + 6 < e_end; i += 8) {
        int2 s0 = sorted[i];
        int2 s1 = sorted[i + 2];
        int2 s2 = sorted[i + 4];
        int2 s3 = sorted[i + 6];
        float4 v0 = *(const float4*)(H + (long long)s0.x * IN_F + l32 * 4);
        float4 v1 = *(const float4*)(H + (long long)s1.x * IN_F + l32 * 4);
        float4 v2 = *(const float4*)(H + (long long)s2.x * IN_F + l32 * 4);
        float4 v3 = *(const float4*)(H + (long long)s3.x * IN_F + l32 * 4);
        float e0 = 0.f, e1 = 0.f, e2 = 0.f, e3 = 0.f;
        if (l32 < EF) {
            e0 = EA[(long long)s0.y * EF + l32];
            e1 = EA[(long long)s1.y * EF + l32];
            e2 = EA[(long long)s2.y * EF + l32];
            e3 = EA[(long long)s3.y * EF + l32];
        }
        acc.x += (v0.x + v1.x) + (v2.x + v3.x);
        acc.y += (v0.y + v1.y) + (v2.y + v3.y);
        acc.z += (v0.z + v1.z) + (v2.z + v3.z);
        acc.w += (v0.w + v1.w) + (v2.w + v3.w);
        accE  += (e0 + e1) + (e2 + e3);
    }
    for (; i < e_end; i += 2) {
        int2 se = sorted[i];
        float4 v = *(const float4*)(H + (long long)se.x * IN_F + l32 * 4);
        acc.x += v.x; acc.y += v.y; acc.z += v.z; acc.w += v.w;
        if (l32 < EF) accE += EA[(long long)se.y * EF + l32];
    }
    acc.x += __shfl_xor(acc.x, 32, 64);
    acc.y += __shfl_xor(acc.y, 32, 64);
    acc.z += __shfl_xor(acc.z, 32, 64);
    acc.w += __shfl_xor(acc.w, 32, 64);
    accE  += __shfl_xor(accE, 32, 64);
    if (half == 0) {
        *(float4*)(agg + (long long)n * IN_F + l32 * 4) = acc;
        if (l32 < EF) aggE[n * EF + l32] = accE;
        if (l32 == 0) degf[n] = (float)(e_end - s);
    }
}

// ======================= fallback: atomic scatter ===========================
__global__ __launch_bounds__(256) void edge_scatter_kernel(
    const float* __restrict__ H,
    const int* __restrict__ ei,
    const float* __restrict__ EA,
    float* __restrict__ agg,
    float* __restrict__ aggE,
    float* __restrict__ deg,
    int E)
{
    long long gid = (long long)blockIdx.x * 256 + threadIdx.x;
    int e = (int)(gid >> 7);
    if (e >= E) return;
    int f = (int)(gid & 127);
    int src = ei[e];
    int dst = ei[E + e];
    float m = H[(long long)src * IN_F + f];
    atomicAdd(&agg[(long long)dst * IN_F + f], m);
    if (f < EF) atomicAdd(&aggE[dst * EF + f], EA[e * EF + f]);
    if (f == 0) atomicAdd(&deg[dst], 1.0f);
}

// ========================= MFMA node-MLP path ===============================

// fused 2-layer MLP on MFMA. Edge correction folded in as ONE extra MFMA
// per output tile via augmented operands:
//   corr = [aggE | deg | 0] (64x32) @ [Wea ; bea ; 0] (32x128)   (bf16 MFMA)
//   h = relu(corr + Ab@W1 + b1);  out = h@W2 + b2
#define XPITCH 136
__global__ __launch_bounds__(256) void mlp_mfma_kernel(
    const unsigned short* __restrict__ Ab,
    const unsigned short* __restrict__ W1t,
    const unsigned short* __restrict__ W2t,
    const float* __restrict__ aggE,     // [N,16]
    const int* __restrict__ offsets,    // [N+1] (deg = diff)
    const unsigned short* __restrict__ WeaTb, // [128][32] bf16 augmented
    const float* __restrict__ b1, const float* __restrict__ b2,
    float* __restrict__ out, int N)
{
    __shared__ unsigned short sW[128 * XPITCH];   // 34816 B
    __shared__ unsigned short sX[64 * XPITCH];    // 17408 B
    const int t    = threadIdx.x;
    const int tile = blockIdx.x * 64;
    const int lane = t & 63;
    const int wv   = t >> 6;          // 0..3
    const int quad = lane >> 4;       // 0..3
    const int lr   = lane & 15;
    const int M0   = wv * 16;

    // stage A tile (64 rows x 16 uint4) and W1t (128 rows x 16 uint4)
    {
        const uint4 z = make_uint4(0, 0, 0, 0);
        #pragma unroll
        for (int j = 0; j < 4; j++) {
            int idx = t + 256 * j;                 // 0..1023
            int row = idx >> 4, c = idx & 15;
            uint4 v = z;
            if (tile + row < N) v = ((const uint4*)Ab)[(long long)(tile + row) * 16 + c];
            ((uint4*)sX)[row * 17 + c] = v;
        }
        #pragma unroll
        for (int j = 0; j < 8; j++) {
            int idx = t + 256 * j;                 // 0..2047
            int row = idx >> 4, c = idx & 15;
            ((uint4*)sW)[row * 17 + c] = ((const uint4*)W1t)[idx];
        }
    }

    // augmented A fragment (in registers; each lane reads ITS row's aggE slice)
    // A-frag layout for 16x16x32: row = lr, k = quad*8 + j.
    bf16x8 afE = (bf16x8){0, 0, 0, 0, 0, 0, 0, 0};
    {
        int grow = tile + M0 + lr;
        if (grow < N) {
            if (quad < 2) {
                const float* ap = &aggE[(long long)grow * EF + quad * 8];
                #pragma unroll
                for (int j = 0; j < 8; j++) afE[j] = (short)f2b(ap[j]);
            } else if (quad == 2) {
                afE[0] = (short)f2b((float)(offsets[grow + 1] - offsets[grow]));
            }
        }
    }
    __syncthreads();

    f32x4 acc[8];
    bf16x8 af[4];
    const f32x4 zero = {0.f, 0.f, 0.f, 0.f};

    // phase 2: h = relu(corr + A@W1 + b1) -> sX rows M0..M0+15 (wave-private)
    #pragma unroll
    for (int kt = 0; kt < 4; kt++)
        af[kt] = *(const bf16x8*)&sX[(M0 + lr) * XPITCH + kt * 32 + quad * 8];
    #pragma unroll
    for (int nt = 0; nt < 8; nt++) {
        bf16x8 bfE = *(const bf16x8*)&WeaTb[(nt * 16 + lr) * 32 + quad * 8];
        acc[nt] = __builtin_amdgcn_mfma_f32_16x16x32_bf16(afE, bfE, zero, 0, 0, 0);
        #pragma unroll
        for (int kt = 0; kt < 4; kt++) {
            bf16x8 bf = *(const bf16x8*)&sW[(nt * 16 + lr) * XPITCH + kt * 32 + quad * 8];
            acc[nt] = __builtin_amdgcn_mfma_f32_16x16x32_bf16(af[kt], bf, acc[nt], 0, 0, 0);
        }
    }
    #pragma unroll
    for (int nt = 0; nt < 8; nt++) {
        int col = nt * 16 + lr;
        float bias = b1[col];
        #pragma unroll
        for (int r = 0; r < 4; r++) {
            float v = fmaxf(acc[nt][r] + bias, 0.f);
            sX[(M0 + quad * 4 + r) * XPITCH + col] = f2b(v);
        }
    }
    __syncthreads();    // all waves done reading W1t
    #pragma unroll
    for (int j = 0; j < 8; j++) {
        int idx = t + 256 * j;
        int row = idx >> 4, c = idx & 15;
        ((uint4*)sW)[row * 17 + c] = ((const uint4*)W2t)[idx];
    }
    __syncthreads();

    // phase 3: out = h @ W2 + b2
    #pragma unroll
    for (int kt = 0; kt < 4; kt++)
        af[kt] = *(const bf16x8*)&sX[(M0 + lr) * XPITCH + kt * 32 + quad * 8];
    #pragma unroll
    for (int nt = 0; nt < 8; nt++) {
        acc[nt] = zero;
        #pragma unroll
        for (int kt = 0; kt < 4; kt++) {
            bf16x8 bf = *(const bf16x8*)&sW[(nt * 16 + lr) * XPITCH + kt * 32 + quad * 8];
            acc[nt] = __builtin_amdgcn_mfma_f32_16x16x32_bf16(af[kt], bf, acc[nt], 0, 0, 0);
        }
    }
    #pragma unroll
    for (int nt = 0; nt < 8; nt++) {
        int col = nt * 16 + lr;
        float bias = b2[col];
        #pragma unroll
        for (int r = 0; r < 4; r++) {
            int row = tile + M0 + quad * 4 + r;
            if (row < N)
                __builtin_nontemporal_store(acc[nt][r] + bias,
                                            &out[(long long)row * IN_F + col]);
        }
    }
}

// ================== fp32 node MLP (fallback path only) ======================
__global__ __launch_bounds__(256) void node_mlp_kernel(
    float* agg_out,
    const float* __restrict__ aggE,
    const float* __restrict__ degf,
    const float* __restrict__ We, const float* __restrict__ be,
    const float* __restrict__ W1, const float* __restrict__ b1,
    const float* __restrict__ W2, const float* __restrict__ b2,
    int N)
{
    __shared__ float sA[32][IN_F];
    __shared__ float sH[32][IN_F];
    const int t  = threadIdx.x;
    const int c4 = (t & 31) * 4;
    const int r0 = t >> 5;

    const int tile = blockIdx.x * 32;
    if (tile >= N) return;
    int rows = N - tile;
    if (rows > 32) rows = 32;

    {
        const float4 bev = *(const float4*)&be[c4];
        #pragma unroll
        for (int i = 0; i < 4; i++) {
            int rr = r0 + 8 * i;
            float4 v = make_float4(0.f, 0.f, 0.f, 0.f);
            if (rr < rows) {
                long long r = tile + rr;
                v = *(const float4*)&agg_out[r * IN_F + c4];
                float d = degf[r];
                v.x += d * bev.x; v.y += d * bev.y; v.z += d * bev.z; v.w += d * bev.w;
                #pragma unroll
                for (int k = 0; k < EF; k++) {
                    float a = aggE[r * EF + k];
                    float4 w = *(const float4*)&We[k * IN_F + c4];
                    v.x += a * w.x; v.y += a * w.y; v.z += a * w.z; v.w += a * w.w;
                }
            }
            *(float4*)&sA[rr][c4] = v;
        }
    }
    __syncthreads();
    {
        const float4 bv = *(const float4*)&b1[c4];
        float4 a0 = bv, a1 = bv, a2 = bv, a3 = bv;
        for (int k = 0; k < IN_F; k++) {
            float4 w = *(const float4*)&W1[k * IN_F + c4];
            float x0 = sA[r0][k], x1 = sA[r0 + 8][k], x2 = sA[r0 + 16][k], x3 = sA[r0 + 24][k];
            a0.x += x0 * w.x; a0.y += x0 * w.y; a0.z += x0 * w.z; a0.w += x0 * w.w;
            a1.x += x1 * w.x; a1.y += x1 * w.y; a1.z += x1 * w.z; a1.w += x1 * w.w;
            a2.x += x2 * w.x; a2.y += x2 * w.y; a2.z += x2 * w.z; a2.w += x2 * w.w;
            a3.x += x3 * w.x; a3.y += x3 * w.y; a3.z += x3 * w.z; a3.w += x3 * w.w;
        }
        a0.x = fmaxf(a0.x, 0.f); a0.y = fmaxf(a0.y, 0.f); a0.z = fmaxf(a0.z, 0.f); a0.w = fmaxf(a0.w, 0.f);
        a1.x = fmaxf(a1.x, 0.f); a1.y = fmaxf(a1.y, 0.f); a1.z = fmaxf(a1.z, 0.f); a1.w = fmaxf(a1.w, 0.f);
        a2.x = fmaxf(a2.x, 0.f); a2.y = fmaxf(a2.y, 0.f); a2.z = fmaxf(a2.z, 0.f); a2.w = fmaxf(a2.w, 0.f);
        a3.x = fmaxf(a3.x, 0.f); a3.y = fmaxf(a3.y, 0.f); a3.z = fmaxf(a3.z, 0.f); a3.w = fmaxf(a3.w, 0.f);
        *(float4*)&sH[r0][c4]      = a0;
        *(float4*)&sH[r0 + 8][c4]  = a1;
        *(float4*)&sH[r0 + 16][c4] = a2;
        *(float4*)&sH[r0 + 24][c4] = a3;
    }
    __syncthreads();
    {
        const float4 bv = *(const float4*)&b2[c4];
        float4 a0 = bv, a1 = bv, a2 = bv, a3 = bv;
        for (int k = 0; k < IN_F; k++) {
            float4 w = *(const float4*)&W2[k * IN_F + c4];
            float x0 = sH[r0][k], x1 = sH[r0 + 8][k], x2 = sH[r0 + 16][k], x3 = sH[r0 + 24][k];
            a0.x += x0 * w.x; a0.y += x0 * w.y; a0.z += x0 * w.z; a0.w += x0 * w.w;
            a1.x += x1 * w.x; a1.y += x1 * w.y; a1.z += x1 * w.z; a1.w += x1 * w.w;
            a2.x += x2 * w.x; a2.y += x2 * w.y; a2.z += x2 * w.z; a2.w += x2 * w.w;
            a3.x += x3 * w.x; a3.y += x3 * w.y; a3.z += x3 * w.z; a3.w += x3 * w.w;
        }
        #pragma unroll
        for (int i = 0; i < 4; i++) {
            int rr = r0 + 8 * i;
            if (rr < rows) {
                float4 v = (i == 0) ? a0 : (i == 1) ? a1 : (i == 2) ? a2 : a3;
                *(float4*)&agg_out[(long long)(tile + rr) * IN_F + c4] = v;
            }
        }
    }
}

// ================================ host ======================================
extern "C" void kernel_launch(void* const* d_in, const int* in_sizes, int n_in,
                              void* d_out, int out_size, void* d_ws, size_t ws_size,
                              hipStream_t stream) {
    const float* H  = (const float*)d_in[0];
    const int*   ei = (const int*)d_in[1];     // int32 [2,E]
    const float* EA = (const float*)d_in[2];
    const float* We = (const float*)d_in[3];
    const float* be = (const float*)d_in[4];
    const float* W1 = (const float*)d_in[5];
    const float* b1 = (const float*)d_in[6];
    const float* W2 = (const float*)d_in[7];
    const float* b2 = (const float*)d_in[8];
    float* out = (float*)d_out;

    const int N = in_sizes[0] / IN_F;
    const int E = in_sizes[2] / EF;

    char* p = (char*)d_ws;
    auto alloc = [&](size_t bytes) { char* r = p; p += (bytes + 255) & ~(size_t)255; return r; };
    int2*  sorted   = (int2*)alloc((size_t)E * sizeof(int2));
    int*   rank     = (int*)alloc((size_t)E * sizeof(int));
    float* degf     = (float*)alloc((size_t)N * sizeof(float));
    float* aggE     = (float*)alloc((size_t)N * EF * sizeof(float));
    int*   counts   = (int*)alloc((size_t)(N + 1) * sizeof(int));
    int*   offsets  = (int*)alloc((size_t)(N + 1) * sizeof(int));
    int*   partials = (int*)alloc(1024 * sizeof(int));
    size_t need_base = (size_t)(p - (char*)d_ws);
    unsigned short* Hb = (unsigned short*)alloc((size_t)N * IN_F * sizeof(unsigned short));
    unsigned short* Ab  = (unsigned short*)alloc((size_t)N * IN_F * sizeof(unsigned short));
    unsigned short* W1t = (unsigned short*)alloc((size_t)IN_F * IN_F * sizeof(unsigned short));
    unsigned short* W2t = (unsigned short*)alloc((size_t)IN_F * IN_F * sizeof(unsigned short));
    unsigned short* WeaTb = (unsigned short*)alloc((size_t)IN_F * 32 * sizeof(unsigned short));
    size_t need_mfma = (size_t)(p - (char*)d_ws);

    const int n_scan = N + 1;
    const int B = (n_scan + 1023) / 1024;

    if (ws_size >= need_mfma && B <= 1024) {
        // fast path: 6 dispatches + 1 memset
        hipMemsetAsync(counts, 0, (size_t)(N + 1) * sizeof(int), stream);
        const int n4 = N * IN_F / 4;
        const int h2b_blocks   = (n4 + 255) / 256;
        const int hist_blocks  = (E + 255) / 256;
        const int sa_blocks    = (n_scan + 255) / 256;
        const int build_blocks = (E + 255) / 256;
        const int wea_blocks   = (IN_F * 32 + 255) / 256;   // 16
        hist_kernel<<<hist_blocks, 256, 0, stream>>>(ei, counts, rank, E);
        scan_blocks_kernel<<<B, 256, 0, stream>>>(counts, offsets, partials, n_scan);
        scan_add_h2b_kernel<<<sa_blocks + h2b_blocks, 256, 0, stream>>>(
            offsets, partials, n_scan, H, Hb, n4, sa_blocks);
        build_wcast_kernel<<<build_blocks + 128 + wea_blocks, 256, 0, stream>>>(
            ei, sorted, offsets, rank, E, W1, W1t, W2, W2t, We, be, WeaTb,
            build_blocks);
        gather_ea_kernel<<<2 * ((N + 3) / 4), 256, 0, stream>>>(
            Hb, EA, sorted, offsets, Ab, aggE, N);
        mlp_mfma_kernel<<<(N + 63) / 64, 256, 0, stream>>>(
            Ab, W1t, W2t, aggE, offsets, WeaTb, b1, b2, out, N);
    } else if (ws_size >= need_base && B <= 1024) {
        // fp32 CSR fallback
        hipMemsetAsync(counts, 0, (size_t)(N + 1) * sizeof(int), stream);
        hist_kernel<<<(E + 255) / 256, 256, 0, stream>>>(ei, counts, rank, E);
        scan_blocks_kernel<<<B, 256, 0, stream>>>(counts, offsets, partials, n_scan);
        scan_add_fused_kernel<<<(n_scan + 255) / 256, 256, 0, stream>>>(offsets, partials, n_scan);
        build_kernel<<<(E + 255) / 256, 256, 0, stream>>>(ei, sorted, offsets, rank, E);
        gather_f32_kernel<<<(N + 3) / 4, 256, 0, stream>>>(H, EA, sorted, offsets, out, aggE, degf, N);
        node_mlp_kernel<<<(N + 31) / 32, 256, 0, stream>>>(out, aggE, degf, We, be, W1, b1, W2, b2, N);
    } else {
        // atomic-scatter fallback
        float* f_aggE = (float*)d_ws;
        float* f_deg  = f_aggE + (size_t)N * EF;
        hipMemsetAsync(d_out, 0, (size_t)N * IN_F * sizeof(float), stream);
        hipMemsetAsync(d_ws, 0, (size_t)N * (EF + 1) * sizeof(float), stream);
        long long tot = (long long)E * IN_F;
        edge_scatter_kernel<<<(int)((tot + 255) / 256), 256, 0, stream>>>(H, ei, EA, out, f_aggE, f_deg, E);
        node_mlp_kernel<<<(N + 31) / 32, 256, 0, stream>>>(out, f_aggE, f_deg, We, be, W1, b1, W2, b2, N);
    }
}

// Round 10
// 469.842 us; speedup vs baseline: 1.1015x; 1.0009x over previous
//
#include <hip/hip_runtime.h>

#define IN_F 128
#define EF 16

typedef short bf16x8 __attribute__((ext_vector_type(8)));
typedef float f32x4  __attribute__((ext_vector_type(4)));

// bf16 helpers: pack is RNE; unpack low/high halves of a uint holding 2 bf16
__device__ __forceinline__ unsigned short f2b(float f) {
    unsigned b = __float_as_uint(f);
    b += 0x7fffu + ((b >> 16) & 1u);
    return (unsigned short)(b >> 16);
}
__device__ __forceinline__ float blo(unsigned u) { return __uint_as_float(u << 16); }
__device__ __forceinline__ float bhi(unsigned u) { return __uint_as_float(u & 0xffff0000u); }

// ============================ CSR-build path ================================

// hist + EA->bf16 cast, parity-interleaved in ONE dispatch:
// hist blocks are atomic-latency-bound (near-zero BW); the streaming cast
// blocks co-schedule against them (same principle as gather_ea's even/odd).
__global__ __launch_bounds__(256) void hist_eab_kernel(
    const int* __restrict__ ei, int* __restrict__ counts,
    int* __restrict__ rank, int E,
    const float* __restrict__ EA, unsigned short* __restrict__ EAb,
    int hist_blocks, int n8)
{
    int b = blockIdx.x;
    int type, idx;
    if (b < 2 * hist_blocks) { type = b & 1; idx = b >> 1; }
    else                     { type = 0;     idx = b - hist_blocks; }
    if (type == 1) {
        int e = idx * 256 + threadIdx.x;
        if (e < E) rank[e] = atomicAdd(&counts[ei[E + e]], 1);
    } else {
        int i = idx * 256 + threadIdx.x;     // one thread = 8 floats = 32B
        if (i < n8) {
            const float4* s4 = (const float4*)EA + (long long)i * 2;
            float4 v0 = s4[0], v1 = s4[1];
            uint4 o;
            o.x = (unsigned)f2b(v0.x) | ((unsigned)f2b(v0.y) << 16);
            o.y = (unsigned)f2b(v0.z) | ((unsigned)f2b(v0.w) << 16);
            o.z = (unsigned)f2b(v1.x) | ((unsigned)f2b(v1.y) << 16);
            o.w = (unsigned)f2b(v1.z) | ((unsigned)f2b(v1.w) << 16);
            ((uint4*)EAb)[i] = o;
        }
    }
}

// plain hist (no-EAb fast path + fp32 CSR fallback path)
__global__ __launch_bounds__(256) void hist_kernel(
    const int* __restrict__ ei, int* __restrict__ counts,
    int* __restrict__ rank, int E)
{
    int e = blockIdx.x * 256 + threadIdx.x;
    if (e >= E) return;
    rank[e] = atomicAdd(&counts[ei[E + e]], 1);
}

__global__ __launch_bounds__(256) void scan_blocks_kernel(
    const int* __restrict__ in, int* __restrict__ out,
    int* __restrict__ partials, int n)
{
    __shared__ int sdata[256];
    const int t = threadIdx.x;
    const int idx0 = blockIdx.x * 1024 + t * 4;
    int v[4];
    #pragma unroll
    for (int i = 0; i < 4; i++) { int idx = idx0 + i; v[i] = (idx < n) ? in[idx] : 0; }
    int s = v[0] + v[1] + v[2] + v[3];
    sdata[t] = s;
    __syncthreads();
    for (int off = 1; off < 256; off <<= 1) {
        int x = (t >= off) ? sdata[t - off] : 0;
        __syncthreads();
        sdata[t] += x;
        __syncthreads();
    }
    if (t == 255) partials[blockIdx.x] = sdata[255];
    int run = (t > 0) ? sdata[t - 1] : 0;
    #pragma unroll
    for (int i = 0; i < 4; i++) {
        int idx = idx0 + i;
        if (idx < n) out[idx] = run;
        run += v[i];
    }
}

// scan_add (partial-prefix computed in-block) FUSED with the h2b cast.
__global__ __launch_bounds__(256) void scan_add_h2b_kernel(
    int* __restrict__ out, const int* __restrict__ partials, int n,
    const float* __restrict__ H, unsigned short* __restrict__ Hb, int n4,
    int sa_blocks)
{
    __shared__ int sw[4];
    const int t = threadIdx.x;
    const int b = blockIdx.x;
    if (b < sa_blocks) {
        const int g = b >> 2;
        int v = 0;
        for (int j = t; j < g; j += 256) v += partials[j];
        #pragma unroll
        for (int off = 1; off < 64; off <<= 1) v += __shfl_xor(v, off, 64);
        if ((t & 63) == 0) sw[t >> 6] = v;
        __syncthreads();
        int P = sw[0] + sw[1] + sw[2] + sw[3];
        int idx = b * 256 + t;
        if (idx < n) out[idx] += P;
    } else {
        int i = (b - sa_blocks) * 256 + t;
        if (i < n4) {
            float4 v = ((const float4*)H)[i];
            ushort4 r;
            r.x = f2b(v.x); r.y = f2b(v.y); r.z = f2b(v.z); r.w = f2b(v.w);
            ((ushort4*)Hb)[i] = r;
        }
    }
}

// standalone scan_add (fp32 fallback path)
__global__ __launch_bounds__(256) void scan_add_fused_kernel(
    int* __restrict__ out, const int* __restrict__ partials, int n)
{
    __shared__ int sw[4];
    const int t = threadIdx.x;
    const int g = blockIdx.x >> 2;
    int v = 0;
    for (int j = t; j < g; j += 256) v += partials[j];
    #pragma unroll
    for (int off = 1; off < 64; off <<= 1) v += __shfl_xor(v, off, 64);
    if ((t & 63) == 0) sw[t >> 6] = v;
    __syncthreads();
    int P = sw[0] + sw[1] + sw[2] + sw[3];
    int idx = blockIdx.x * 256 + t;
    if (idx < n) out[idx] += P;
}

// build (pos = offsets[dst] + rank[e], nt 8B scatter) FUSED with the
// W1/W2 transpose-casts and WeaTb (bf16 [128][32] augmented edge-correction
// operand: col k<16 = (We@W1)^T, col 16 = be@W1, rest 0) — all independent.
__global__ __launch_bounds__(256) void build_wcast_kernel(
    const int* __restrict__ ei, int2* __restrict__ sorted,
    const int* __restrict__ offsets, const int* __restrict__ rank, int E,
    const float* __restrict__ W1, unsigned short* __restrict__ W1t,
    const float* __restrict__ W2, unsigned short* __restrict__ W2t,
    const float* __restrict__ We, const float* __restrict__ be,
    unsigned short* __restrict__ WeaTb,
    int build_blocks)
{
    int b = blockIdx.x;
    if (b < build_blocks) {
        int e = b * 256 + threadIdx.x;
        if (e >= E) return;
        int src = ei[e];
        int dst = ei[E + e];
        int pos = offsets[dst] + rank[e];
        long long v = ((long long)(unsigned)e << 32) | (unsigned)src;  // .x=src,.y=e
        __builtin_nontemporal_store(v, (long long*)&sorted[pos]);
    } else if (b < build_blocks + 128) {
        int idx = (b - build_blocks) * 256 + threadIdx.x; // 0..32767
        int w = idx >> 14;           // 0: W1, 1: W2
        int r = idx & 16383;
        int n = r >> 7, k = r & 127;
        if (w == 0) W1t[n * IN_F + k] = f2b(W1[k * IN_F + n]);
        else        W2t[n * IN_F + k] = f2b(W2[k * IN_F + n]);
    } else {
        // WeaTb[n][k]: k<16 -> sum_j We[k][j]*W1[j][n]; k==16 -> be@W1
        int idx = (b - build_blocks - 128) * 256 + threadIdx.x; // 0..4095
        if (idx < IN_F * 32) {
            int n = idx >> 5, k = idx & 31;
            unsigned short o = 0;
            if (k < EF) {
                float acc = 0.f;
                for (int j = 0; j < IN_F; j++) acc += We[k * IN_F + j] * W1[j * IN_F + n];
                o = f2b(acc);
            } else if (k == EF) {
                float acc = 0.f;
                for (int j = 0; j < IN_F; j++) acc += be[j] * W1[j * IN_F + n];
                o = f2b(acc);
            }
            WeaTb[n * 32 + k] = o;
        }
    }
}

// build v1 (fallback path): (src, e) pairs
__global__ __launch_bounds__(256) void build_kernel(
    const int* __restrict__ ei, int2* __restrict__ sorted,
    const int* __restrict__ offsets, const int* __restrict__ rank, int E)
{
    int e = blockIdx.x * 256 + threadIdx.x;
    if (e >= E) return;
    int src = ei[e];
    int dst = ei[E + e];
    int pos = offsets[dst] + rank[e];
    sorted[pos] = make_int2(src, e);
}

// fused gather + EA segment-sum, co-scheduled in one dispatch:
// even blocks: gather Hb rows -> Ab (bf16) for 4 nodes (latency-bound).
// odd  blocks: EA segment-sum -> aggE (BW-bound). If EAb != nullptr the
// EA stream is bf16 (32B rows: 8 edge slots x 8 lanes x 1 uint = 2 feats),
// halving the EA fetch; else fp32 path (round-9 behavior).
__global__ __launch_bounds__(256) void gather_ea_kernel(
    const unsigned short* __restrict__ Hb,
    const float* __restrict__ EA,
    const unsigned short* __restrict__ EAb,   // bf16 [E,16] or nullptr
    const int2* __restrict__ sorted,
    const int* __restrict__ offsets,
    unsigned short* __restrict__ Ab,    // [N,128] bf16
    float* __restrict__ aggE,           // [N,16]
    int N)
{
    const int bt = blockIdx.x & 1;
    const int bg = blockIdx.x >> 1;
    int n = bg * 4 + (threadIdx.x >> 6);
    if (n >= N) return;
    int lane = threadIdx.x & 63;
    int s = offsets[n];
    int e_end = offsets[n + 1];

    if (bt == 0) {
        // ---- gather: half-waves own alternate edge slots; 32 lanes x 8B/row
        int half = lane >> 5;
        int l32  = lane & 31;
        float a0 = 0.f, a1 = 0.f, a2 = 0.f, a3 = 0.f;
        int i = s + half;
        for (; i + 6 < e_end; i += 8) {
            int s0 = sorted[i].x;
            int s1 = sorted[i + 2].x;
            int s2 = sorted[i + 4].x;
            int s3 = sorted[i + 6].x;
            uint2 u0 = *(const uint2*)(Hb + (long long)s0 * IN_F + l32 * 4);
            uint2 u1 = *(const uint2*)(Hb + (long long)s1 * IN_F + l32 * 4);
            uint2 u2 = *(const uint2*)(Hb + (long long)s2 * IN_F + l32 * 4);
            uint2 u3 = *(const uint2*)(Hb + (long long)s3 * IN_F + l32 * 4);
            a0 += (blo(u0.x) + blo(u1.x)) + (blo(u2.x) + blo(u3.x));
            a1 += (bhi(u0.x) + bhi(u1.x)) + (bhi(u2.x) + bhi(u3.x));
            a2 += (blo(u0.y) + blo(u1.y)) + (blo(u2.y) + blo(u3.y));
            a3 += (bhi(u0.y) + bhi(u1.y)) + (bhi(u2.y) + bhi(u3.y));
        }
        for (; i < e_end; i += 2) {
            int se = sorted[i].x;
            uint2 u = *(const uint2*)(Hb + (long long)se * IN_F + l32 * 4);
            a0 += blo(u.x); a1 += bhi(u.x); a2 += blo(u.y); a3 += bhi(u.y);
        }
        a0 += __shfl_xor(a0, 32, 64);
        a1 += __shfl_xor(a1, 32, 64);
        a2 += __shfl_xor(a2, 32, 64);
        a3 += __shfl_xor(a3, 32, 64);
        if (half == 0) {
            ushort4 o;
            o.x = f2b(a0); o.y = f2b(a1); o.z = f2b(a2); o.w = f2b(a3);
            *(ushort4*)&Ab[(long long)n * IN_F + l32 * 4] = o;
        }
    } else if (EAb) {
        // ---- EA segment-sum (bf16): 8 edge slots x 8 lanes (2 feats/lane)
        int sub = lane >> 3;       // 0..7 edge slot
        int fp  = lane & 7;        // feature pair: feats 2fp, 2fp+1
        float acc0 = 0.f, acc1 = 0.f;
        int i = s + sub;
        for (; i + 8 < e_end; i += 16) {
            int e0 = sorted[i].y;
            int e1 = sorted[i + 8].y;
            unsigned u0 = __builtin_nontemporal_load((const unsigned*)(EAb + (long long)e0 * EF) + fp);
            unsigned u1 = __builtin_nontemporal_load((const unsigned*)(EAb + (long long)e1 * EF) + fp);
            acc0 += blo(u0) + blo(u1);
            acc1 += bhi(u0) + bhi(u1);
        }
        for (; i < e_end; i += 8) {
            int e0 = sorted[i].y;
            unsigned u0 = __builtin_nontemporal_load((const unsigned*)(EAb + (long long)e0 * EF) + fp);
            acc0 += blo(u0); acc1 += bhi(u0);
        }
        acc0 += __shfl_xor(acc0, 8, 64);  acc1 += __shfl_xor(acc1, 8, 64);
        acc0 += __shfl_xor(acc0, 16, 64); acc1 += __shfl_xor(acc1, 16, 64);
        acc0 += __shfl_xor(acc0, 32, 64); acc1 += __shfl_xor(acc1, 32, 64);
        if (sub == 0) {
            aggE[n * EF + 2 * fp]     = acc0;
            aggE[n * EF + 2 * fp + 1] = acc1;
        }
    } else {
        // ---- EA segment-sum (fp32): 4 edge slots x 16 feats; 64B row/edge
        int sub = lane >> 4;
        int f   = lane & 15;
        float acc = 0.f;
        int i = s + sub;
        for (; i + 4 < e_end; i += 8) {
            int e0 = sorted[i].y;
            int e1 = sorted[i + 4].y;
            float v0 = __builtin_nontemporal_load(&EA[(long long)e0 * EF + f]);
            float v1 = __builtin_nontemporal_load(&EA[(long long)e1 * EF + f]);
            acc += v0 + v1;
        }
        for (; i < e_end; i += 4) {
            int e0 = sorted[i].y;
            acc += __builtin_nontemporal_load(&EA[(long long)e0 * EF + f]);
        }
        acc += __shfl_xor(acc, 16, 64);
        acc += __shfl_xor(acc, 32, 64);
        if (sub == 0) aggE[n * EF + f] = acc;
    }
}

// gather (fp32 H) fallback — writes agg/aggE/deg for node_mlp path
__global__ __launch_bounds__(256) void gather_f32_kernel(
    const float* __restrict__ H,
    const float* __restrict__ EA,
    const int2* __restrict__ sorted,
    const int* __restrict__ offsets,
    float* __restrict__ agg,
    float* __restrict__ aggE,
    float* __restrict__ degf,
    int N)
{
    int n = blockIdx.x * 4 + (threadIdx.x >> 6);
    if (n >= N) return;
    int lane = threadIdx.x & 63;
    int half = lane >> 5;
    int l32  = lane & 31;
    int s = offsets[n];
    int e_end = offsets[n + 1];
    float4 acc = make_float4(0.f, 0.f, 0.f, 0.f);
    float accE = 0.f;
    int i = s + half;
    for (; i + 6 < e_end; i += 8) {
        int2 s0 = sorted[i];
        int2 s1 = sorted[i + 2];
        int2 s2 = sorted[i + 4];
        int2 s3 = sorted[i + 6];
        float4 v0 = *(const float4*)(H + (long long)s0.x * IN_F + l32 * 4);
        float4 v1 = *(const float4*)(H + (long long)s1.x * IN_F + l32 * 4);
        float4 v2 = *(const float4*)(H + (long long)s2.x * IN_F + l32 * 4);
        float4 v3 = *(const float4*)(H + (long long)s3.x * IN_F + l32 * 4);
        float e0 = 0.f, e1 = 0.f, e2 = 0.f, e3 = 0.f;
        if (l32 < EF) {
            e0 = EA[(long long)s0.y * EF + l32];
            e1 = EA[(long long)s1.y * EF + l32];
            e2 = EA[(long long)s2.y * EF + l32];
            e3 = EA[(long long)s3.y * EF + l32];
        }
        acc.x += (v0.x + v1.x) + (v2.x + v3.x);
        acc.y += (v0.y + v1.y) + (v2.y + v3.y);
        acc.z += (v0.z + v1.z) + (v2.z + v3.z);
        acc.w += (v0.w + v1.w) + (v2.w + v3.w);
        accE  += (e0 + e1) + (e2 + e3);
    }
    for (; i < e_end; i += 2) {
        int2 se = sorted[i];
        float4 v = *(const float4*)(H + (long long)se.x * IN_F + l32 * 4);
        acc.x += v.x; acc.y += v.y; acc.z += v.z; acc.w += v.w;
        if (l32 < EF) accE += EA[(long long)se.y * EF + l32];
    }
    acc.x += __shfl_xor(acc.x, 32, 64);
    acc.y += __shfl_xor(acc.y, 32, 64);
    acc.z += __shfl_xor(acc.z, 32, 64);
    acc.w += __shfl_xor(acc.w, 32, 64);
    accE  += __shfl_xor(accE, 32, 64);
    if (half == 0) {
        *(float4*)(agg + (long long)n * IN_F + l32 * 4) = acc;
        if (l32 < EF) aggE[n * EF + l32] = accE;
        if (l32 == 0) degf[n] = (float)(e_end - s);
    }
}

// ======================= fallback: atomic scatter ===========================
__global__ __launch_bounds__(256) void edge_scatter_kernel(
    const float* __restrict__ H,
    const int* __restrict__ ei,
    const float* __restrict__ EA,
    float* __restrict__ agg,
    float* __restrict__ aggE,
    float* __restrict__ deg,
    int E)
{
    long long gid = (long long)blockIdx.x * 256 + threadIdx.x;
    int e = (int)(gid >> 7);
    if (e >= E) return;
    int f = (int)(gid & 127);
    int src = ei[e];
    int dst = ei[E + e];
    float m = H[(long long)src * IN_F + f];
    atomicAdd(&agg[(long long)dst * IN_F + f], m);
    if (f < EF) atomicAdd(&aggE[dst * EF + f], EA[e * EF + f]);
    if (f == 0) atomicAdd(&deg[dst], 1.0f);
}

// ========================= MFMA node-MLP path ===============================

// fused 2-layer MLP on MFMA. Edge correction folded in as ONE extra MFMA
// per output tile via augmented operands:
//   corr = [aggE | deg | 0] (64x32) @ [Wea ; bea ; 0] (32x128)   (bf16 MFMA)
//   h = relu(corr + Ab@W1 + b1);  out = h@W2 + b2
#define XPITCH 136
__global__ __launch_bounds__(256) void mlp_mfma_kernel(
    const unsigned short* __restrict__ Ab,
    const unsigned short* __restrict__ W1t,
    const unsigned short* __restrict__ W2t,
    const float* __restrict__ aggE,     // [N,16]
    const int* __restrict__ offsets,    // [N+1] (deg = diff)
    const unsigned short* __restrict__ WeaTb, // [128][32] bf16 augmented
    const float* __restrict__ b1, const float* __restrict__ b2,
    float* __restrict__ out, int N)
{
    __shared__ unsigned short sW[128 * XPITCH];   // 34816 B
    __shared__ unsigned short sX[64 * XPITCH];    // 17408 B
    const int t    = threadIdx.x;
    const int tile = blockIdx.x * 64;
    const int lane = t & 63;
    const int wv   = t >> 6;          // 0..3
    const int quad = lane >> 4;       // 0..3
    const int lr   = lane & 15;
    const int M0   = wv * 16;

    // stage A tile (64 rows x 16 uint4) and W1t (128 rows x 16 uint4)
    {
        const uint4 z = make_uint4(0, 0, 0, 0);
        #pragma unroll
        for (int j = 0; j < 4; j++) {
            int idx = t + 256 * j;                 // 0..1023
            int row = idx >> 4, c = idx & 15;
            uint4 v = z;
            if (tile + row < N) v = ((const uint4*)Ab)[(long long)(tile + row) * 16 + c];
            ((uint4*)sX)[row * 17 + c] = v;
        }
        #pragma unroll
        for (int j = 0; j < 8; j++) {
            int idx = t + 256 * j;                 // 0..2047
            int row = idx >> 4, c = idx & 15;
            ((uint4*)sW)[row * 17 + c] = ((const uint4*)W1t)[idx];
        }
    }

    // augmented A fragment (in registers; each lane reads ITS row's aggE slice)
    // A-frag layout for 16x16x32: row = lr, k = quad*8 + j.
    bf16x8 afE = (bf16x8){0, 0, 0, 0, 0, 0, 0, 0};
    {
        int grow = tile + M0 + lr;
        if (grow < N) {
            if (quad < 2) {
                const float* ap = &aggE[(long long)grow * EF + quad * 8];
                #pragma unroll
                for (int j = 0; j < 8; j++) afE[j] = (short)f2b(ap[j]);
            } else if (quad == 2) {
                afE[0] = (short)f2b((float)(offsets[grow + 1] - offsets[grow]));
            }
        }
    }
    __syncthreads();

    f32x4 acc[8];
    bf16x8 af[4];
    const f32x4 zero = {0.f, 0.f, 0.f, 0.f};

    // phase 2: h = relu(corr + A@W1 + b1) -> sX rows M0..M0+15 (wave-private)
    #pragma unroll
    for (int kt = 0; kt < 4; kt++)
        af[kt] = *(const bf16x8*)&sX[(M0 + lr) * XPITCH + kt * 32 + quad * 8];
    #pragma unroll
    for (int nt = 0; nt < 8; nt++) {
        bf16x8 bfE = *(const bf16x8*)&WeaTb[(nt * 16 + lr) * 32 + quad * 8];
        acc[nt] = __builtin_amdgcn_mfma_f32_16x16x32_bf16(afE, bfE, zero, 0, 0, 0);
        #pragma unroll
        for (int kt = 0; kt < 4; kt++) {
            bf16x8 bf = *(const bf16x8*)&sW[(nt * 16 + lr) * XPITCH + kt * 32 + quad * 8];
            acc[nt] = __builtin_amdgcn_mfma_f32_16x16x32_bf16(af[kt], bf, acc[nt], 0, 0, 0);
        }
    }
    #pragma unroll
    for (int nt = 0; nt < 8; nt++) {
        int col = nt * 16 + lr;
        float bias = b1[col];
        #pragma unroll
        for (int r = 0; r < 4; r++) {
            float v = fmaxf(acc[nt][r] + bias, 0.f);
            sX[(M0 + quad * 4 + r) * XPITCH + col] = f2b(v);
        }
    }
    __syncthreads();    // all waves done reading W1t
    #pragma unroll
    for (int j = 0; j < 8; j++) {
        int idx = t + 256 * j;
        int row = idx >> 4, c = idx & 15;
        ((uint4*)sW)[row * 17 + c] = ((const uint4*)W2t)[idx];
    }
    __syncthreads();

    // phase 3: out = h @ W2 + b2
    #pragma unroll
    for (int kt = 0; kt < 4; kt++)
        af[kt] = *(const bf16x8*)&sX[(M0 + lr) * XPITCH + kt * 32 + quad * 8];
    #pragma unroll
    for (int nt = 0; nt < 8; nt++) {
        acc[nt] = zero;
        #pragma unroll
        for (int kt = 0; kt < 4; kt++) {
            bf16x8 bf = *(const bf16x8*)&sW[(nt * 16 + lr) * XPITCH + kt * 32 + quad * 8];
            acc[nt] = __builtin_amdgcn_mfma_f32_16x16x32_bf16(af[kt], bf, acc[nt], 0, 0, 0);
        }
    }
    #pragma unroll
    for (int nt = 0; nt < 8; nt++) {
        int col = nt * 16 + lr;
        float bias = b2[col];
        #pragma unroll
        for (int r = 0; r < 4; r++) {
            int row = tile + M0 + quad * 4 + r;
            if (row < N)
                __builtin_nontemporal_store(acc[nt][r] + bias,
                                            &out[(long long)row * IN_F + col]);
        }
    }
}

// ================== fp32 node MLP (fallback path only) ======================
__global__ __launch_bounds__(256) void node_mlp_kernel(
    float* agg_out,
    const float* __restrict__ aggE,
    const float* __restrict__ degf,
    const float* __restrict__ We, const float* __restrict__ be,
    const float* __restrict__ W1, const float* __restrict__ b1,
    const float* __restrict__ W2, const float* __restrict__ b2,
    int N)
{
    __shared__ float sA[32][IN_F];
    __shared__ float sH[32][IN_F];
    const int t  = threadIdx.x;
    const int c4 = (t & 31) * 4;
    const int r0 = t >> 5;

    const int tile = blockIdx.x * 32;
    if (tile >= N) return;
    int rows = N - tile;
    if (rows > 32) rows = 32;

    {
        const float4 bev = *(const float4*)&be[c4];
        #pragma unroll
        for (int i = 0; i < 4; i++) {
            int rr = r0 + 8 * i;
            float4 v = make_float4(0.f, 0.f, 0.f, 0.f);
            if (rr < rows) {
                long long r = tile + rr;
                v = *(const float4*)&agg_out[r * IN_F + c4];
                float d = degf[r];
                v.x += d * bev.x; v.y += d * bev.y; v.z += d * bev.z; v.w += d * bev.w;
                #pragma unroll
                for (int k = 0; k < EF; k++) {
                    float a = aggE[r * EF + k];
                    float4 w = *(const float4*)&We[k * IN_F + c4];
                    v.x += a * w.x; v.y += a * w.y; v.z += a * w.z; v.w += a * w.w;
                }
            }
            *(float4*)&sA[rr][c4] = v;
        }
    }
    __syncthreads();
    {
        const float4 bv = *(const float4*)&b1[c4];
        float4 a0 = bv, a1 = bv, a2 = bv, a3 = bv;
        for (int k = 0; k < IN_F; k++) {
            float4 w = *(const float4*)&W1[k * IN_F + c4];
            float x0 = sA[r0][k], x1 = sA[r0 + 8][k], x2 = sA[r0 + 16][k], x3 = sA[r0 + 24][k];
            a0.x += x0 * w.x; a0.y += x0 * w.y; a0.z += x0 * w.z; a0.w += x0 * w.w;
            a1.x += x1 * w.x; a1.y += x1 * w.y; a1.z += x1 * w.z; a1.w += x1 * w.w;
            a2.x += x2 * w.x; a2.y += x2 * w.y; a2.z += x2 * w.z; a2.w += x2 * w.w;
            a3.x += x3 * w.x; a3.y += x3 * w.y; a3.z += x3 * w.z; a3.w += x3 * w.w;
        }
        a0.x = fmaxf(a0.x, 0.f); a0.y = fmaxf(a0.y, 0.f); a0.z = fmaxf(a0.z, 0.f); a0.w = fmaxf(a0.w, 0.f);
        a1.x = fmaxf(a1.x, 0.f); a1.y = fmaxf(a1.y, 0.f); a1.z = fmaxf(a1.z, 0.f); a1.w = fmaxf(a1.w, 0.f);
        a2.x = fmaxf(a2.x, 0.f); a2.y = fmaxf(a2.y, 0.f); a2.z = fmaxf(a2.z, 0.f); a2.w = fmaxf(a2.w, 0.f);
        a3.x = fmaxf(a3.x, 0.f); a3.y = fmaxf(a3.y, 0.f); a3.z = fmaxf(a3.z, 0.f); a3.w = fmaxf(a3.w, 0.f);
        *(float4*)&sH[r0][c4]      = a0;
        *(float4*)&sH[r0 + 8][c4]  = a1;
        *(float4*)&sH[r0 + 16][c4] = a2;
        *(float4*)&sH[r0 + 24][c4] = a3;
    }
    __syncthreads();
    {
        const float4 bv = *(const float4*)&b2[c4];
        float4 a0 = bv, a1 = bv, a2 = bv, a3 = bv;
        for (int k = 0; k < IN_F; k++) {
            float4 w = *(const float4*)&W2[k * IN_F + c4];
            float x0 = sH[r0][k], x1 = sH[r0 + 8][k], x2 = sH[r0 + 16][k], x3 = sH[r0 + 24][k];
            a0.x += x0 * w.x; a0.y += x0 * w.y; a0.z += x0 * w.z; a0.w += x0 * w.w;
            a1.x += x1 * w.x; a1.y += x1 * w.y; a1.z += x1 * w.z; a1.w += x1 * w.w;
            a2.x += x2 * w.x; a2.y += x2 * w.y; a2.z += x2 * w.z; a2.w += x2 * w.w;
            a3.x += x3 * w.x; a3.y += x3 * w.y; a3.z += x3 * w.z; a3.w += x3 * w.w;
        }
        #pragma unroll
        for (int i = 0; i < 4; i++) {
            int rr = r0 + 8 * i;
            if (rr < rows) {
                float4 v = (i == 0) ? a0 : (i == 1) ? a1 : (i == 2) ? a2 : a3;
                *(float4*)&agg_out[(long long)(tile + rr) * IN_F + c4] = v;
            }
        }
    }
}

// ================================ host ======================================
extern "C" void kernel_launch(void* const* d_in, const int* in_sizes, int n_in,
                              void* d_out, int out_size, void* d_ws, size_t ws_size,
                              hipStream_t stream) {
    const float* H  = (const float*)d_in[0];
    const int*   ei = (const int*)d_in[1];     // int32 [2,E]
    const float* EA = (const float*)d_in[2];
    const float* We = (const float*)d_in[3];
    const float* be = (const float*)d_in[4];
    const float* W1 = (const float*)d_in[5];
    const float* b1 = (const float*)d_in[6];
    const float* W2 = (const float*)d_in[7];
    const float* b2 = (const float*)d_in[8];
    float* out = (float*)d_out;

    const int N = in_sizes[0] / IN_F;
    const int E = in_sizes[2] / EF;

    char* p = (char*)d_ws;
    auto alloc = [&](size_t bytes) { char* r = p; p += (bytes + 255) & ~(size_t)255; return r; };
    int2*  sorted   = (int2*)alloc((size_t)E * sizeof(int2));
    int*   rank     = (int*)alloc((size_t)E * sizeof(int));
    float* degf     = (float*)alloc((size_t)N * sizeof(float));
    float* aggE     = (float*)alloc((size_t)N * EF * sizeof(float));
    int*   counts   = (int*)alloc((size_t)(N + 1) * sizeof(int));
    int*   offsets  = (int*)alloc((size_t)(N + 1) * sizeof(int));
    int*   partials = (int*)alloc(1024 * sizeof(int));
    size_t need_base = (size_t)(p - (char*)d_ws);
    unsigned short* Hb = (unsigned short*)alloc((size_t)N * IN_F * sizeof(unsigned short));
    unsigned short* Ab  = (unsigned short*)alloc((size_t)N * IN_F * sizeof(unsigned short));
    unsigned short* W1t = (unsigned short*)alloc((size_t)IN_F * IN_F * sizeof(unsigned short));
    unsigned short* W2t = (unsigned short*)alloc((size_t)IN_F * IN_F * sizeof(unsigned short));
    unsigned short* WeaTb = (unsigned short*)alloc((size_t)IN_F * 32 * sizeof(unsigned short));
    size_t need_mfma = (size_t)(p - (char*)d_ws);
    unsigned short* EAb = (unsigned short*)alloc((size_t)E * EF * sizeof(unsigned short));
    size_t need_eab = (size_t)(p - (char*)d_ws);

    const int n_scan = N + 1;
    const int B = (n_scan + 1023) / 1024;

    if (ws_size >= need_mfma && B <= 1024) {
        // fast path: 6 dispatches + 1 memset
        hipMemsetAsync(counts, 0, (size_t)(N + 1) * sizeof(int), stream);
        const int n4 = N * IN_F / 4;
        const int h2b_blocks   = (n4 + 255) / 256;
        const int hist_blocks  = (E + 255) / 256;
        const int sa_blocks    = (n_scan + 255) / 256;
        const int build_blocks = (E + 255) / 256;
        const int wea_blocks   = (IN_F * 32 + 255) / 256;   // 16
        const bool use_eab = (ws_size >= need_eab);
        if (use_eab) {
            const int n8 = E * EF / 8;                       // 32B per thread
            const int cast_blocks = (n8 + 255) / 256;
            hist_eab_kernel<<<hist_blocks + cast_blocks, 256, 0, stream>>>(
                ei, counts, rank, E, EA, EAb, hist_blocks, n8);
        } else {
            hist_kernel<<<hist_blocks, 256, 0, stream>>>(ei, counts, rank, E);
        }
        scan_blocks_kernel<<<B, 256, 0, stream>>>(counts, offsets, partials, n_scan);
        scan_add_h2b_kernel<<<sa_blocks + h2b_blocks, 256, 0, stream>>>(
            offsets, partials, n_scan, H, Hb, n4, sa_blocks);
        build_wcast_kernel<<<build_blocks + 128 + wea_blocks, 256, 0, stream>>>(
            ei, sorted, offsets, rank, E, W1, W1t, W2, W2t, We, be, WeaTb,
            build_blocks);
        gather_ea_kernel<<<2 * ((N + 3) / 4), 256, 0, stream>>>(
            Hb, EA, use_eab ? EAb : (const unsigned short*)nullptr,
            sorted, offsets, Ab, aggE, N);
        mlp_mfma_kernel<<<(N + 63) / 64, 256, 0, stream>>>(
            Ab, W1t, W2t, aggE, offsets, WeaTb, b1, b2, out, N);
    } else if (ws_size >= need_base && B <= 1024) {
        // fp32 CSR fallback
        hipMemsetAsync(counts, 0, (size_t)(N + 1) * sizeof(int), stream);
        hist_kernel<<<(E + 255) / 256, 256, 0, stream>>>(ei, counts, rank, E);
        scan_blocks_kernel<<<B, 256, 0, stream>>>(counts, offsets, partials, n_scan);
        scan_add_fused_kernel<<<(n_scan + 255) / 256, 256, 0, stream>>>(offsets, partials, n_scan);
        build_kernel<<<(E + 255) / 256, 256, 0, stream>>>(ei, sorted, offsets, rank, E);
        gather_f32_kernel<<<(N + 3) / 4, 256, 0, stream>>>(H, EA, sorted, offsets, out, aggE, degf, N);
        node_mlp_kernel<<<(N + 31) / 32, 256, 0, stream>>>(out, aggE, degf, We, be, W1, b1, W2, b2, N);
    } else {
        // atomic-scatter fallback
        float* f_aggE = (float*)d_ws;
        float* f_deg  = f_aggE + (size_t)N * EF;
        hipMemsetAsync(d_out, 0, (size_t)N * IN_F * sizeof(float), stream);
        hipMemsetAsync(d_ws, 0, (size_t)N * (EF + 1) * sizeof(float), stream);
        long long tot = (long long)E * IN_F;
        edge_scatter_kernel<<<(int)((tot + 255) / 256), 256, 0, stream>>>(H, ei, EA, out, f_aggE, f_deg, E);
        node_mlp_kernel<<<(N + 31) / 32, 256, 0, stream>>>(out, f_aggE, f_deg, We, be, W1, b1, W2, b2, N);
    }
}

// Round 11
// 448.980 us; speedup vs baseline: 1.1527x; 1.0465x over previous
//
#include <hip/hip_runtime.h>

#define IN_F 128
#define EF 16

typedef short bf16x8 __attribute__((ext_vector_type(8)));
typedef float f32x4  __attribute__((ext_vector_type(4)));

// bf16 helpers: pack is RNE; unpack low/high halves of a uint holding 2 bf16
__device__ __forceinline__ unsigned short f2b(float f) {
    unsigned b = __float_as_uint(f);
    b += 0x7fffu + ((b >> 16) & 1u);
    return (unsigned short)(b >> 16);
}
__device__ __forceinline__ float blo(unsigned u) { return __uint_as_float(u << 16); }
__device__ __forceinline__ float bhi(unsigned u) { return __uint_as_float(u & 0xffff0000u); }

// ============================ CSR-build path ================================

// hist: records per-edge rank for the atomic-free build.
__global__ __launch_bounds__(256) void hist_kernel(
    const int* __restrict__ ei, int* __restrict__ counts,
    int* __restrict__ rank, int E)
{
    int e = blockIdx.x * 256 + threadIdx.x;
    if (e >= E) return;
    rank[e] = atomicAdd(&counts[ei[E + e]], 1);
}

__global__ __launch_bounds__(256) void scan_blocks_kernel(
    const int* __restrict__ in, int* __restrict__ out,
    int* __restrict__ partials, int n)
{
    __shared__ int sdata[256];
    const int t = threadIdx.x;
    const int idx0 = blockIdx.x * 1024 + t * 4;
    int v[4];
    #pragma unroll
    for (int i = 0; i < 4; i++) { int idx = idx0 + i; v[i] = (idx < n) ? in[idx] : 0; }
    int s = v[0] + v[1] + v[2] + v[3];
    sdata[t] = s;
    __syncthreads();
    for (int off = 1; off < 256; off <<= 1) {
        int x = (t >= off) ? sdata[t - off] : 0;
        __syncthreads();
        sdata[t] += x;
        __syncthreads();
    }
    if (t == 255) partials[blockIdx.x] = sdata[255];
    int run = (t > 0) ? sdata[t - 1] : 0;
    #pragma unroll
    for (int i = 0; i < 4; i++) {
        int idx = idx0 + i;
        if (idx < n) out[idx] = run;
        run += v[i];
    }
}

// scan_add (partial-prefix computed in-block) FUSED with the h2b cast.
__global__ __launch_bounds__(256) void scan_add_h2b_kernel(
    int* __restrict__ out, const int* __restrict__ partials, int n,
    const float* __restrict__ H, unsigned short* __restrict__ Hb, int n4,
    int sa_blocks)
{
    __shared__ int sw[4];
    const int t = threadIdx.x;
    const int b = blockIdx.x;
    if (b < sa_blocks) {
        const int g = b >> 2;
        int v = 0;
        for (int j = t; j < g; j += 256) v += partials[j];
        #pragma unroll
        for (int off = 1; off < 64; off <<= 1) v += __shfl_xor(v, off, 64);
        if ((t & 63) == 0) sw[t >> 6] = v;
        __syncthreads();
        int P = sw[0] + sw[1] + sw[2] + sw[3];
        int idx = b * 256 + t;
        if (idx < n) out[idx] += P;
    } else {
        int i = (b - sa_blocks) * 256 + t;
        if (i < n4) {
            float4 v = ((const float4*)H)[i];
            ushort4 r;
            r.x = f2b(v.x); r.y = f2b(v.y); r.z = f2b(v.z); r.w = f2b(v.w);
            ((ushort4*)Hb)[i] = r;
        }
    }
}

// standalone scan_add (fp32 fallback path)
__global__ __launch_bounds__(256) void scan_add_fused_kernel(
    int* __restrict__ out, const int* __restrict__ partials, int n)
{
    __shared__ int sw[4];
    const int t = threadIdx.x;
    const int g = blockIdx.x >> 2;
    int v = 0;
    for (int j = t; j < g; j += 256) v += partials[j];
    #pragma unroll
    for (int off = 1; off < 64; off <<= 1) v += __shfl_xor(v, off, 64);
    if ((t & 63) == 0) sw[t >> 6] = v;
    __syncthreads();
    int P = sw[0] + sw[1] + sw[2] + sw[3];
    int idx = blockIdx.x * 256 + t;
    if (idx < n) out[idx] += P;
}

// build (pos = offsets[dst] + rank[e], nt 8B scatter) FUSED with the
// W1/W2 transpose-casts and WeaTb (bf16 [128][32] augmented edge-correction
// operand: col k<16 = (We@W1)^T, col 16 = be@W1, rest 0) — all independent.
__global__ __launch_bounds__(256) void build_wcast_kernel(
    const int* __restrict__ ei, int2* __restrict__ sorted,
    const int* __restrict__ offsets, const int* __restrict__ rank, int E,
    const float* __restrict__ W1, unsigned short* __restrict__ W1t,
    const float* __restrict__ W2, unsigned short* __restrict__ W2t,
    const float* __restrict__ We, const float* __restrict__ be,
    unsigned short* __restrict__ WeaTb,
    int build_blocks)
{
    int b = blockIdx.x;
    if (b < build_blocks) {
        int e = b * 256 + threadIdx.x;
        if (e >= E) return;
        int src = ei[e];
        int dst = ei[E + e];
        int pos = offsets[dst] + rank[e];
        long long v = ((long long)(unsigned)e << 32) | (unsigned)src;  // .x=src,.y=e
        __builtin_nontemporal_store(v, (long long*)&sorted[pos]);
    } else if (b < build_blocks + 128) {
        int idx = (b - build_blocks) * 256 + threadIdx.x; // 0..32767
        int w = idx >> 14;           // 0: W1, 1: W2
        int r = idx & 16383;
        int n = r >> 7, k = r & 127;
        if (w == 0) W1t[n * IN_F + k] = f2b(W1[k * IN_F + n]);
        else        W2t[n * IN_F + k] = f2b(W2[k * IN_F + n]);
    } else {
        // WeaTb[n][k]: k<16 -> sum_j We[k][j]*W1[j][n]; k==16 -> be@W1
        int idx = (b - build_blocks - 128) * 256 + threadIdx.x; // 0..4095
        if (idx < IN_F * 32) {
            int n = idx >> 5, k = idx & 31;
            unsigned short o = 0;
            if (k < EF) {
                float acc = 0.f;
                for (int j = 0; j < IN_F; j++) acc += We[k * IN_F + j] * W1[j * IN_F + n];
                o = f2b(acc);
            } else if (k == EF) {
                float acc = 0.f;
                for (int j = 0; j < IN_F; j++) acc += be[j] * W1[j * IN_F + n];
                o = f2b(acc);
            }
            WeaTb[n * 32 + k] = o;
        }
    }
}

// build v1 (fallback path): (src, e) pairs
__global__ __launch_bounds__(256) void build_kernel(
    const int* __restrict__ ei, int2* __restrict__ sorted,
    const int* __restrict__ offsets, const int* __restrict__ rank, int E)
{
    int e = blockIdx.x * 256 + threadIdx.x;
    if (e >= E) return;
    int src = ei[e];
    int dst = ei[E + e];
    int pos = offsets[dst] + rank[e];
    sorted[pos] = make_int2(src, e);
}

// fused gather + EA segment-sum, co-scheduled in one dispatch.
// Both sides widened to 16B/lane loads (coalescing sweet spot; 2x per-wave
// outstanding bytes vs round 10 — the concurrency lever for a latency-bound
// random-row phase):
//  even blocks (gather): 4 edge slots (sub) x 16 lanes; lane loads uint4 =
//    8 bf16 feats of its slot's Hb row; unroll x4 -> 16 rows in flight.
//  odd blocks (EA-sum): 16 edge slots x 4 lanes; lane loads float4 = 4 feats;
//    unroll x2 -> 32 rows in flight; nt loads (read-once stream).
__global__ __launch_bounds__(256) void gather_ea_kernel(
    const unsigned short* __restrict__ Hb,
    const float* __restrict__ EA,
    const int2* __restrict__ sorted,
    const int* __restrict__ offsets,
    unsigned short* __restrict__ Ab,    // [N,128] bf16
    float* __restrict__ aggE,           // [N,16]
    int N)
{
    const int bt = blockIdx.x & 1;
    const int bg = blockIdx.x >> 1;
    int n = bg * 4 + (threadIdx.x >> 6);
    if (n >= N) return;
    int lane = threadIdx.x & 63;
    int s = offsets[n];
    int e_end = offsets[n + 1];

    if (bt == 0) {
        // ---- gather: sub = edge slot (0..3), fq = feature quad (8 feats)
        int sub = lane >> 4;
        int fq  = lane & 15;
        float a0 = 0.f, a1 = 0.f, a2 = 0.f, a3 = 0.f;
        float a4 = 0.f, a5 = 0.f, a6 = 0.f, a7 = 0.f;
        int i = s + sub;
        for (; i + 12 < e_end; i += 16) {
            int r0 = sorted[i].x;
            int r1 = sorted[i + 4].x;
            int r2 = sorted[i + 8].x;
            int r3 = sorted[i + 12].x;
            uint4 u0 = *(const uint4*)(Hb + (long long)r0 * IN_F + fq * 8);
            uint4 u1 = *(const uint4*)(Hb + (long long)r1 * IN_F + fq * 8);
            uint4 u2 = *(const uint4*)(Hb + (long long)r2 * IN_F + fq * 8);
            uint4 u3 = *(const uint4*)(Hb + (long long)r3 * IN_F + fq * 8);
            a0 += (blo(u0.x) + blo(u1.x)) + (blo(u2.x) + blo(u3.x));
            a1 += (bhi(u0.x) + bhi(u1.x)) + (bhi(u2.x) + bhi(u3.x));
            a2 += (blo(u0.y) + blo(u1.y)) + (blo(u2.y) + blo(u3.y));
            a3 += (bhi(u0.y) + bhi(u1.y)) + (bhi(u2.y) + bhi(u3.y));
            a4 += (blo(u0.z) + blo(u1.z)) + (blo(u2.z) + blo(u3.z));
            a5 += (bhi(u0.z) + bhi(u1.z)) + (bhi(u2.z) + bhi(u3.z));
            a6 += (blo(u0.w) + blo(u1.w)) + (blo(u2.w) + blo(u3.w));
            a7 += (bhi(u0.w) + bhi(u1.w)) + (bhi(u2.w) + bhi(u3.w));
        }
        for (; i < e_end; i += 4) {
            int r0 = sorted[i].x;
            uint4 u = *(const uint4*)(Hb + (long long)r0 * IN_F + fq * 8);
            a0 += blo(u.x); a1 += bhi(u.x);
            a2 += blo(u.y); a3 += bhi(u.y);
            a4 += blo(u.z); a5 += bhi(u.z);
            a6 += blo(u.w); a7 += bhi(u.w);
        }
        // reduce across the 4 slots (lane bits 4,5)
        a0 += __shfl_xor(a0, 16, 64); a1 += __shfl_xor(a1, 16, 64);
        a2 += __shfl_xor(a2, 16, 64); a3 += __shfl_xor(a3, 16, 64);
        a4 += __shfl_xor(a4, 16, 64); a5 += __shfl_xor(a5, 16, 64);
        a6 += __shfl_xor(a6, 16, 64); a7 += __shfl_xor(a7, 16, 64);
        a0 += __shfl_xor(a0, 32, 64); a1 += __shfl_xor(a1, 32, 64);
        a2 += __shfl_xor(a2, 32, 64); a3 += __shfl_xor(a3, 32, 64);
        a4 += __shfl_xor(a4, 32, 64); a5 += __shfl_xor(a5, 32, 64);
        a6 += __shfl_xor(a6, 32, 64); a7 += __shfl_xor(a7, 32, 64);
        if (sub == 0) {
            uint4 o;
            o.x = (unsigned)f2b(a0) | ((unsigned)f2b(a1) << 16);
            o.y = (unsigned)f2b(a2) | ((unsigned)f2b(a3) << 16);
            o.z = (unsigned)f2b(a4) | ((unsigned)f2b(a5) << 16);
            o.w = (unsigned)f2b(a6) | ((unsigned)f2b(a7) << 16);
            *(uint4*)&Ab[(long long)n * IN_F + fq * 8] = o;
        }
    } else {
        // ---- EA segment-sum: sub = edge slot (0..15), q = feature quad
        int sub = lane >> 2;
        int q   = lane & 3;
        f32x4 acc = {0.f, 0.f, 0.f, 0.f};
        int i = s + sub;
        for (; i + 16 < e_end; i += 32) {
            int e0 = sorted[i].y;
            int e1 = sorted[i + 16].y;
            f32x4 v0 = __builtin_nontemporal_load(
                (const f32x4*)(EA + (long long)e0 * EF + q * 4));
            f32x4 v1 = __builtin_nontemporal_load(
                (const f32x4*)(EA + (long long)e1 * EF + q * 4));
            acc += v0 + v1;
        }
        for (; i < e_end; i += 16) {
            int e0 = sorted[i].y;
            acc += __builtin_nontemporal_load(
                (const f32x4*)(EA + (long long)e0 * EF + q * 4));
        }
        // reduce across the 16 slots (lane bits 2..5)
        #pragma unroll
        for (int off = 4; off < 64; off <<= 1) {
            acc[0] += __shfl_xor(acc[0], off, 64);
            acc[1] += __shfl_xor(acc[1], off, 64);
            acc[2] += __shfl_xor(acc[2], off, 64);
            acc[3] += __shfl_xor(acc[3], off, 64);
        }
        if (sub == 0) *(f32x4*)&aggE[n * EF + q * 4] = acc;
    }
}

// gather (fp32 H) fallback — writes agg/aggE/deg for node_mlp path
__global__ __launch_bounds__(256) void gather_f32_kernel(
    const float* __restrict__ H,
    const float* __restrict__ EA,
    const int2* __restrict__ sorted,
    const int* __restrict__ offsets,
    float* __restrict__ agg,
    float* __restrict__ aggE,
    float* __restrict__ degf,
    int N)
{
    int n = blockIdx.x * 4 + (threadIdx.x >> 6);
    if (n >= N) return;
    int lane = threadIdx.x & 63;
    int half = lane >> 5;
    int l32  = lane & 31;
    int s = offsets[n];
    int e_end = offsets[n + 1];
    float4 acc = make_float4(0.f, 0.f, 0.f, 0.f);
    float accE = 0.f;
    int i = s + half;
    for (; i + 6 < e_end; i += 8) {
        int2 s0 = sorted[i];
        int2 s1 = sorted[i + 2];
        int2 s2 = sorted[i + 4];
        int2 s3 = sorted[i + 6];
        float4 v0 = *(const float4*)(H + (long long)s0.x * IN_F + l32 * 4);
        float4 v1 = *(const float4*)(H + (long long)s1.x * IN_F + l32 * 4);
        float4 v2 = *(const float4*)(H + (long long)s2.x * IN_F + l32 * 4);
        float4 v3 = *(const float4*)(H + (long long)s3.x * IN_F + l32 * 4);
        float e0 = 0.f, e1 = 0.f, e2 = 0.f, e3 = 0.f;
        if (l32 < EF) {
            e0 = EA[(long long)s0.y * EF + l32];
            e1 = EA[(long long)s1.y * EF + l32];
            e2 = EA[(long long)s2.y * EF + l32];
            e3 = EA[(long long)s3.y * EF + l32];
        }
        acc.x += (v0.x + v1.x) + (v2.x + v3.x);
        acc.y += (v0.y + v1.y) + (v2.y + v3.y);
        acc.z += (v0.z + v1.z) + (v2.z + v3.z);
        acc.w += (v0.w + v1.w) + (v2.w + v3.w);
        accE  += (e0 + e1) + (e2 + e3);
    }
    for (; i < e_end; i += 2) {
        int2 se = sorted[i];
        float4 v = *(const float4*)(H + (long long)se.x * IN_F + l32 * 4);
        acc.x += v.x; acc.y += v.y; acc.z += v.z; acc.w += v.w;
        if (l32 < EF) accE += EA[(long long)se.y * EF + l32];
    }
    acc.x += __shfl_xor(acc.x, 32, 64);
    acc.y += __shfl_xor(acc.y, 32, 64);
    acc.z += __shfl_xor(acc.z, 32, 64);
    acc.w += __shfl_xor(acc.w, 32, 64);
    accE  += __shfl_xor(accE, 32, 64);
    if (half == 0) {
        *(float4*)(agg + (long long)n * IN_F + l32 * 4) = acc;
        if (l32 < EF) aggE[n * EF + l32] = accE;
        if (l32 == 0) degf[n] = (float)(e_end - s);
    }
}

// ======================= fallback: atomic scatter ===========================
__global__ __launch_bounds__(256) void edge_scatter_kernel(
    const float* __restrict__ H,
    const int* __restrict__ ei,
    const float* __restrict__ EA,
    float* __restrict__ agg,
    float* __restrict__ aggE,
    float* __restrict__ deg,
    int E)
{
    long long gid = (long long)blockIdx.x * 256 + threadIdx.x;
    int e = (int)(gid >> 7);
    if (e >= E) return;
    int f = (int)(gid & 127);
    int src = ei[e];
    int dst = ei[E + e];
    float m = H[(long long)src * IN_F + f];
    atomicAdd(&agg[(long long)dst * IN_F + f], m);
    if (f < EF) atomicAdd(&aggE[dst * EF + f], EA[e * EF + f]);
    if (f == 0) atomicAdd(&deg[dst], 1.0f);
}

// ========================= MFMA node-MLP path ===============================

// fused 2-layer MLP on MFMA. Edge correction folded in as ONE extra MFMA
// per output tile via augmented operands:
//   corr = [aggE | deg | 0] (64x32) @ [Wea ; bea ; 0] (32x128)   (bf16 MFMA)
//   h = relu(corr + Ab@W1 + b1);  out = h@W2 + b2
#define XPITCH 136
__global__ __launch_bounds__(256) void mlp_mfma_kernel(
    const unsigned short* __restrict__ Ab,
    const unsigned short* __restrict__ W1t,
    const unsigned short* __restrict__ W2t,
    const float* __restrict__ aggE,     // [N,16]
    const int* __restrict__ offsets,    // [N+1] (deg = diff)
    const unsigned short* __restrict__ WeaTb, // [128][32] bf16 augmented
    const float* __restrict__ b1, const float* __restrict__ b2,
    float* __restrict__ out, int N)
{
    __shared__ unsigned short sW[128 * XPITCH];   // 34816 B
    __shared__ unsigned short sX[64 * XPITCH];    // 17408 B
    const int t    = threadIdx.x;
    const int tile = blockIdx.x * 64;
    const int lane = t & 63;
    const int wv   = t >> 6;          // 0..3
    const int quad = lane >> 4;       // 0..3
    const int lr   = lane & 15;
    const int M0   = wv * 16;

    // stage A tile (64 rows x 16 uint4) and W1t (128 rows x 16 uint4)
    {
        const uint4 z = make_uint4(0, 0, 0, 0);
        #pragma unroll
        for (int j = 0; j < 4; j++) {
            int idx = t + 256 * j;                 // 0..1023
            int row = idx >> 4, c = idx & 15;
            uint4 v = z;
            if (tile + row < N) v = ((const uint4*)Ab)[(long long)(tile + row) * 16 + c];
            ((uint4*)sX)[row * 17 + c] = v;
        }
        #pragma unroll
        for (int j = 0; j < 8; j++) {
            int idx = t + 256 * j;                 // 0..2047
            int row = idx >> 4, c = idx & 15;
            ((uint4*)sW)[row * 17 + c] = ((const uint4*)W1t)[idx];
        }
    }

    // augmented A fragment (in registers; each lane reads ITS row's aggE slice)
    // A-frag layout for 16x16x32: row = lr, k = quad*8 + j.
    bf16x8 afE = (bf16x8){0, 0, 0, 0, 0, 0, 0, 0};
    {
        int grow = tile + M0 + lr;
        if (grow < N) {
            if (quad < 2) {
                const float* ap = &aggE[(long long)grow * EF + quad * 8];
                #pragma unroll
                for (int j = 0; j < 8; j++) afE[j] = (short)f2b(ap[j]);
            } else if (quad == 2) {
                afE[0] = (short)f2b((float)(offsets[grow + 1] - offsets[grow]));
            }
        }
    }
    __syncthreads();

    f32x4 acc[8];
    bf16x8 af[4];
    const f32x4 zero = {0.f, 0.f, 0.f, 0.f};

    // phase 2: h = relu(corr + A@W1 + b1) -> sX rows M0..M0+15 (wave-private)
    #pragma unroll
    for (int kt = 0; kt < 4; kt++)
        af[kt] = *(const bf16x8*)&sX[(M0 + lr) * XPITCH + kt * 32 + quad * 8];
    #pragma unroll
    for (int nt = 0; nt < 8; nt++) {
        bf16x8 bfE = *(const bf16x8*)&WeaTb[(nt * 16 + lr) * 32 + quad * 8];
        acc[nt] = __builtin_amdgcn_mfma_f32_16x16x32_bf16(afE, bfE, zero, 0, 0, 0);
        #pragma unroll
        for (int kt = 0; kt < 4; kt++) {
            bf16x8 bf = *(const bf16x8*)&sW[(nt * 16 + lr) * XPITCH + kt * 32 + quad * 8];
            acc[nt] = __builtin_amdgcn_mfma_f32_16x16x32_bf16(af[kt], bf, acc[nt], 0, 0, 0);
        }
    }
    #pragma unroll
    for (int nt = 0; nt < 8; nt++) {
        int col = nt * 16 + lr;
        float bias = b1[col];
        #pragma unroll
        for (int r = 0; r < 4; r++) {
            float v = fmaxf(acc[nt][r] + bias, 0.f);
            sX[(M0 + quad * 4 + r) * XPITCH + col] = f2b(v);
        }
    }
    __syncthreads();    // all waves done reading W1t
    #pragma unroll
    for (int j = 0; j < 8; j++) {
        int idx = t + 256 * j;
        int row = idx >> 4, c = idx & 15;
        ((uint4*)sW)[row * 17 + c] = ((const uint4*)W2t)[idx];
    }
    __syncthreads();

    // phase 3: out = h @ W2 + b2
    #pragma unroll
    for (int kt = 0; kt < 4; kt++)
        af[kt] = *(const bf16x8*)&sX[(M0 + lr) * XPITCH + kt * 32 + quad * 8];
    #pragma unroll
    for (int nt = 0; nt < 8; nt++) {
        acc[nt] = zero;
        #pragma unroll
        for (int kt = 0; kt < 4; kt++) {
            bf16x8 bf = *(const bf16x8*)&sW[(nt * 16 + lr) * XPITCH + kt * 32 + quad * 8];
            acc[nt] = __builtin_amdgcn_mfma_f32_16x16x32_bf16(af[kt], bf, acc[nt], 0, 0, 0);
        }
    }
    #pragma unroll
    for (int nt = 0; nt < 8; nt++) {
        int col = nt * 16 + lr;
        float bias = b2[col];
        #pragma unroll
        for (int r = 0; r < 4; r++) {
            int row = tile + M0 + quad * 4 + r;
            if (row < N)
                __builtin_nontemporal_store(acc[nt][r] + bias,
                                            &out[(long long)row * IN_F + col]);
        }
    }
}

// ================== fp32 node MLP (fallback path only) ======================
__global__ __launch_bounds__(256) void node_mlp_kernel(
    float* agg_out,
    const float* __restrict__ aggE,
    const float* __restrict__ degf,
    const float* __restrict__ We, const float* __restrict__ be,
    const float* __restrict__ W1, const float* __restrict__ b1,
    const float* __restrict__ W2, const float* __restrict__ b2,
    int N)
{
    __shared__ float sA[32][IN_F];
    __shared__ float sH[32][IN_F];
    const int t  = threadIdx.x;
    const int c4 = (t & 31) * 4;
    const int r0 = t >> 5;

    const int tile = blockIdx.x * 32;
    if (tile >= N) return;
    int rows = N - tile;
    if (rows > 32) rows = 32;

    {
        const float4 bev = *(const float4*)&be[c4];
        #pragma unroll
        for (int i = 0; i < 4; i++) {
            int rr = r0 + 8 * i;
            float4 v = make_float4(0.f, 0.f, 0.f, 0.f);
            if (rr < rows) {
                long long r = tile + rr;
                v = *(const float4*)&agg_out[r * IN_F + c4];
                float d = degf[r];
                v.x += d * bev.x; v.y += d * bev.y; v.z += d * bev.z; v.w += d * bev.w;
                #pragma unroll
                for (int k = 0; k < EF; k++) {
                    float a = aggE[r * EF + k];
                    float4 w = *(const float4*)&We[k * IN_F + c4];
                    v.x += a * w.x; v.y += a * w.y; v.z += a * w.z; v.w += a * w.w;
                }
            }
            *(float4*)&sA[rr][c4] = v;
        }
    }
    __syncthreads();
    {
        const float4 bv = *(const float4*)&b1[c4];
        float4 a0 = bv, a1 = bv, a2 = bv, a3 = bv;
        for (int k = 0; k < IN_F; k++) {
            float4 w = *(const float4*)&W1[k * IN_F + c4];
            float x0 = sA[r0][k], x1 = sA[r0 + 8][k], x2 = sA[r0 + 16][k], x3 = sA[r0 + 24][k];
            a0.x += x0 * w.x; a0.y += x0 * w.y; a0.z += x0 * w.z; a0.w += x0 * w.w;
            a1.x += x1 * w.x; a1.y += x1 * w.y; a1.z += x1 * w.z; a1.w += x1 * w.w;
            a2.x += x2 * w.x; a2.y += x2 * w.y; a2.z += x2 * w.z; a2.w += x2 * w.w;
            a3.x += x3 * w.x; a3.y += x3 * w.y; a3.z += x3 * w.z; a3.w += x3 * w.w;
        }
        a0.x = fmaxf(a0.x, 0.f); a0.y = fmaxf(a0.y, 0.f); a0.z = fmaxf(a0.z, 0.f); a0.w = fmaxf(a0.w, 0.f);
        a1.x = fmaxf(a1.x, 0.f); a1.y = fmaxf(a1.y, 0.f); a1.z = fmaxf(a1.z, 0.f); a1.w = fmaxf(a1.w, 0.f);
        a2.x = fmaxf(a2.x, 0.f); a2.y = fmaxf(a2.y, 0.f); a2.z = fmaxf(a2.z, 0.f); a2.w = fmaxf(a2.w, 0.f);
        a3.x = fmaxf(a3.x, 0.f); a3.y = fmaxf(a3.y, 0.f); a3.z = fmaxf(a3.z, 0.f); a3.w = fmaxf(a3.w, 0.f);
        *(float4*)&sH[r0][c4]      = a0;
        *(float4*)&sH[r0 + 8][c4]  = a1;
        *(float4*)&sH[r0 + 16][c4] = a2;
        *(float4*)&sH[r0 + 24][c4] = a3;
    }
    __syncthreads();
    {
        const float4 bv = *(const float4*)&b2[c4];
        float4 a0 = bv, a1 = bv, a2 = bv, a3 = bv;
        for (int k = 0; k < IN_F; k++) {
            float4 w = *(const float4*)&W2[k * IN_F + c4];
            float x0 = sH[r0][k], x1 = sH[r0 + 8][k], x2 = sH[r0 + 16][k], x3 = sH[r0 + 24][k];
            a0.x += x0 * w.x; a0.y += x0 * w.y; a0.z += x0 * w.z; a0.w += x0 * w.w;
            a1.x += x1 * w.x; a1.y += x1 * w.y; a1.z += x1 * w.z; a1.w += x1 * w.w;
            a2.x += x2 * w.x; a2.y += x2 * w.y; a2.z += x2 * w.z; a2.w += x2 * w.w;
            a3.x += x3 * w.x; a3.y += x3 * w.y; a3.z += x3 * w.z; a3.w += x3 * w.w;
        }
        #pragma unroll
        for (int i = 0; i < 4; i++) {
            int rr = r0 + 8 * i;
            if (rr < rows) {
                float4 v = (i == 0) ? a0 : (i == 1) ? a1 : (i == 2) ? a2 : a3;
                *(float4*)&agg_out[(long long)(tile + rr) * IN_F + c4] = v;
            }
        }
    }
}

// ================================ host ======================================
extern "C" void kernel_launch(void* const* d_in, const int* in_sizes, int n_in,
                              void* d_out, int out_size, void* d_ws, size_t ws_size,
                              hipStream_t stream) {
    const float* H  = (const float*)d_in[0];
    const int*   ei = (const int*)d_in[1];     // int32 [2,E]
    const float* EA = (const float*)d_in[2];
    const float* We = (const float*)d_in[3];
    const float* be = (const float*)d_in[4];
    const float* W1 = (const float*)d_in[5];
    const float* b1 = (const float*)d_in[6];
    const float* W2 = (const float*)d_in[7];
    const float* b2 = (const float*)d_in[8];
    float* out = (float*)d_out;

    const int N = in_sizes[0] / IN_F;
    const int E = in_sizes[2] / EF;

    char* p = (char*)d_ws;
    auto alloc = [&](size_t bytes) { char* r = p; p += (bytes + 255) & ~(size_t)255; return r; };
    int2*  sorted   = (int2*)alloc((size_t)E * sizeof(int2));
    int*   rank     = (int*)alloc((size_t)E * sizeof(int));
    float* degf     = (float*)alloc((size_t)N * sizeof(float));
    float* aggE     = (float*)alloc((size_t)N * EF * sizeof(float));
    int*   counts   = (int*)alloc((size_t)(N + 1) * sizeof(int));
    int*   offsets  = (int*)alloc((size_t)(N + 1) * sizeof(int));
    int*   partials = (int*)alloc(1024 * sizeof(int));
    size_t need_base = (size_t)(p - (char*)d_ws);
    unsigned short* Hb = (unsigned short*)alloc((size_t)N * IN_F * sizeof(unsigned short));
    unsigned short* Ab  = (unsigned short*)alloc((size_t)N * IN_F * sizeof(unsigned short));
    unsigned short* W1t = (unsigned short*)alloc((size_t)IN_F * IN_F * sizeof(unsigned short));
    unsigned short* W2t = (unsigned short*)alloc((size_t)IN_F * IN_F * sizeof(unsigned short));
    unsigned short* WeaTb = (unsigned short*)alloc((size_t)IN_F * 32 * sizeof(unsigned short));
    size_t need_mfma = (size_t)(p - (char*)d_ws);

    const int n_scan = N + 1;
    const int B = (n_scan + 1023) / 1024;

    if (ws_size >= need_mfma && B <= 1024) {
        // fast path: 6 dispatches + 1 memset
        hipMemsetAsync(counts, 0, (size_t)(N + 1) * sizeof(int), stream);
        const int n4 = N * IN_F / 4;
        const int h2b_blocks   = (n4 + 255) / 256;
        const int hist_blocks  = (E + 255) / 256;
        const int sa_blocks    = (n_scan + 255) / 256;
        const int build_blocks = (E + 255) / 256;
        const int wea_blocks   = (IN_F * 32 + 255) / 256;   // 16
        hist_kernel<<<hist_blocks, 256, 0, stream>>>(ei, counts, rank, E);
        scan_blocks_kernel<<<B, 256, 0, stream>>>(counts, offsets, partials, n_scan);
        scan_add_h2b_kernel<<<sa_blocks + h2b_blocks, 256, 0, stream>>>(
            offsets, partials, n_scan, H, Hb, n4, sa_blocks);
        build_wcast_kernel<<<build_blocks + 128 + wea_blocks, 256, 0, stream>>>(
            ei, sorted, offsets, rank, E, W1, W1t, W2, W2t, We, be, WeaTb,
            build_blocks);
        gather_ea_kernel<<<2 * ((N + 3) / 4), 256, 0, stream>>>(
            Hb, EA, sorted, offsets, Ab, aggE, N);
        mlp_mfma_kernel<<<(N + 63) / 64, 256, 0, stream>>>(
            Ab, W1t, W2t, aggE, offsets, WeaTb, b1, b2, out, N);
    } else if (ws_size >= need_base && B <= 1024) {
        // fp32 CSR fallback
        hipMemsetAsync(counts, 0, (size_t)(N + 1) * sizeof(int), stream);
        hist_kernel<<<(E + 255) / 256, 256, 0, stream>>>(ei, counts, rank, E);
        scan_blocks_kernel<<<B, 256, 0, stream>>>(counts, offsets, partials, n_scan);
        scan_add_fused_kernel<<<(n_scan + 255) / 256, 256, 0, stream>>>(offsets, partials, n_scan);
        build_kernel<<<(E + 255) / 256, 256, 0, stream>>>(ei, sorted, offsets, rank, E);
        gather_f32_kernel<<<(N + 3) / 4, 256, 0, stream>>>(H, EA, sorted, offsets, out, aggE, degf, N);
        node_mlp_kernel<<<(N + 31) / 32, 256, 0, stream>>>(out, aggE, degf, We, be, W1, b1, W2, b2, N);
    } else {
        // atomic-scatter fallback
        float* f_aggE = (float*)d_ws;
        float* f_deg  = f_aggE + (size_t)N * EF;
        hipMemsetAsync(d_out, 0, (size_t)N * IN_F * sizeof(float), stream);
        hipMemsetAsync(d_ws, 0, (size_t)N * (EF + 1) * sizeof(float), stream);
        long long tot = (long long)E * IN_F;
        edge_scatter_kernel<<<(int)((tot + 255) / 256), 256, 0, stream>>>(H, ei, EA, out, f_aggE, f_deg, E);
        node_mlp_kernel<<<(N + 31) / 32, 256, 0, stream>>>(out, f_aggE, f_deg, We, be, W1, b1, W2, b2, N);
    }
}